// Round 2
// baseline (534.446 us; speedup 1.0000x reference)
//
#include <hip/hip_runtime.h>
#include <hip/hip_bf16.h>
#include <stdint.h>

typedef __attribute__((ext_vector_type(8))) short short8;   // 8 bf16 (4 VGPRs)
typedef __attribute__((ext_vector_type(4))) float f32x4;    // 4 fp32 acc
typedef __hip_bfloat16 bf16;

#define NB   8
#define LSEQ 2048
#define NM   256
#define DMODEL 1024
#define DO   256
#define BLR  16384   /* NB*LSEQ rows */
#define NCH  32      /* scan chunks */
#define CLK  64      /* chunk length */

__device__ __forceinline__ float sigm(float x) { return 1.f / (1.f + __expf(-x)); }

__device__ __forceinline__ void gl_lds16(const void* g, void* l) {
  __builtin_amdgcn_global_load_lds((const __attribute__((address_space(1))) void*)g,
                                   (__attribute__((address_space(3))) void*)l, 16, 0, 0);
}

__device__ __forceinline__ unsigned short bf16bits(float v) {
  bf16 b = __float2bfloat16(v);
  return *(unsigned short*)&b;
}
__device__ __forceinline__ float bits2f(unsigned short u) {
  bf16 b = *(bf16*)&u;
  return __bfloat162float(b);
}

// ---------------- prep: all weight cvts + e8l2a in ONE dispatch ----------------

__global__ __launch_bounds__(256) void prep_kernel(
    const float* __restrict__ gate_w, const float* __restrict__ down_w,
    const float* __restrict__ up_w, const float* __restrict__ wr_w,
    const float* __restrict__ wi_w, const float* __restrict__ ow_w,
    const float* __restrict__ log_a,
    bf16* __restrict__ gate_wb, bf16* __restrict__ down_wb, bf16* __restrict__ up_wb,
    bf16* __restrict__ wrb, bf16* __restrict__ wib, bf16* __restrict__ owb,
    float* __restrict__ e8) {
  int i = blockIdx.x * 256 + threadIdx.x;
  if (i < 1048576) { gate_wb[i] = __float2bfloat16(gate_w[i]); return; }
  i -= 1048576;
  if (i < 262144) { down_wb[i] = __float2bfloat16(down_w[i]); return; }
  i -= 262144;
  if (i < 262144) { up_wb[i] = __float2bfloat16(up_w[i]); return; }
  i -= 262144;
  if (i < 196608) { wrb[i] = __float2bfloat16(wr_w[i]); return; }
  i -= 196608;
  if (i < 196608) { wib[i] = __float2bfloat16(wi_w[i]); return; }
  i -= 196608;
  if (i < 196608) { owb[i] = __float2bfloat16(ow_w[i]); return; }
  i -= 196608;
  if (i < 768) {
    float ab = 1.f / (1.f + expf(-log_a[i]));
    e8[i] = 8.f * log2f(ab);
  }
}

// vectorized f32 -> bf16 (4 elem/thread)
__global__ __launch_bounds__(256) void cvt4_kernel(const float4* __restrict__ in,
                                                   ushort4* __restrict__ out, int n4) {
  int i = blockIdx.x * 256 + threadIdx.x;
  if (i < n4) {
    float4 v = in[i];
    ushort4 o;
    o.x = bf16bits(v.x); o.y = bf16bits(v.y); o.z = bf16bits(v.z); o.w = bf16bits(v.w);
    out[i] = o;
  }
}

// ---------------- EMA + bucket ----------------

__global__ __launch_bounds__(256) void ema_kernel(const float* __restrict__ cpt,
                                                  const float* __restrict__ bprobs,
                                                  const int* __restrict__ bidx,
                                                  float* __restrict__ smoothed) {
  int b = blockIdx.x >> 2;
  int c = ((blockIdx.x & 3) << 8) + threadIdx.x;
  __shared__ float p[NM];
  p[threadIdx.x] = bprobs[b * LSEQ + bidx[b * NM + threadIdx.x]];
  __syncthreads();
  const float* cp = cpt + (size_t)b * NM * DMODEL + c;
  float* sp = smoothed + (size_t)b * NM * DMODEL + c;
  float h = 0.f;
  for (int m = 0; m < NM; ++m) {
    float pm = p[m];
    h = pm * cp[(size_t)m * DMODEL] + (1.f - pm) * h;
    sp[(size_t)m * DMODEL] = h;
  }
}

__global__ __launch_bounds__(256) void bucket_kernel(const int* __restrict__ bidx,
                                                     int* __restrict__ bucket) {
  int i = blockIdx.x * 256 + threadIdx.x;
  int b = i >> 11, l = i & 2047;
  const int* bi = bidx + b * NM;
  int lo = 0, hi = NM;
  while (lo < hi) {
    int mid = (lo + hi) >> 1;
    if (bi[mid] <= l) lo = mid + 1; else hi = mid;
  }
  int v = lo - 1;
  bucket[i] = v < 0 ? 0 : v;
}

// ---------------- depthwise causal conv k=4 ----------------

__global__ __launch_bounds__(256) void conv_kernel(const bf16* __restrict__ x,
                                                   const float* __restrict__ cw,
                                                   const float* __restrict__ cb,
                                                   bf16* __restrict__ xcb) {
  int i = blockIdx.x * 256 + threadIdx.x;
  int c = i & 255;
  int bl = i >> 8;
  int l = bl & 2047;
  float4 w4 = ((const float4*)cw)[c];
  const float* wf = (const float*)&w4;
  float s = cb[c];
#pragma unroll
  for (int kk = 0; kk < 4; ++kk) {
    int ll = l - 3 + kk;
    if (ll >= 0) s += wf[kk] * __bfloat162float(x[i + (kk - 3) * 256]);
  }
  xcb[i] = __float2bfloat16(s);
}

// ---------------- chunked scan, 2 dispatches, 256 blocks each ----------------
// input packed uint: lo16 = d = 1-a (bf16), hi16 = s (bf16). h = (1-d)*h + s.

__global__ __launch_bounds__(256) void scan_p1(const unsigned int* __restrict__ ds,
                                               float2* __restrict__ AS) {
  int b = blockIdx.x >> 5, ch = blockIdx.x & 31, c = threadIdx.x;
  size_t base = ((size_t)b * LSEQ + ch * CLK) * DO + c;
  float A = 1.f, S = 0.f;
  for (int t = 0; t < CLK; ++t) {
    unsigned int u = ds[base + (size_t)t * DO];
    float d = bits2f((unsigned short)(u & 0xffff));
    float s = bits2f((unsigned short)(u >> 16));
    float a = 1.f - d;
    A *= a;
    S = __builtin_fmaf(a, S, s);
  }
  AS[blockIdx.x * DO + c] = make_float2(A, S);
}

__global__ __launch_bounds__(256) void scan_p2(const unsigned int* __restrict__ ds,
                                               const float2* __restrict__ AS,
                                               bf16* __restrict__ hs) {
  int b = blockIdx.x >> 5, ch = blockIdx.x & 31, c = threadIdx.x;
  // prefix over earlier chunks of this batch (L2-hot, <=31 iterations)
  float h = 0.f;
  for (int j = 0; j < ch; ++j) {
    float2 as = AS[(b * NCH + j) * DO + c];
    h = __builtin_fmaf(as.x, h, as.y);
  }
  size_t base = ((size_t)b * LSEQ + ch * CLK) * DO + c;
  for (int t = 0; t < CLK; ++t) {
    unsigned int u = ds[base + (size_t)t * DO];
    float d = bits2f((unsigned short)(u & 0xffff));
    float s = bits2f((unsigned short)(u >> 16));
    h = __builtin_fmaf(-d, h, h) + s;   // (1-d)*h + s
    hs[base + (size_t)t * DO] = __float2bfloat16(h);
  }
}

// ---------------- final rmsnorm over 1024, bf16 in -> f32 out ----------------

__global__ __launch_bounds__(256) void rmsnorm1024_kernel(const bf16* __restrict__ in,
                                                          const float* __restrict__ w,
                                                          float* __restrict__ out) {
  int row = blockIdx.x, t = threadIdx.x;
  ushort4 raw = ((const ushort4*)(in + (size_t)row * 1024))[t];
  float v0 = bits2f(raw.x), v1 = bits2f(raw.y), v2 = bits2f(raw.z), v3 = bits2f(raw.w);
  float ss = v0 * v0 + v1 * v1 + v2 * v2 + v3 * v3;
#pragma unroll
  for (int ofs = 32; ofs > 0; ofs >>= 1) ss += __shfl_down(ss, ofs, 64);
  __shared__ float wsum[4];
  if ((t & 63) == 0) wsum[t >> 6] = ss;
  __syncthreads();
  float tot = wsum[0] + wsum[1] + wsum[2] + wsum[3];
  float sc = rsqrtf(tot * (1.f / 1024.f) + 1e-6f);
  float4 wv = ((const float4*)w)[t];
  float4 o;
  o.x = v0 * sc * wv.x; o.y = v1 * sc * wv.y;
  o.z = v2 * sc * wv.z; o.w = v3 * sc * wv.w;
  ((float4*)(out + (size_t)row * 1024))[t] = o;
}

// ---------------- epilogue arg pack ----------------

struct EpA {
  bf16* outb;
  const float* bias;
  const bf16* encb;
  const float* p;
  const int* bucket;
  const float* smoothed;
};

// ---------------- generic MFMA GEMM 128x128, 2-phase (kept for small-N GEMMs) ----------------

template <int EP>
__global__ __launch_bounds__(256) void gemm_bt(const bf16* __restrict__ A,
                                               const bf16* __restrict__ W,
                                               int N, int K, EpA ep) {
  __shared__ __align__(16) bf16 As[128 * 64];
  __shared__ __align__(16) bf16 Bs[128 * 64];
  const int t = threadIdx.x;
  const int lane = t & 63;
  const int wv = t >> 6;
  const int wm = wv >> 1, wn = wv & 1;
  const int quad = lane >> 4, l16 = lane & 15;
  const int bm = blockIdx.x << 7, bn = blockIdx.y << 7;

  f32x4 acc[4][4] = {};

  for (int k0 = 0; k0 < K; k0 += 64) {
    __syncthreads();
#pragma unroll
    for (int i = 0; i < 4; ++i) {
      int slot = i * 256 + t;
      int m = slot >> 3;
      int lk8 = (slot & 7) ^ (m & 7);
      gl_lds16(A + (size_t)(bm + m) * K + k0 + lk8 * 8, As + slot * 8);
      gl_lds16(W + (size_t)(bn + m) * K + k0 + lk8 * 8, Bs + slot * 8);
    }
    __syncthreads();
#pragma unroll
    for (int ks = 0; ks < 2; ++ks) {
      short8 af[4], bfr[4];
#pragma unroll
      for (int i = 0; i < 4; ++i) {
        int m = wm * 64 + i * 16 + l16;
        int pa = (ks * 4 + quad) ^ (m & 7);
        af[i] = *(const short8*)(As + m * 64 + pa * 8);
        int n = wn * 64 + i * 16 + l16;
        int pb = (ks * 4 + quad) ^ (n & 7);
        bfr[i] = *(const short8*)(Bs + n * 64 + pb * 8);
      }
#pragma unroll
      for (int i = 0; i < 4; ++i)
#pragma unroll
        for (int j = 0; j < 4; ++j)
          acc[i][j] = __builtin_amdgcn_mfma_f32_16x16x32_bf16(af[i], bfr[j], acc[i][j], 0, 0, 0);
    }
  }

#pragma unroll
  for (int i = 0; i < 4; ++i) {
#pragma unroll
    for (int j = 0; j < 4; ++j) {
#pragma unroll
      for (int r = 0; r < 4; ++r) {
        int m = bm + wm * 64 + i * 16 + quad * 4 + r;
        int n = bn + wn * 64 + j * 16 + l16;
        size_t idx = (size_t)m * N + n;
        float v = acc[i][j][r];
        if (EP == 1) {         // gate + plugback (N == DMODEL)
          float g = sigm(v + ep.bias[n]);
          float pm = ep.p[m];
          int bb = m >> 11;
          float sm = ep.smoothed[((size_t)(bb * NM + ep.bucket[m])) * DMODEL + n];
          float e = __bfloat162float(ep.encb[idx]);
          ep.outb[idx] = __float2bfloat16((1.f - pm) * g * e + sm);
        } else {               // EP == 5: plain bf16 out
          ep.outb[idx] = __float2bfloat16(v);
        }
      }
    }
  }
}

// ---------------- 256x256 8-phase GEMM (T2+T3+T4+T5), for N>=256 GEMMs ----------------
// 8 waves (2M x 4N), BK=64, LDS = 2 dbuf x {A,B} x 2 half-tiles of [128][64] bf16 = 128 KiB.
// Half-tile interleave: A-half h holds M-rows {h*64..h*64+63} U {h*64+128..h*64+191}
// (so phase quadrant mg reads exactly slot A[mg] for ALL waves); B-half h holds
// N-rows with ((n>>5)&1)==h analogously. Counted vmcnt(4) at phases 4/8 only.

template <int EP>
__global__ __launch_bounds__(512, 2) void gemm256(const bf16* __restrict__ Ag,
                                                  const bf16* __restrict__ W,
                                                  int N, int K, EpA ep) {
  __shared__ __align__(16) bf16 lds[2][4][128 * 64];   // [buf][A0,A1,B0,B1][...]
  const int t = threadIdx.x;
  const int lane = t & 63;
  const int wv = t >> 6;
  const int wm = wv >> 2, wn = wv & 3;
  const int quad = lane >> 4, l16 = lane & 15;
  const int bm = blockIdx.x << 8, bn = blockIdx.y << 8;
  const int KT = K >> 6;        // # 64-wide k-tiles (power of 2, >= 4)
  const int KM = KT - 1;

  const int rr = t >> 3;                 // 0..63 staging row (q=0); q=1 adds +128 global
  const int cc = (t & 7) ^ (rr & 7);     // pre-swizzled source chunk

  f32x4 acc[8][4] = {};
  short8 af[4][2], bfr[2][2];

#define STAGE_A(BUF, H, KTI)                                                      \
  {                                                                               \
    int kk = ((KTI) & KM) << 6;                                                   \
    const bf16* s0 = Ag + (size_t)(bm + (H) * 64 + rr) * K + kk + cc * 8;         \
    gl_lds16(s0, &lds[BUF][H][t * 8]);                                            \
    const bf16* s1 = Ag + (size_t)(bm + (H) * 64 + rr + 128) * K + kk + cc * 8;   \
    gl_lds16(s1, &lds[BUF][H][(512 + t) * 8]);                                    \
  }
#define STAGE_B(BUF, H, KTI)                                                      \
  {                                                                               \
    int kk = ((KTI) & KM) << 6;                                                   \
    int n0 = (H) * 32 + (rr & 31) + ((rr >> 5) << 6);                             \
    const bf16* s0 = W + (size_t)(bn + n0) * K + kk + cc * 8;                     \
    gl_lds16(s0, &lds[BUF][2 + (H)][t * 8]);                                      \
    const bf16* s1 = W + (size_t)(bn + n0 + 128) * K + kk + cc * 8;               \
    gl_lds16(s1, &lds[BUF][2 + (H)][(512 + t) * 8]);                              \
  }
#define LD_A(BUF, MG)                                                             \
  _Pragma("unroll") for (int ii = 0; ii < 4; ++ii) {                              \
    int r = wm * 64 + ii * 16 + l16;                                              \
    _Pragma("unroll") for (int ks = 0; ks < 2; ++ks) {                            \
      int ch = (ks * 4 + quad) ^ (r & 7);                                         \
      af[ii][ks] = *(const short8*)&lds[BUF][MG][(r * 8 + ch) * 8];               \
    }                                                                             \
  }
#define LD_B(BUF, NG)                                                             \
  _Pragma("unroll") for (int jj = 0; jj < 2; ++jj) {                              \
    int r = wn * 32 + jj * 16 + l16;                                              \
    _Pragma("unroll") for (int ks = 0; ks < 2; ++ks) {                            \
      int ch = (ks * 4 + quad) ^ (r & 7);                                         \
      bfr[jj][ks] = *(const short8*)&lds[BUF][2 + (NG)][(r * 8 + ch) * 8];        \
    }                                                                             \
  }
#define MMA(MG, NG)                                                               \
  _Pragma("unroll") for (int ks = 0; ks < 2; ++ks)                                \
  _Pragma("unroll") for (int ii = 0; ii < 4; ++ii)                                \
  _Pragma("unroll") for (int jj = 0; jj < 2; ++jj)                                \
    acc[(MG) * 4 + ii][(NG) * 2 + jj] = __builtin_amdgcn_mfma_f32_16x16x32_bf16(  \
        af[ii][ks], bfr[jj][ks], acc[(MG) * 4 + ii][(NG) * 2 + jj], 0, 0, 0);
#define BARR __builtin_amdgcn_s_barrier()
#define WAIT_LGKM asm volatile("s_waitcnt lgkmcnt(0)" ::: "memory")
#define WAIT_VM4 asm volatile("s_waitcnt vmcnt(4)" ::: "memory")
#define PH(MG, NG)                   \
  BARR; WAIT_LGKM;                   \
  __builtin_amdgcn_s_setprio(1);     \
  MMA(MG, NG);                       \
  __builtin_amdgcn_s_setprio(0);     \
  BARR;
#define PH_V(MG, NG)                 \
  BARR; WAIT_LGKM;                   \
  __builtin_amdgcn_s_setprio(1);     \
  MMA(MG, NG);                       \
  __builtin_amdgcn_s_setprio(0);     \
  WAIT_VM4;                          \
  BARR;

  // prologue: buf0 <- kt0 complete; buf1 <- kt1 {A0, B1} (steady-state shape)
  STAGE_A(0, 0, 0) STAGE_A(0, 1, 0) STAGE_B(0, 0, 0) STAGE_B(0, 1, 0)
  STAGE_A(1, 0, 1) STAGE_B(1, 1, 1)
  WAIT_VM4;   // buf0's 8 loads (oldest) complete; buf1's 4 stay in flight
  BARR;

#pragma unroll 1
  for (int it = 0; it < (KT >> 1); ++it) {
    const int kt = it * 2;
    // g1: quad (mg0,ng0) of buf0; stage buf1.A1 <- kt+1
    LD_A(0, 0) LD_B(0, 0)
    STAGE_A(1, 1, kt + 1)
    PH(0, 0)
    // g2: (0,1); stage buf1.B0 <- kt+1
    LD_B(0, 1)
    STAGE_B(1, 0, kt + 1)
    PH(0, 1)
    // g3: (1,1); stage buf0.A0 <- kt+2
    LD_A(0, 1)
    STAGE_A(0, 0, kt + 2)
    PH(1, 1)
    // g4: (1,0) re-reads B0; stage buf0.B1 <- kt+2; vmcnt(4) -> buf1(kt+1) resident
    LD_B(0, 0)
    STAGE_B(0, 1, kt + 2)
    PH_V(1, 0)
    // g5: quad (0,0) of buf1; stage buf0.A1 <- kt+2
    LD_A(1, 0) LD_B(1, 0)
    STAGE_A(0, 1, kt + 2)
    PH(0, 0)
    // g6: (0,1); stage buf0.B0 <- kt+2
    LD_B(1, 1)
    STAGE_B(0, 0, kt + 2)
    PH(0, 1)
    // g7: (1,1); stage buf1.A0 <- kt+3
    LD_A(1, 1)
    STAGE_A(1, 0, kt + 3)
    PH(1, 1)
    // g8: (1,0); stage buf1.B1 <- kt+3; vmcnt(4) -> buf0(kt+2) resident
    LD_B(1, 0)
    STAGE_B(1, 1, kt + 3)
    PH_V(1, 0)
  }

#undef STAGE_A
#undef STAGE_B
#undef LD_A
#undef LD_B
#undef MMA
#undef BARR
#undef WAIT_LGKM
#undef WAIT_VM4
#undef PH
#undef PH_V

#pragma unroll
  for (int i = 0; i < 8; ++i) {
#pragma unroll
    for (int j = 0; j < 4; ++j) {
#pragma unroll
      for (int r = 0; r < 4; ++r) {
        int m = bm + wm * 128 + i * 16 + quad * 4 + r;
        int n = bn + wn * 64 + j * 16 + l16;
        size_t idx = (size_t)m * N + n;
        float v = acc[i][j][r];
        if (EP == 1) {         // gate + plugback (N == DMODEL)
          float g = sigm(v + ep.bias[n]);
          float pm = ep.p[m];
          int bb = m >> 11;
          float sm = ep.smoothed[((size_t)(bb * NM + ep.bucket[m])) * DMODEL + n];
          float e = __bfloat162float(ep.encb[idx]);
          ep.outb[idx] = __float2bfloat16((1.f - pm) * g * e + sm);
        } else {               // EP == 5: plain bf16 out
          ep.outb[idx] = __float2bfloat16(v);
        }
      }
    }
  }
}

// ---------------- dual GEMM: r & i heads share A, fused a_t/s_t epilogue ----------------
// A = xconv bf16 [BLR,256]; Wr,Wi [256,256]. Writes packed uint{d=1-a bf16, s bf16}.

__global__ __launch_bounds__(256) void gemm_ri(const bf16* __restrict__ A,
                                               const bf16* __restrict__ Wr,
                                               const bf16* __restrict__ Wi,
                                               const float* __restrict__ rbias,
                                               const float* __restrict__ ibias,
                                               const float* __restrict__ e8,
                                               unsigned int* __restrict__ ds_out) {
  __shared__ __align__(16) bf16 As[128 * 64];
  __shared__ __align__(16) bf16 Br[128 * 64];
  __shared__ __align__(16) bf16 Bi[128 * 64];
  const int t = threadIdx.x;
  const int lane = t & 63;
  const int wv = t >> 6;
  const int wm = wv >> 1, wn = wv & 1;
  const int quad = lane >> 4, l16 = lane & 15;
  const int bm = blockIdx.x << 7, bn = blockIdx.y << 7;

  f32x4 ar[4][4] = {};
  f32x4 ai[4][4] = {};

  for (int k0 = 0; k0 < DO; k0 += 64) {
    __syncthreads();
#pragma unroll
    for (int i = 0; i < 4; ++i) {
      int slot = i * 256 + t;
      int m = slot >> 3;
      int lk8 = (slot & 7) ^ (m & 7);
      gl_lds16(A + (size_t)(bm + m) * DO + k0 + lk8 * 8, As + slot * 8);
      gl_lds16(Wr + (size_t)(bn + m) * DO + k0 + lk8 * 8, Br + slot * 8);
      gl_lds16(Wi + (size_t)(bn + m) * DO + k0 + lk8 * 8, Bi + slot * 8);
    }
    __syncthreads();
#pragma unroll
    for (int ks = 0; ks < 2; ++ks) {
      short8 af[4], br[4], bi[4];
#pragma unroll
      for (int i = 0; i < 4; ++i) {
        int m = wm * 64 + i * 16 + l16;
        int pa = (ks * 4 + quad) ^ (m & 7);
        af[i] = *(const short8*)(As + m * 64 + pa * 8);
        int n = wn * 64 + i * 16 + l16;
        int pb = (ks * 4 + quad) ^ (n & 7);
        br[i] = *(const short8*)(Br + n * 64 + pb * 8);
        bi[i] = *(const short8*)(Bi + n * 64 + pb * 8);
      }
#pragma unroll
      for (int i = 0; i < 4; ++i)
#pragma unroll
        for (int j = 0; j < 4; ++j) {
          ar[i][j] = __builtin_amdgcn_mfma_f32_16x16x32_bf16(af[i], br[j], ar[i][j], 0, 0, 0);
          ai[i][j] = __builtin_amdgcn_mfma_f32_16x16x32_bf16(af[i], bi[j], ai[i][j], 0, 0, 0);
        }
    }
  }

#pragma unroll
  for (int i = 0; i < 4; ++i) {
#pragma unroll
    for (int j = 0; j < 4; ++j) {
#pragma unroll
      for (int r = 0; r < 4; ++r) {
        int m = bm + wm * 64 + i * 16 + quad * 4 + r;
        int n = bn + wn * 64 + j * 16 + l16;
        size_t idx = (size_t)m * DO + n;
        float rv = sigm(ar[i][j][r] + rbias[n]);
        float a = exp2f(rv * e8[n]);
        float d = 1.f - a;                               // ~5e-3, bf16-safe
        float iv = sigm(ai[i][j][r] + ibias[n]);
        float xc = __bfloat162float(A[idx]);             // xconv[m][n] == A[m][n]
        float s = sqrtf(fmaxf(1.f - a * a, 0.f)) * iv * xc;
        ds_out[idx] = (unsigned int)bf16bits(d) | ((unsigned int)bf16bits(s) << 16);
      }
    }
  }
}

// ---------------- out-proj GEMM tile 64x256 + fused RMSNorm(256) ----------------

__global__ __launch_bounds__(256) void gemm_on(const bf16* __restrict__ A,   // hs [BLR,256]
                                               const bf16* __restrict__ W,   // ow [256,256]
                                               const float* __restrict__ rnw,
                                               bf16* __restrict__ xb) {
  __shared__ __align__(16) bf16 As[64 * 64];
  __shared__ __align__(16) bf16 Bs[256 * 64];
  __shared__ float red[4][64];
  const int t = threadIdx.x;
  const int lane = t & 63;
  const int wn = t >> 6;           // wave = column slice of 64
  const int quad = lane >> 4, l16 = lane & 15;
  const int bm = blockIdx.x << 6;

  f32x4 acc[4][4] = {};

  for (int k0 = 0; k0 < DO; k0 += 64) {
    __syncthreads();
#pragma unroll
    for (int i = 0; i < 2; ++i) {
      int slot = i * 256 + t;
      int m = slot >> 3;
      int lk8 = (slot & 7) ^ (m & 7);
      gl_lds16(A + (size_t)(bm + m) * DO + k0 + lk8 * 8, As + slot * 8);
    }
#pragma unroll
    for (int i = 0; i < 8; ++i) {
      int slot = i * 256 + t;
      int n = slot >> 3;
      int lk8 = (slot & 7) ^ (n & 7);
      gl_lds16(W + (size_t)n * DO + k0 + lk8 * 8, Bs + slot * 8);
    }
    __syncthreads();
#pragma unroll
    for (int ks = 0; ks < 2; ++ks) {
      short8 af[4], bfr[4];
#pragma unroll
      for (int i = 0; i < 4; ++i) {
        int m = i * 16 + l16;
        int pa = (ks * 4 + quad) ^ (m & 7);
        af[i] = *(const short8*)(As + m * 64 + pa * 8);
        int n = wn * 64 + i * 16 + l16;
        int pb = (ks * 4 + quad) ^ (n & 7);
        bfr[i] = *(const short8*)(Bs + n * 64 + pb * 8);
      }
#pragma unroll
      for (int i = 0; i < 4; ++i)
#pragma unroll
        for (int j = 0; j < 4; ++j)
          acc[i][j] = __builtin_amdgcn_mfma_f32_16x16x32_bf16(af[i], bfr[j], acc[i][j], 0, 0, 0);
    }
  }

  float part[4][4];
#pragma unroll
  for (int i = 0; i < 4; ++i)
#pragma unroll
    for (int r = 0; r < 4; ++r) {
      float s = 0.f;
#pragma unroll
      for (int j = 0; j < 4; ++j) s += acc[i][j][r] * acc[i][j][r];
      part[i][r] = s;
    }
#pragma unroll
  for (int mask = 1; mask <= 8; mask <<= 1)
#pragma unroll
    for (int i = 0; i < 4; ++i)
#pragma unroll
      for (int r = 0; r < 4; ++r) part[i][r] += __shfl_xor(part[i][r], mask, 64);
  if (l16 == 0) {
#pragma unroll
    for (int i = 0; i < 4; ++i)
#pragma unroll
      for (int r = 0; r < 4; ++r) red[wn][i * 16 + quad * 4 + r] = part[i][r];
  }
  __syncthreads();
#pragma unroll
  for (int i = 0; i < 4; ++i) {
#pragma unroll
    for (int r = 0; r < 4; ++r) {
      int ml = i * 16 + quad * 4 + r;
      float tot = red[0][ml] + red[1][ml] + red[2][ml] + red[3][ml];
      float sc = rsqrtf(tot * (1.f / 256.f) + 1e-6f);
#pragma unroll
      for (int j = 0; j < 4; ++j) {
        int n = wn * 64 + j * 16 + l16;
        xb[(size_t)(bm + ml) * DO + n] = __float2bfloat16(acc[i][j][r] * sc * rnw[n]);
      }
    }
  }
}

// ---------------- launch ----------------

extern "C" void kernel_launch(void* const* d_in, const int* in_sizes, int n_in,
                              void* d_out, int out_size, void* d_ws, size_t ws_size,
                              hipStream_t stream) {
  const float* concept_out = (const float*)d_in[0];
  const float* encoder_out = (const float*)d_in[1];
  const float* bprobs      = (const float*)d_in[2];
  const int*   bidx        = (const int*)d_in[3];
  const float* gate_w      = (const float*)d_in[4];
  const float* gate_b      = (const float*)d_in[5];
  const float* down_w      = (const float*)d_in[6];
  const float* up_w        = (const float*)d_in[7];
  const float* norm_out_w  = (const float*)d_in[8];
  const float* rc_w        = (const float*)d_in[9];
  const float* rc_b        = (const float*)d_in[10];
  const float* wr_w        = (const float*)d_in[11];
  const float* wr_b        = (const float*)d_in[12];
  const float* wi_w        = (const float*)d_in[13];
  const float* wi_b        = (const float*)d_in[14];
  const float* log_a       = (const float*)d_in[15];
  const float* ow_w        = (const float*)d_in[16];
  const float* rn_w        = (const float*)d_in[17];
  float* out = (float*)d_out;
  (void)in_sizes; (void)n_in; (void)out_size; (void)ws_size;

  char* base = (char*)d_ws;
  size_t off = 0;
  auto alloc = [&](size_t bytes) -> char* {
    char* p = base + off;
    off += (bytes + 255) & ~(size_t)255;
    return p;
  };
  float* smoothed = (float*)alloc((size_t)NB * NM * DMODEL * 4);   // 8 MB
  int*   bucket   = (int*)alloc((size_t)BLR * 4);
  bf16*  gate_wb  = (bf16*)alloc((size_t)DMODEL * DMODEL * 2);
  bf16*  down_wb  = (bf16*)alloc((size_t)DO * DMODEL * 2);
  bf16*  up_wb    = (bf16*)alloc((size_t)DMODEL * DO * 2);
  bf16*  wrb      = (bf16*)alloc((size_t)3 * DO * DO * 2);
  bf16*  wib      = (bf16*)alloc((size_t)3 * DO * DO * 2);
  bf16*  owb      = (bf16*)alloc((size_t)3 * DO * DO * 2);
  float* e8       = (float*)alloc(3 * DO * 4);
  float2* ASsum   = (float2*)alloc((size_t)NB * NCH * DO * 8);     // 512 KB chunk summaries
  bf16*  xb       = (bf16*)alloc((size_t)BLR * DO * 2);            // 8 MB layer io

  // reused overlay region — offsets computed from actual buffer sizes
  const size_t SZ_ENC   = (size_t)BLR * DMODEL * 2;   // 32 MB
  const size_t SZ_XCONV = (size_t)BLR * DO * 2;       //  8 MB
  const size_t SZ_DS    = (size_t)BLR * DO * 4;       // 16 MB (packed uint32!)
  char* RA = alloc(2 * SZ_ENC);                       // 64 MB
  // head overlays
  bf16*  encb = (bf16*)RA;
  bf16*  h0b  = (bf16*)(RA + SZ_ENC);
  // layer overlays (xconvb | dsbuf | hsb disjoint: 8 + 16 + 8 = 32 MB)
  bf16*         xconvb = (bf16*)RA;
  unsigned int* dsbuf  = (unsigned int*)(RA + SZ_XCONV);
  bf16*         hsb    = (bf16*)(RA + SZ_XCONV + SZ_DS);
  // tail overlay
  bf16*  tmp2b  = (bf16*)RA;

  cvt4_kernel<<<(BLR * DMODEL / 4 + 255) / 256, 256, 0, stream>>>(
      (const float4*)encoder_out, (ushort4*)encb, BLR * DMODEL / 4);
  prep_kernel<<<(2163456 + 255) / 256, 256, 0, stream>>>(
      gate_w, down_w, up_w, wr_w, wi_w, ow_w, log_a,
      gate_wb, down_wb, up_wb, wrb, wib, owb, e8);
  ema_kernel<<<NB * 4, 256, 0, stream>>>(concept_out, bprobs, bidx, smoothed);
  bucket_kernel<<<BLR / 256, 256, 0, stream>>>(bidx, bucket);

  EpA ep;
  // G1: gate GEMM + fused gated residual + plugback -> h0 (bf16), 256^2 8-phase
  ep = EpA{};
  ep.outb = h0b; ep.bias = gate_b; ep.encb = encb; ep.p = bprobs;
  ep.bucket = bucket; ep.smoothed = smoothed;
  gemm256<1><<<dim3(BLR / 256, DMODEL / 256), 512, 0, stream>>>(encb, gate_wb, DMODEL, DMODEL, ep);
  // G2: down projection -> xb (bf16)  (N=256 -> keep 128^2 kernel for grid occupancy)
  ep = EpA{}; ep.outb = xb;
  gemm_bt<5><<<dim3(BLR / 128, DO / 128), 256, 0, stream>>>(h0b, down_wb, DO, DMODEL, ep);

  for (int k = 0; k < 3; ++k) {
    conv_kernel<<<BLR, 256, 0, stream>>>(xb, rc_w + k * DO * 4, rc_b + k * DO, xconvb);
    gemm_ri<<<dim3(BLR / 128, DO / 128), 256, 0, stream>>>(
        xconvb, wrb + k * DO * DO, wib + k * DO * DO,
        wr_b + k * DO, wi_b + k * DO, e8 + k * DO, dsbuf);
    scan_p1<<<NB * NCH, 256, 0, stream>>>(dsbuf, ASsum);
    scan_p2<<<NB * NCH, 256, 0, stream>>>(dsbuf, ASsum, hsb);
    gemm_on<<<BLR / 64, 256, 0, stream>>>(hsb, owb + k * DO * DO, rn_w + k * DO, xb);
  }

  // up projection -> tmp2 (bf16), 256^2 8-phase; final rmsnorm -> out (f32)
  ep = EpA{}; ep.outb = tmp2b;
  gemm256<5><<<dim3(BLR / 256, DMODEL / 256), 512, 0, stream>>>(xb, up_wb, DMODEL, DO, ep);
  rmsnorm1024_kernel<<<BLR, 256, 0, stream>>>(tmp2b, norm_out_w, out);
}

// Round 3
// 534.318 us; speedup vs baseline: 1.0002x; 1.0002x over previous
//
#include <hip/hip_runtime.h>
#include <hip/hip_bf16.h>
#include <stdint.h>

typedef __attribute__((ext_vector_type(8))) short short8;   // 8 bf16 (4 VGPRs)
typedef __attribute__((ext_vector_type(4))) float f32x4;    // 4 fp32 acc
typedef __hip_bfloat16 bf16;

#define NB   8
#define LSEQ 2048
#define NM   256
#define DMODEL 1024
#define DO   256
#define BLR  16384   /* NB*LSEQ rows */
#define NCH  32      /* scan chunks */
#define CLK  64      /* chunk length */

__device__ __forceinline__ float sigm(float x) { return 1.f / (1.f + __expf(-x)); }

__device__ __forceinline__ void gl_lds16(const void* g, void* l) {
  __builtin_amdgcn_global_load_lds((const __attribute__((address_space(1))) void*)g,
                                   (__attribute__((address_space(3))) void*)l, 16, 0, 0);
}

__device__ __forceinline__ unsigned short bf16bits(float v) {
  bf16 b = __float2bfloat16(v);
  return *(unsigned short*)&b;
}
__device__ __forceinline__ float bits2f(unsigned short u) {
  bf16 b = *(bf16*)&u;
  return __bfloat162float(b);
}

// ---------------- prep: all weight cvts + e8l2a in ONE dispatch ----------------

__global__ __launch_bounds__(256) void prep_kernel(
    const float* __restrict__ gate_w, const float* __restrict__ down_w,
    const float* __restrict__ up_w, const float* __restrict__ wr_w,
    const float* __restrict__ wi_w, const float* __restrict__ ow_w,
    const float* __restrict__ log_a,
    bf16* __restrict__ gate_wb, bf16* __restrict__ down_wb, bf16* __restrict__ up_wb,
    bf16* __restrict__ wrb, bf16* __restrict__ wib, bf16* __restrict__ owb,
    float* __restrict__ e8) {
  int i = blockIdx.x * 256 + threadIdx.x;
  if (i < 1048576) { gate_wb[i] = __float2bfloat16(gate_w[i]); return; }
  i -= 1048576;
  if (i < 262144) { down_wb[i] = __float2bfloat16(down_w[i]); return; }
  i -= 262144;
  if (i < 262144) { up_wb[i] = __float2bfloat16(up_w[i]); return; }
  i -= 262144;
  if (i < 196608) { wrb[i] = __float2bfloat16(wr_w[i]); return; }
  i -= 196608;
  if (i < 196608) { wib[i] = __float2bfloat16(wi_w[i]); return; }
  i -= 196608;
  if (i < 196608) { owb[i] = __float2bfloat16(ow_w[i]); return; }
  i -= 196608;
  if (i < 768) {
    float ab = 1.f / (1.f + expf(-log_a[i]));
    e8[i] = 8.f * log2f(ab);
  }
}

// vectorized f32 -> bf16 (4 elem/thread)
__global__ __launch_bounds__(256) void cvt4_kernel(const float4* __restrict__ in,
                                                   ushort4* __restrict__ out, int n4) {
  int i = blockIdx.x * 256 + threadIdx.x;
  if (i < n4) {
    float4 v = in[i];
    ushort4 o;
    o.x = bf16bits(v.x); o.y = bf16bits(v.y); o.z = bf16bits(v.z); o.w = bf16bits(v.w);
    out[i] = o;
  }
}

// ---------------- EMA + bucket ----------------

__global__ __launch_bounds__(256) void ema_kernel(const float* __restrict__ cpt,
                                                  const float* __restrict__ bprobs,
                                                  const int* __restrict__ bidx,
                                                  float* __restrict__ smoothed) {
  int b = blockIdx.x >> 2;
  int c = ((blockIdx.x & 3) << 8) + threadIdx.x;
  __shared__ float p[NM];
  p[threadIdx.x] = bprobs[b * LSEQ + bidx[b * NM + threadIdx.x]];
  __syncthreads();
  const float* cp = cpt + (size_t)b * NM * DMODEL + c;
  float* sp = smoothed + (size_t)b * NM * DMODEL + c;
  float h = 0.f;
  for (int m = 0; m < NM; ++m) {
    float pm = p[m];
    h = pm * cp[(size_t)m * DMODEL] + (1.f - pm) * h;
    sp[(size_t)m * DMODEL] = h;
  }
}

__global__ __launch_bounds__(256) void bucket_kernel(const int* __restrict__ bidx,
                                                     int* __restrict__ bucket) {
  int i = blockIdx.x * 256 + threadIdx.x;
  int b = i >> 11, l = i & 2047;
  const int* bi = bidx + b * NM;
  int lo = 0, hi = NM;
  while (lo < hi) {
    int mid = (lo + hi) >> 1;
    if (bi[mid] <= l) lo = mid + 1; else hi = mid;
  }
  int v = lo - 1;
  bucket[i] = v < 0 ? 0 : v;
}

// ---------------- depthwise causal conv k=4 ----------------

__global__ __launch_bounds__(256) void conv_kernel(const bf16* __restrict__ x,
                                                   const float* __restrict__ cw,
                                                   const float* __restrict__ cb,
                                                   bf16* __restrict__ xcb) {
  int i = blockIdx.x * 256 + threadIdx.x;
  int c = i & 255;
  int bl = i >> 8;
  int l = bl & 2047;
  float4 w4 = ((const float4*)cw)[c];
  const float* wf = (const float*)&w4;
  float s = cb[c];
#pragma unroll
  for (int kk = 0; kk < 4; ++kk) {
    int ll = l - 3 + kk;
    if (ll >= 0) s += wf[kk] * __bfloat162float(x[i + (kk - 3) * 256]);
  }
  xcb[i] = __float2bfloat16(s);
}

// ---------------- chunked scan, 2 dispatches, 256 blocks each ----------------
// input packed uint: lo16 = d = 1-a (bf16), hi16 = s (bf16). h = (1-d)*h + s.

__global__ __launch_bounds__(256) void scan_p1(const unsigned int* __restrict__ ds,
                                               float2* __restrict__ AS) {
  int b = blockIdx.x >> 5, ch = blockIdx.x & 31, c = threadIdx.x;
  size_t base = ((size_t)b * LSEQ + ch * CLK) * DO + c;
  float A = 1.f, S = 0.f;
  for (int t = 0; t < CLK; ++t) {
    unsigned int u = ds[base + (size_t)t * DO];
    float d = bits2f((unsigned short)(u & 0xffff));
    float s = bits2f((unsigned short)(u >> 16));
    float a = 1.f - d;
    A *= a;
    S = __builtin_fmaf(a, S, s);
  }
  AS[blockIdx.x * DO + c] = make_float2(A, S);
}

__global__ __launch_bounds__(256) void scan_p2(const unsigned int* __restrict__ ds,
                                               const float2* __restrict__ AS,
                                               bf16* __restrict__ hs) {
  int b = blockIdx.x >> 5, ch = blockIdx.x & 31, c = threadIdx.x;
  // prefix over earlier chunks of this batch (L2-hot, <=31 iterations)
  float h = 0.f;
  for (int j = 0; j < ch; ++j) {
    float2 as = AS[(b * NCH + j) * DO + c];
    h = __builtin_fmaf(as.x, h, as.y);
  }
  size_t base = ((size_t)b * LSEQ + ch * CLK) * DO + c;
  for (int t = 0; t < CLK; ++t) {
    unsigned int u = ds[base + (size_t)t * DO];
    float d = bits2f((unsigned short)(u & 0xffff));
    float s = bits2f((unsigned short)(u >> 16));
    h = __builtin_fmaf(-d, h, h) + s;   // (1-d)*h + s
    hs[base + (size_t)t * DO] = __float2bfloat16(h);
  }
}

// ---------------- final rmsnorm over 1024, bf16 in -> f32 out ----------------

__global__ __launch_bounds__(256) void rmsnorm1024_kernel(const bf16* __restrict__ in,
                                                          const float* __restrict__ w,
                                                          float* __restrict__ out) {
  int row = blockIdx.x, t = threadIdx.x;
  ushort4 raw = ((const ushort4*)(in + (size_t)row * 1024))[t];
  float v0 = bits2f(raw.x), v1 = bits2f(raw.y), v2 = bits2f(raw.z), v3 = bits2f(raw.w);
  float ss = v0 * v0 + v1 * v1 + v2 * v2 + v3 * v3;
#pragma unroll
  for (int ofs = 32; ofs > 0; ofs >>= 1) ss += __shfl_down(ss, ofs, 64);
  __shared__ float wsum[4];
  if ((t & 63) == 0) wsum[t >> 6] = ss;
  __syncthreads();
  float tot = wsum[0] + wsum[1] + wsum[2] + wsum[3];
  float sc = rsqrtf(tot * (1.f / 1024.f) + 1e-6f);
  float4 wv = ((const float4*)w)[t];
  float4 o;
  o.x = v0 * sc * wv.x; o.y = v1 * sc * wv.y;
  o.z = v2 * sc * wv.z; o.w = v3 * sc * wv.w;
  ((float4*)(out + (size_t)row * 1024))[t] = o;
}

// ---------------- epilogue arg pack ----------------

struct EpA {
  bf16* outb;
  const float* bias;
  const bf16* encb;
  const float* p;
  const int* bucket;
  const float* smoothed;
};

// ---------------- generic MFMA GEMM 128x128, 2-phase (kept for small-N GEMMs) ----------------

template <int EP>
__global__ __launch_bounds__(256) void gemm_bt(const bf16* __restrict__ A,
                                               const bf16* __restrict__ W,
                                               int N, int K, EpA ep) {
  __shared__ __align__(16) bf16 As[128 * 64];
  __shared__ __align__(16) bf16 Bs[128 * 64];
  const int t = threadIdx.x;
  const int lane = t & 63;
  const int wv = t >> 6;
  const int wm = wv >> 1, wn = wv & 1;
  const int quad = lane >> 4, l16 = lane & 15;
  const int bm = blockIdx.x << 7, bn = blockIdx.y << 7;

  f32x4 acc[4][4] = {};

  for (int k0 = 0; k0 < K; k0 += 64) {
    __syncthreads();
#pragma unroll
    for (int i = 0; i < 4; ++i) {
      int slot = i * 256 + t;
      int m = slot >> 3;
      int lk8 = (slot & 7) ^ (m & 7);
      gl_lds16(A + (size_t)(bm + m) * K + k0 + lk8 * 8, As + slot * 8);
      gl_lds16(W + (size_t)(bn + m) * K + k0 + lk8 * 8, Bs + slot * 8);
    }
    __syncthreads();
#pragma unroll
    for (int ks = 0; ks < 2; ++ks) {
      short8 af[4], bfr[4];
#pragma unroll
      for (int i = 0; i < 4; ++i) {
        int m = wm * 64 + i * 16 + l16;
        int pa = (ks * 4 + quad) ^ (m & 7);
        af[i] = *(const short8*)(As + m * 64 + pa * 8);
        int n = wn * 64 + i * 16 + l16;
        int pb = (ks * 4 + quad) ^ (n & 7);
        bfr[i] = *(const short8*)(Bs + n * 64 + pb * 8);
      }
#pragma unroll
      for (int i = 0; i < 4; ++i)
#pragma unroll
        for (int j = 0; j < 4; ++j)
          acc[i][j] = __builtin_amdgcn_mfma_f32_16x16x32_bf16(af[i], bfr[j], acc[i][j], 0, 0, 0);
    }
  }

#pragma unroll
  for (int i = 0; i < 4; ++i) {
#pragma unroll
    for (int j = 0; j < 4; ++j) {
#pragma unroll
      for (int r = 0; r < 4; ++r) {
        int m = bm + wm * 64 + i * 16 + quad * 4 + r;
        int n = bn + wn * 64 + j * 16 + l16;
        size_t idx = (size_t)m * N + n;
        float v = acc[i][j][r];
        if (EP == 1) {         // gate + plugback (N == DMODEL)
          float g = sigm(v + ep.bias[n]);
          float pm = ep.p[m];
          int bb = m >> 11;
          float sm = ep.smoothed[((size_t)(bb * NM + ep.bucket[m])) * DMODEL + n];
          float e = __bfloat162float(ep.encb[idx]);
          ep.outb[idx] = __float2bfloat16((1.f - pm) * g * e + sm);
        } else {               // EP == 5: plain bf16 out
          ep.outb[idx] = __float2bfloat16(v);
        }
      }
    }
  }
}

// ---------------- 256x256 8-phase GEMM (T2+T3+T4+T5), for N>=256 GEMMs ----------------
// 8 waves (2M x 4N), BK=64, LDS = 2 dbuf x {A,B} x 2 half-tiles of [128][64] bf16 = 128 KiB.
// m201-depth schedule: every STAGE lands exactly 1 phase after its slot's last
// ds_read; waits are vmcnt(6) at phases 4/8 (3 half-tiles in flight, >=3-phase
// window per load). Steady-state ledger: enter iter with 6 outstanding, peak 14,
// each wait retires exactly the 8 loads of the buffer consumed next.

template <int EP>
__global__ __launch_bounds__(512, 2) void gemm256(const bf16* __restrict__ Ag,
                                                  const bf16* __restrict__ W,
                                                  int N, int K, EpA ep) {
  __shared__ __align__(16) bf16 lds[2][4][128 * 64];   // [buf][A0,A1,B0,B1][...]
  const int t = threadIdx.x;
  const int lane = t & 63;
  const int wv = t >> 6;
  const int wm = wv >> 2, wn = wv & 3;
  const int quad = lane >> 4, l16 = lane & 15;
  const int bm = blockIdx.x << 8, bn = blockIdx.y << 8;
  const int KT = K >> 6;        // # 64-wide k-tiles (power of 2, >= 4)
  const int KM = KT - 1;

  const int rr = t >> 3;                 // 0..63 staging row (q=0); q=1 adds +128 global
  const int cc = (t & 7) ^ (rr & 7);     // pre-swizzled source chunk

  f32x4 acc[8][4] = {};
  short8 af[4][2], bfr[2][2];

#define STAGE_A(BUF, H, KTI)                                                      \
  {                                                                               \
    int kk = ((KTI) & KM) << 6;                                                   \
    const bf16* s0 = Ag + (size_t)(bm + (H) * 64 + rr) * K + kk + cc * 8;         \
    gl_lds16(s0, &lds[BUF][H][t * 8]);                                            \
    const bf16* s1 = Ag + (size_t)(bm + (H) * 64 + rr + 128) * K + kk + cc * 8;   \
    gl_lds16(s1, &lds[BUF][H][(512 + t) * 8]);                                    \
  }
#define STAGE_B(BUF, H, KTI)                                                      \
  {                                                                               \
    int kk = ((KTI) & KM) << 6;                                                   \
    int n0 = (H) * 32 + (rr & 31) + ((rr >> 5) << 6);                             \
    const bf16* s0 = W + (size_t)(bn + n0) * K + kk + cc * 8;                     \
    gl_lds16(s0, &lds[BUF][2 + (H)][t * 8]);                                      \
    const bf16* s1 = W + (size_t)(bn + n0 + 128) * K + kk + cc * 8;               \
    gl_lds16(s1, &lds[BUF][2 + (H)][(512 + t) * 8]);                              \
  }
#define LD_A(BUF, MG)                                                             \
  _Pragma("unroll") for (int ii = 0; ii < 4; ++ii) {                              \
    int r = wm * 64 + ii * 16 + l16;                                              \
    _Pragma("unroll") for (int ks = 0; ks < 2; ++ks) {                            \
      int ch = (ks * 4 + quad) ^ (r & 7);                                         \
      af[ii][ks] = *(const short8*)&lds[BUF][MG][(r * 8 + ch) * 8];               \
    }                                                                             \
  }
#define LD_B(BUF, NG)                                                             \
  _Pragma("unroll") for (int jj = 0; jj < 2; ++jj) {                              \
    int r = wn * 32 + jj * 16 + l16;                                              \
    _Pragma("unroll") for (int ks = 0; ks < 2; ++ks) {                            \
      int ch = (ks * 4 + quad) ^ (r & 7);                                         \
      bfr[jj][ks] = *(const short8*)&lds[BUF][2 + (NG)][(r * 8 + ch) * 8];        \
    }                                                                             \
  }
#define MMA(MG, NG)                                                               \
  _Pragma("unroll") for (int ks = 0; ks < 2; ++ks)                                \
  _Pragma("unroll") for (int ii = 0; ii < 4; ++ii)                                \
  _Pragma("unroll") for (int jj = 0; jj < 2; ++jj)                                \
    acc[(MG) * 4 + ii][(NG) * 2 + jj] = __builtin_amdgcn_mfma_f32_16x16x32_bf16(  \
        af[ii][ks], bfr[jj][ks], acc[(MG) * 4 + ii][(NG) * 2 + jj], 0, 0, 0);
#define BARR __builtin_amdgcn_s_barrier()
#define WAIT_LGKM asm volatile("s_waitcnt lgkmcnt(0)" ::: "memory")
#define WAIT_VM6 asm volatile("s_waitcnt vmcnt(6)" ::: "memory")
#define PH(MG, NG)                   \
  BARR; WAIT_LGKM;                   \
  __builtin_amdgcn_s_setprio(1);     \
  MMA(MG, NG);                       \
  __builtin_amdgcn_s_setprio(0);     \
  BARR;
#define PH_V(MG, NG)                 \
  BARR; WAIT_LGKM;                   \
  __builtin_amdgcn_s_setprio(1);     \
  MMA(MG, NG);                       \
  __builtin_amdgcn_s_setprio(0);     \
  WAIT_VM6;                          \
  BARR;

  // prologue: buf0 <- kt0 complete; buf1 <- kt1 {A0, A1, B1} (B0 staged at g1)
  STAGE_A(0, 0, 0) STAGE_A(0, 1, 0) STAGE_B(0, 0, 0) STAGE_B(0, 1, 0)
  STAGE_A(1, 0, 1) STAGE_A(1, 1, 1) STAGE_B(1, 1, 1)
  WAIT_VM6;   // buf0's 8 loads (oldest) complete; buf1's 6 stay in flight
  BARR;

#pragma unroll 1
  for (int it = 0; it < (KT >> 1); ++it) {
    const int kt = it * 2;
    // g1: quad (0,0) of buf0; stage buf1.B0 <- kt+1 (slot dead since prev g8)
    LD_A(0, 0) LD_B(0, 0)
    STAGE_B(1, 0, kt + 1)
    PH(0, 0)
    // g2: (0,1); stage buf0.A0 <- kt+2 (A0 last read g1)
    LD_B(0, 1)
    STAGE_A(0, 0, kt + 2)
    PH(0, 1)
    // g3: (1,1); stage buf0.B1 <- kt+2 (B1 last read g2)
    LD_A(0, 1)
    STAGE_B(0, 1, kt + 2)
    PH(1, 1)
    // g4: (1,0) re-reads B0; stage buf0.A1 <- kt+2 (A1 last read g3);
    //     vmcnt(6): retires buf1(kt+1)'s 8, leaves buf0(kt+2)'s 6 in flight
    LD_B(0, 0)
    STAGE_A(0, 1, kt + 2)
    PH_V(1, 0)
    // g5: quad (0,0) of buf1; stage buf0.B0 <- kt+2 (B0 last read g4)
    LD_A(1, 0) LD_B(1, 0)
    STAGE_B(0, 0, kt + 2)
    PH(0, 0)
    // g6: (0,1); stage buf1.A0 <- kt+3 (A0 last read g5)
    LD_B(1, 1)
    STAGE_A(1, 0, kt + 3)
    PH(0, 1)
    // g7: (1,1); stage buf1.B1 <- kt+3 (B1 last read g6)
    LD_A(1, 1)
    STAGE_B(1, 1, kt + 3)
    PH(1, 1)
    // g8: (1,0); stage buf1.A1 <- kt+3 (A1 last read g7);
    //     vmcnt(6): retires buf0(kt+2)'s 8, leaves buf1(kt+3)'s 6 in flight
    LD_B(1, 0)
    STAGE_A(1, 1, kt + 3)
    PH_V(1, 0)
  }

#undef STAGE_A
#undef STAGE_B
#undef LD_A
#undef LD_B
#undef MMA
#undef BARR
#undef WAIT_LGKM
#undef WAIT_VM6
#undef PH
#undef PH_V

#pragma unroll
  for (int i = 0; i < 8; ++i) {
#pragma unroll
    for (int j = 0; j < 4; ++j) {
#pragma unroll
      for (int r = 0; r < 4; ++r) {
        int m = bm + wm * 128 + i * 16 + quad * 4 + r;
        int n = bn + wn * 64 + j * 16 + l16;
        size_t idx = (size_t)m * N + n;
        float v = acc[i][j][r];
        if (EP == 1) {         // gate + plugback (N == DMODEL)
          float g = sigm(v + ep.bias[n]);
          float pm = ep.p[m];
          int bb = m >> 11;
          float sm = ep.smoothed[((size_t)(bb * NM + ep.bucket[m])) * DMODEL + n];
          float e = __bfloat162float(ep.encb[idx]);
          ep.outb[idx] = __float2bfloat16((1.f - pm) * g * e + sm);
        } else {               // EP == 5: plain bf16 out
          ep.outb[idx] = __float2bfloat16(v);
        }
      }
    }
  }
}

// ---------------- dual GEMM: r & i heads share A, fused a_t/s_t epilogue ----------------
// A = xconv bf16 [BLR,256]; Wr,Wi [256,256]. Writes packed uint{d=1-a bf16, s bf16}.

__global__ __launch_bounds__(256) void gemm_ri(const bf16* __restrict__ A,
                                               const bf16* __restrict__ Wr,
                                               const bf16* __restrict__ Wi,
                                               const float* __restrict__ rbias,
                                               const float* __restrict__ ibias,
                                               const float* __restrict__ e8,
                                               unsigned int* __restrict__ ds_out) {
  __shared__ __align__(16) bf16 As[128 * 64];
  __shared__ __align__(16) bf16 Br[128 * 64];
  __shared__ __align__(16) bf16 Bi[128 * 64];
  const int t = threadIdx.x;
  const int lane = t & 63;
  const int wv = t >> 6;
  const int wm = wv >> 1, wn = wv & 1;
  const int quad = lane >> 4, l16 = lane & 15;
  const int bm = blockIdx.x << 7, bn = blockIdx.y << 7;

  f32x4 ar[4][4] = {};
  f32x4 ai[4][4] = {};

  for (int k0 = 0; k0 < DO; k0 += 64) {
    __syncthreads();
#pragma unroll
    for (int i = 0; i < 4; ++i) {
      int slot = i * 256 + t;
      int m = slot >> 3;
      int lk8 = (slot & 7) ^ (m & 7);
      gl_lds16(A + (size_t)(bm + m) * DO + k0 + lk8 * 8, As + slot * 8);
      gl_lds16(Wr + (size_t)(bn + m) * DO + k0 + lk8 * 8, Br + slot * 8);
      gl_lds16(Wi + (size_t)(bn + m) * DO + k0 + lk8 * 8, Bi + slot * 8);
    }
    __syncthreads();
#pragma unroll
    for (int ks = 0; ks < 2; ++ks) {
      short8 af[4], br[4], bi[4];
#pragma unroll
      for (int i = 0; i < 4; ++i) {
        int m = wm * 64 + i * 16 + l16;
        int pa = (ks * 4 + quad) ^ (m & 7);
        af[i] = *(const short8*)(As + m * 64 + pa * 8);
        int n = wn * 64 + i * 16 + l16;
        int pb = (ks * 4 + quad) ^ (n & 7);
        br[i] = *(const short8*)(Br + n * 64 + pb * 8);
        bi[i] = *(const short8*)(Bi + n * 64 + pb * 8);
      }
#pragma unroll
      for (int i = 0; i < 4; ++i)
#pragma unroll
        for (int j = 0; j < 4; ++j) {
          ar[i][j] = __builtin_amdgcn_mfma_f32_16x16x32_bf16(af[i], br[j], ar[i][j], 0, 0, 0);
          ai[i][j] = __builtin_amdgcn_mfma_f32_16x16x32_bf16(af[i], bi[j], ai[i][j], 0, 0, 0);
        }
    }
  }

#pragma unroll
  for (int i = 0; i < 4; ++i) {
#pragma unroll
    for (int j = 0; j < 4; ++j) {
#pragma unroll
      for (int r = 0; r < 4; ++r) {
        int m = bm + wm * 64 + i * 16 + quad * 4 + r;
        int n = bn + wn * 64 + j * 16 + l16;
        size_t idx = (size_t)m * DO + n;
        float rv = sigm(ar[i][j][r] + rbias[n]);
        float a = exp2f(rv * e8[n]);
        float d = 1.f - a;                               // ~5e-3, bf16-safe
        float iv = sigm(ai[i][j][r] + ibias[n]);
        float xc = __bfloat162float(A[idx]);             // xconv[m][n] == A[m][n]
        float s = sqrtf(fmaxf(1.f - a * a, 0.f)) * iv * xc;
        ds_out[idx] = (unsigned int)bf16bits(d) | ((unsigned int)bf16bits(s) << 16);
      }
    }
  }
}

// ---------------- out-proj GEMM tile 64x256 + fused RMSNorm(256) ----------------

__global__ __launch_bounds__(256) void gemm_on(const bf16* __restrict__ A,   // hs [BLR,256]
                                               const bf16* __restrict__ W,   // ow [256,256]
                                               const float* __restrict__ rnw,
                                               bf16* __restrict__ xb) {
  __shared__ __align__(16) bf16 As[64 * 64];
  __shared__ __align__(16) bf16 Bs[256 * 64];
  __shared__ float red[4][64];
  const int t = threadIdx.x;
  const int lane = t & 63;
  const int wn = t >> 6;           // wave = column slice of 64
  const int quad = lane >> 4, l16 = lane & 15;
  const int bm = blockIdx.x << 6;

  f32x4 acc[4][4] = {};

  for (int k0 = 0; k0 < DO; k0 += 64) {
    __syncthreads();
#pragma unroll
    for (int i = 0; i < 2; ++i) {
      int slot = i * 256 + t;
      int m = slot >> 3;
      int lk8 = (slot & 7) ^ (m & 7);
      gl_lds16(A + (size_t)(bm + m) * DO + k0 + lk8 * 8, As + slot * 8);
    }
#pragma unroll
    for (int i = 0; i < 8; ++i) {
      int slot = i * 256 + t;
      int n = slot >> 3;
      int lk8 = (slot & 7) ^ (n & 7);
      gl_lds16(W + (size_t)n * DO + k0 + lk8 * 8, Bs + slot * 8);
    }
    __syncthreads();
#pragma unroll
    for (int ks = 0; ks < 2; ++ks) {
      short8 af[4], bfr[4];
#pragma unroll
      for (int i = 0; i < 4; ++i) {
        int m = i * 16 + l16;
        int pa = (ks * 4 + quad) ^ (m & 7);
        af[i] = *(const short8*)(As + m * 64 + pa * 8);
        int n = wn * 64 + i * 16 + l16;
        int pb = (ks * 4 + quad) ^ (n & 7);
        bfr[i] = *(const short8*)(Bs + n * 64 + pb * 8);
      }
#pragma unroll
      for (int i = 0; i < 4; ++i)
#pragma unroll
        for (int j = 0; j < 4; ++j)
          acc[i][j] = __builtin_amdgcn_mfma_f32_16x16x32_bf16(af[i], bfr[j], acc[i][j], 0, 0, 0);
    }
  }

  float part[4][4];
#pragma unroll
  for (int i = 0; i < 4; ++i)
#pragma unroll
    for (int r = 0; r < 4; ++r) {
      float s = 0.f;
#pragma unroll
      for (int j = 0; j < 4; ++j) s += acc[i][j][r] * acc[i][j][r];
      part[i][r] = s;
    }
#pragma unroll
  for (int mask = 1; mask <= 8; mask <<= 1)
#pragma unroll
    for (int i = 0; i < 4; ++i)
#pragma unroll
      for (int r = 0; r < 4; ++r) part[i][r] += __shfl_xor(part[i][r], mask, 64);
  if (l16 == 0) {
#pragma unroll
    for (int i = 0; i < 4; ++i)
#pragma unroll
      for (int r = 0; r < 4; ++r) red[wn][i * 16 + quad * 4 + r] = part[i][r];
  }
  __syncthreads();
#pragma unroll
  for (int i = 0; i < 4; ++i) {
#pragma unroll
    for (int r = 0; r < 4; ++r) {
      int ml = i * 16 + quad * 4 + r;
      float tot = red[0][ml] + red[1][ml] + red[2][ml] + red[3][ml];
      float sc = rsqrtf(tot * (1.f / 256.f) + 1e-6f);
#pragma unroll
      for (int j = 0; j < 4; ++j) {
        int n = wn * 64 + j * 16 + l16;
        xb[(size_t)(bm + ml) * DO + n] = __float2bfloat16(acc[i][j][r] * sc * rnw[n]);
      }
    }
  }
}

// ---------------- launch ----------------

extern "C" void kernel_launch(void* const* d_in, const int* in_sizes, int n_in,
                              void* d_out, int out_size, void* d_ws, size_t ws_size,
                              hipStream_t stream) {
  const float* concept_out = (const float*)d_in[0];
  const float* encoder_out = (const float*)d_in[1];
  const float* bprobs      = (const float*)d_in[2];
  const int*   bidx        = (const int*)d_in[3];
  const float* gate_w      = (const float*)d_in[4];
  const float* gate_b      = (const float*)d_in[5];
  const float* down_w      = (const float*)d_in[6];
  const float* up_w        = (const float*)d_in[7];
  const float* norm_out_w  = (const float*)d_in[8];
  const float* rc_w        = (const float*)d_in[9];
  const float* rc_b        = (const float*)d_in[10];
  const float* wr_w        = (const float*)d_in[11];
  const float* wr_b        = (const float*)d_in[12];
  const float* wi_w        = (const float*)d_in[13];
  const float* wi_b        = (const float*)d_in[14];
  const float* log_a       = (const float*)d_in[15];
  const float* ow_w        = (const float*)d_in[16];
  const float* rn_w        = (const float*)d_in[17];
  float* out = (float*)d_out;
  (void)in_sizes; (void)n_in; (void)out_size; (void)ws_size;

  char* base = (char*)d_ws;
  size_t off = 0;
  auto alloc = [&](size_t bytes) -> char* {
    char* p = base + off;
    off += (bytes + 255) & ~(size_t)255;
    return p;
  };
  float* smoothed = (float*)alloc((size_t)NB * NM * DMODEL * 4);   // 8 MB
  int*   bucket   = (int*)alloc((size_t)BLR * 4);
  bf16*  gate_wb  = (bf16*)alloc((size_t)DMODEL * DMODEL * 2);
  bf16*  down_wb  = (bf16*)alloc((size_t)DO * DMODEL * 2);
  bf16*  up_wb    = (bf16*)alloc((size_t)DMODEL * DO * 2);
  bf16*  wrb      = (bf16*)alloc((size_t)3 * DO * DO * 2);
  bf16*  wib      = (bf16*)alloc((size_t)3 * DO * DO * 2);
  bf16*  owb      = (bf16*)alloc((size_t)3 * DO * DO * 2);
  float* e8       = (float*)alloc(3 * DO * 4);
  float2* ASsum   = (float2*)alloc((size_t)NB * NCH * DO * 8);     // 512 KB chunk summaries
  bf16*  xb       = (bf16*)alloc((size_t)BLR * DO * 2);            // 8 MB layer io

  // reused overlay region — offsets computed from actual buffer sizes
  const size_t SZ_ENC   = (size_t)BLR * DMODEL * 2;   // 32 MB
  const size_t SZ_XCONV = (size_t)BLR * DO * 2;       //  8 MB
  const size_t SZ_DS    = (size_t)BLR * DO * 4;       // 16 MB (packed uint32!)
  char* RA = alloc(2 * SZ_ENC);                       // 64 MB
  // head overlays
  bf16*  encb = (bf16*)RA;
  bf16*  h0b  = (bf16*)(RA + SZ_ENC);
  // layer overlays (xconvb | dsbuf | hsb disjoint: 8 + 16 + 8 = 32 MB)
  bf16*         xconvb = (bf16*)RA;
  unsigned int* dsbuf  = (unsigned int*)(RA + SZ_XCONV);
  bf16*         hsb    = (bf16*)(RA + SZ_XCONV + SZ_DS);
  // tail overlay
  bf16*  tmp2b  = (bf16*)RA;

  cvt4_kernel<<<(BLR * DMODEL / 4 + 255) / 256, 256, 0, stream>>>(
      (const float4*)encoder_out, (ushort4*)encb, BLR * DMODEL / 4);
  prep_kernel<<<(2163456 + 255) / 256, 256, 0, stream>>>(
      gate_w, down_w, up_w, wr_w, wi_w, ow_w, log_a,
      gate_wb, down_wb, up_wb, wrb, wib, owb, e8);
  ema_kernel<<<NB * 4, 256, 0, stream>>>(concept_out, bprobs, bidx, smoothed);
  bucket_kernel<<<BLR / 256, 256, 0, stream>>>(bidx, bucket);

  EpA ep;
  // G1: gate GEMM + fused gated residual + plugback -> h0 (bf16), 256^2 8-phase
  ep = EpA{};
  ep.outb = h0b; ep.bias = gate_b; ep.encb = encb; ep.p = bprobs;
  ep.bucket = bucket; ep.smoothed = smoothed;
  gemm256<1><<<dim3(BLR / 256, DMODEL / 256), 512, 0, stream>>>(encb, gate_wb, DMODEL, DMODEL, ep);
  // G2: down projection -> xb (bf16)  (N=256 -> keep 128^2 kernel for grid occupancy)
  ep = EpA{}; ep.outb = xb;
  gemm_bt<5><<<dim3(BLR / 128, DO / 128), 256, 0, stream>>>(h0b, down_wb, DO, DMODEL, ep);

  for (int k = 0; k < 3; ++k) {
    conv_kernel<<<BLR, 256, 0, stream>>>(xb, rc_w + k * DO * 4, rc_b + k * DO, xconvb);
    gemm_ri<<<dim3(BLR / 128, DO / 128), 256, 0, stream>>>(
        xconvb, wrb + k * DO * DO, wib + k * DO * DO,
        wr_b + k * DO, wi_b + k * DO, e8 + k * DO, dsbuf);
    scan_p1<<<NB * NCH, 256, 0, stream>>>(dsbuf, ASsum);
    scan_p2<<<NB * NCH, 256, 0, stream>>>(dsbuf, ASsum, hsb);
    gemm_on<<<BLR / 64, 256, 0, stream>>>(hsb, owb + k * DO * DO, rn_w + k * DO, xb);
  }

  // up projection -> tmp2 (bf16), 256^2 8-phase; final rmsnorm -> out (f32)
  ep = EpA{}; ep.outb = tmp2b;
  gemm256<5><<<dim3(BLR / 256, DMODEL / 256), 512, 0, stream>>>(xb, up_wb, DMODEL, DO, ep);
  rmsnorm1024_kernel<<<BLR, 256, 0, stream>>>(tmp2b, norm_out_w, out);
}

// Round 4
// 533.189 us; speedup vs baseline: 1.0024x; 1.0021x over previous
//
#include <hip/hip_runtime.h>
#include <hip/hip_bf16.h>
#include <stdint.h>

typedef __attribute__((ext_vector_type(8))) short short8;   // 8 bf16 (4 VGPRs)
typedef __attribute__((ext_vector_type(4))) float f32x4;    // 4 fp32 acc
typedef __hip_bfloat16 bf16;

#define NB   8
#define LSEQ 2048
#define NM   256
#define DMODEL 1024
#define DO   256
#define BLR  16384   /* NB*LSEQ rows */
#define NCH  32      /* scan chunks */
#define CLK  64      /* chunk length */

__device__ __forceinline__ float sigm(float x) { return 1.f / (1.f + __expf(-x)); }

__device__ __forceinline__ void gl_lds16(const void* g, void* l) {
  __builtin_amdgcn_global_load_lds((const __attribute__((address_space(1))) void*)g,
                                   (__attribute__((address_space(3))) void*)l, 16, 0, 0);
}

// inline-asm LDS read: invisible to compiler alias analysis (no auto vmcnt(0)
// drain vs in-flight global_load_lds). Caller MUST fence with lgkmcnt(0) +
// sched_barrier(0) before consuming the result (rule #18).
__device__ __forceinline__ short8 ds_read128(const bf16* p) {
  short8 r;
  unsigned a = (unsigned)(uintptr_t)(const __attribute__((address_space(3))) bf16*)p;
  asm volatile("ds_read_b128 %0, %1" : "=v"(r) : "v"(a));
  return r;
}

__device__ __forceinline__ unsigned short bf16bits(float v) {
  bf16 b = __float2bfloat16(v);
  return *(unsigned short*)&b;
}
__device__ __forceinline__ float bits2f(unsigned short u) {
  bf16 b = *(bf16*)&u;
  return __bfloat162float(b);
}

// ---------------- prep: all weight cvts + e8l2a in ONE dispatch ----------------

__global__ __launch_bounds__(256) void prep_kernel(
    const float* __restrict__ gate_w, const float* __restrict__ down_w,
    const float* __restrict__ up_w, const float* __restrict__ wr_w,
    const float* __restrict__ wi_w, const float* __restrict__ ow_w,
    const float* __restrict__ log_a,
    bf16* __restrict__ gate_wb, bf16* __restrict__ down_wb, bf16* __restrict__ up_wb,
    bf16* __restrict__ wrb, bf16* __restrict__ wib, bf16* __restrict__ owb,
    float* __restrict__ e8) {
  int i = blockIdx.x * 256 + threadIdx.x;
  if (i < 1048576) { gate_wb[i] = __float2bfloat16(gate_w[i]); return; }
  i -= 1048576;
  if (i < 262144) { down_wb[i] = __float2bfloat16(down_w[i]); return; }
  i -= 262144;
  if (i < 262144) { up_wb[i] = __float2bfloat16(up_w[i]); return; }
  i -= 262144;
  if (i < 196608) { wrb[i] = __float2bfloat16(wr_w[i]); return; }
  i -= 196608;
  if (i < 196608) { wib[i] = __float2bfloat16(wi_w[i]); return; }
  i -= 196608;
  if (i < 196608) { owb[i] = __float2bfloat16(ow_w[i]); return; }
  i -= 196608;
  if (i < 768) {
    float ab = 1.f / (1.f + expf(-log_a[i]));
    e8[i] = 8.f * log2f(ab);
  }
}

// vectorized f32 -> bf16 (4 elem/thread)
__global__ __launch_bounds__(256) void cvt4_kernel(const float4* __restrict__ in,
                                                   ushort4* __restrict__ out, int n4) {
  int i = blockIdx.x * 256 + threadIdx.x;
  if (i < n4) {
    float4 v = in[i];
    ushort4 o;
    o.x = bf16bits(v.x); o.y = bf16bits(v.y); o.z = bf16bits(v.z); o.w = bf16bits(v.w);
    out[i] = o;
  }
}

// ---------------- EMA + bucket ----------------

__global__ __launch_bounds__(256) void ema_kernel(const float* __restrict__ cpt,
                                                  const float* __restrict__ bprobs,
                                                  const int* __restrict__ bidx,
                                                  float* __restrict__ smoothed) {
  int b = blockIdx.x >> 2;
  int c = ((blockIdx.x & 3) << 8) + threadIdx.x;
  __shared__ float p[NM];
  p[threadIdx.x] = bprobs[b * LSEQ + bidx[b * NM + threadIdx.x]];
  __syncthreads();
  const float* cp = cpt + (size_t)b * NM * DMODEL + c;
  float* sp = smoothed + (size_t)b * NM * DMODEL + c;
  float h = 0.f;
  for (int m = 0; m < NM; ++m) {
    float pm = p[m];
    h = pm * cp[(size_t)m * DMODEL] + (1.f - pm) * h;
    sp[(size_t)m * DMODEL] = h;
  }
}

__global__ __launch_bounds__(256) void bucket_kernel(const int* __restrict__ bidx,
                                                     int* __restrict__ bucket) {
  int i = blockIdx.x * 256 + threadIdx.x;
  int b = i >> 11, l = i & 2047;
  const int* bi = bidx + b * NM;
  int lo = 0, hi = NM;
  while (lo < hi) {
    int mid = (lo + hi) >> 1;
    if (bi[mid] <= l) lo = mid + 1; else hi = mid;
  }
  int v = lo - 1;
  bucket[i] = v < 0 ? 0 : v;
}

// ---------------- depthwise causal conv k=4 ----------------

__global__ __launch_bounds__(256) void conv_kernel(const bf16* __restrict__ x,
                                                   const float* __restrict__ cw,
                                                   const float* __restrict__ cb,
                                                   bf16* __restrict__ xcb) {
  int i = blockIdx.x * 256 + threadIdx.x;
  int c = i & 255;
  int bl = i >> 8;
  int l = bl & 2047;
  float4 w4 = ((const float4*)cw)[c];
  const float* wf = (const float*)&w4;
  float s = cb[c];
#pragma unroll
  for (int kk = 0; kk < 4; ++kk) {
    int ll = l - 3 + kk;
    if (ll >= 0) s += wf[kk] * __bfloat162float(x[i + (kk - 3) * 256]);
  }
  xcb[i] = __float2bfloat16(s);
}

// ---------------- chunked scan, 2 dispatches, 256 blocks each ----------------
// input packed uint: lo16 = d = 1-a (bf16), hi16 = s (bf16). h = (1-d)*h + s.

__global__ __launch_bounds__(256) void scan_p1(const unsigned int* __restrict__ ds,
                                               float2* __restrict__ AS) {
  int b = blockIdx.x >> 5, ch = blockIdx.x & 31, c = threadIdx.x;
  size_t base = ((size_t)b * LSEQ + ch * CLK) * DO + c;
  float A = 1.f, S = 0.f;
  for (int t = 0; t < CLK; ++t) {
    unsigned int u = ds[base + (size_t)t * DO];
    float d = bits2f((unsigned short)(u & 0xffff));
    float s = bits2f((unsigned short)(u >> 16));
    float a = 1.f - d;
    A *= a;
    S = __builtin_fmaf(a, S, s);
  }
  AS[blockIdx.x * DO + c] = make_float2(A, S);
}

__global__ __launch_bounds__(256) void scan_p2(const unsigned int* __restrict__ ds,
                                               const float2* __restrict__ AS,
                                               bf16* __restrict__ hs) {
  int b = blockIdx.x >> 5, ch = blockIdx.x & 31, c = threadIdx.x;
  // prefix over earlier chunks of this batch (L2-hot, <=31 iterations)
  float h = 0.f;
  for (int j = 0; j < ch; ++j) {
    float2 as = AS[(b * NCH + j) * DO + c];
    h = __builtin_fmaf(as.x, h, as.y);
  }
  size_t base = ((size_t)b * LSEQ + ch * CLK) * DO + c;
  for (int t = 0; t < CLK; ++t) {
    unsigned int u = ds[base + (size_t)t * DO];
    float d = bits2f((unsigned short)(u & 0xffff));
    float s = bits2f((unsigned short)(u >> 16));
    h = __builtin_fmaf(-d, h, h) + s;   // (1-d)*h + s
    hs[base + (size_t)t * DO] = __float2bfloat16(h);
  }
}

// ---------------- final rmsnorm over 1024, bf16 in -> f32 out ----------------

__global__ __launch_bounds__(256) void rmsnorm1024_kernel(const bf16* __restrict__ in,
                                                          const float* __restrict__ w,
                                                          float* __restrict__ out) {
  int row = blockIdx.x, t = threadIdx.x;
  ushort4 raw = ((const ushort4*)(in + (size_t)row * 1024))[t];
  float v0 = bits2f(raw.x), v1 = bits2f(raw.y), v2 = bits2f(raw.z), v3 = bits2f(raw.w);
  float ss = v0 * v0 + v1 * v1 + v2 * v2 + v3 * v3;
#pragma unroll
  for (int ofs = 32; ofs > 0; ofs >>= 1) ss += __shfl_down(ss, ofs, 64);
  __shared__ float wsum[4];
  if ((t & 63) == 0) wsum[t >> 6] = ss;
  __syncthreads();
  float tot = wsum[0] + wsum[1] + wsum[2] + wsum[3];
  float sc = rsqrtf(tot * (1.f / 1024.f) + 1e-6f);
  float4 wv = ((const float4*)w)[t];
  float4 o;
  o.x = v0 * sc * wv.x; o.y = v1 * sc * wv.y;
  o.z = v2 * sc * wv.z; o.w = v3 * sc * wv.w;
  ((float4*)(out + (size_t)row * 1024))[t] = o;
}

// ---------------- epilogue arg pack ----------------

struct EpA {
  bf16* outb;
  const float* bias;
  const bf16* encb;
  const float* p;
  const int* bucket;
  const float* smoothed;
};

// ---------------- generic MFMA GEMM 128x128, 2-phase (control: C++ LDS reads) ----

template <int EP, int NC, int KC>
__global__ __launch_bounds__(256) void gemm_bt(const bf16* __restrict__ A,
                                               const bf16* __restrict__ W, EpA ep) {
  __shared__ __align__(16) bf16 As[128 * 64];
  __shared__ __align__(16) bf16 Bs[128 * 64];
  const int t = threadIdx.x;
  const int lane = t & 63;
  const int wv = t >> 6;
  const int wm = wv >> 1, wn = wv & 1;
  const int quad = lane >> 4, l16 = lane & 15;
  const int bm = blockIdx.x << 7, bn = blockIdx.y << 7;

  f32x4 acc[4][4] = {};

  for (int k0 = 0; k0 < KC; k0 += 64) {
    __syncthreads();
#pragma unroll
    for (int i = 0; i < 4; ++i) {
      int slot = i * 256 + t;
      int m = slot >> 3;
      int lk8 = (slot & 7) ^ (m & 7);
      gl_lds16(A + (size_t)(bm + m) * KC + k0 + lk8 * 8, As + slot * 8);
      gl_lds16(W + (size_t)(bn + m) * KC + k0 + lk8 * 8, Bs + slot * 8);
    }
    __syncthreads();
#pragma unroll
    for (int ks = 0; ks < 2; ++ks) {
      short8 af[4], bfr[4];
#pragma unroll
      for (int i = 0; i < 4; ++i) {
        int m = wm * 64 + i * 16 + l16;
        int pa = (ks * 4 + quad) ^ (m & 7);
        af[i] = *(const short8*)(As + m * 64 + pa * 8);
        int n = wn * 64 + i * 16 + l16;
        int pb = (ks * 4 + quad) ^ (n & 7);
        bfr[i] = *(const short8*)(Bs + n * 64 + pb * 8);
      }
#pragma unroll
      for (int i = 0; i < 4; ++i)
#pragma unroll
        for (int j = 0; j < 4; ++j)
          acc[i][j] = __builtin_amdgcn_mfma_f32_16x16x32_bf16(af[i], bfr[j], acc[i][j], 0, 0, 0);
    }
  }

#pragma unroll
  for (int i = 0; i < 4; ++i) {
#pragma unroll
    for (int j = 0; j < 4; ++j) {
#pragma unroll
      for (int r = 0; r < 4; ++r) {
        int m = bm + wm * 64 + i * 16 + quad * 4 + r;
        int n = bn + wn * 64 + j * 16 + l16;
        size_t idx = (size_t)m * NC + n;
        float v = acc[i][j][r];
        if (EP == 1) {         // gate + plugback (NC == DMODEL)
          float g = sigm(v + ep.bias[n]);
          float pm = ep.p[m];
          int bb = m >> 11;
          float sm = ep.smoothed[((size_t)(bb * NM + ep.bucket[m])) * DMODEL + n];
          float e = __bfloat162float(ep.encb[idx]);
          ep.outb[idx] = __float2bfloat16((1.f - pm) * g * e + sm);
        } else {               // EP == 5: plain bf16 out
          ep.outb[idx] = __float2bfloat16(v);
        }
      }
    }
  }
}

// ---------------- 256x256 8-phase GEMM (T2+T3+T4+T5), N = DMODEL ----------------
// 8 waves (2M x 4N), BK=64, LDS = 2 dbuf x {A,B} x 2 half-tiles of [128][64] bf16.
// LDS fragment reads are inline-asm ds_read_b128 so the compiler cannot insert
// conservative vmcnt(0) drains against in-flight global_load_lds (alias theory).
// Fencing per rule #18: lgkmcnt(0) + sched_barrier(0) before each MFMA cluster.

template <int EP, int KC>
__global__ __launch_bounds__(512, 2) void gemm256(const bf16* __restrict__ Ag,
                                                  const bf16* __restrict__ W, EpA ep) {
  __shared__ __align__(16) bf16 lds[2][4][128 * 64];   // [buf][A0,A1,B0,B1][...]
  const int t = threadIdx.x;
  const int lane = t & 63;
  const int wv = t >> 6;
  const int wm = wv >> 2, wn = wv & 3;
  const int quad = lane >> 4, l16 = lane & 15;
  const int bm = blockIdx.x << 8, bn = blockIdx.y << 8;
  constexpr int KT = KC >> 6;   // # 64-wide k-tiles (power of 2, >= 4)
  constexpr int KM = KT - 1;

  const int rr = t >> 3;                 // 0..63 staging row (q=0); q=1 adds +128 global
  const int cc = (t & 7) ^ (rr & 7);     // pre-swizzled source chunk

  f32x4 acc[8][4] = {};
  short8 af[4][2], bfr[2][2];

#define STAGE_A(BUF, H, KTI)                                                      \
  {                                                                               \
    int kk = ((KTI) & KM) << 6;                                                   \
    const bf16* s0 = Ag + (size_t)(bm + (H) * 64 + rr) * KC + kk + cc * 8;        \
    gl_lds16(s0, &lds[BUF][H][t * 8]);                                            \
    const bf16* s1 = Ag + (size_t)(bm + (H) * 64 + rr + 128) * KC + kk + cc * 8;  \
    gl_lds16(s1, &lds[BUF][H][(512 + t) * 8]);                                    \
  }
#define STAGE_B(BUF, H, KTI)                                                      \
  {                                                                               \
    int kk = ((KTI) & KM) << 6;                                                   \
    int n0 = (H) * 32 + (rr & 31) + ((rr >> 5) << 6);                             \
    const bf16* s0 = W + (size_t)(bn + n0) * KC + kk + cc * 8;                    \
    gl_lds16(s0, &lds[BUF][2 + (H)][t * 8]);                                      \
    const bf16* s1 = W + (size_t)(bn + n0 + 128) * KC + kk + cc * 8;              \
    gl_lds16(s1, &lds[BUF][2 + (H)][(512 + t) * 8]);                              \
  }
#define LD_A(BUF, MG)                                                             \
  _Pragma("unroll") for (int ii = 0; ii < 4; ++ii) {                              \
    int r = wm * 64 + ii * 16 + l16;                                              \
    _Pragma("unroll") for (int ks = 0; ks < 2; ++ks) {                            \
      int ch = (ks * 4 + quad) ^ (r & 7);                                         \
      af[ii][ks] = ds_read128(&lds[BUF][MG][(r * 8 + ch) * 8]);                   \
    }                                                                             \
  }
#define LD_B(BUF, NG)                                                             \
  _Pragma("unroll") for (int jj = 0; jj < 2; ++jj) {                              \
    int r = wn * 32 + jj * 16 + l16;                                              \
    _Pragma("unroll") for (int ks = 0; ks < 2; ++ks) {                            \
      int ch = (ks * 4 + quad) ^ (r & 7);                                         \
      bfr[jj][ks] = ds_read128(&lds[BUF][2 + (NG)][(r * 8 + ch) * 8]);            \
    }                                                                             \
  }
#define MMA(MG, NG)                                                               \
  _Pragma("unroll") for (int ks = 0; ks < 2; ++ks)                                \
  _Pragma("unroll") for (int ii = 0; ii < 4; ++ii)                                \
  _Pragma("unroll") for (int jj = 0; jj < 2; ++jj)                                \
    acc[(MG) * 4 + ii][(NG) * 2 + jj] = __builtin_amdgcn_mfma_f32_16x16x32_bf16(  \
        af[ii][ks], bfr[jj][ks], acc[(MG) * 4 + ii][(NG) * 2 + jj], 0, 0, 0);
#define BARR __builtin_amdgcn_s_barrier()
#define WAIT_LGKM asm volatile("s_waitcnt lgkmcnt(0)" ::: "memory")
#define WAIT_VM6 asm volatile("s_waitcnt vmcnt(6)" ::: "memory")
#define SBAR __builtin_amdgcn_sched_barrier(0)
#define PH(MG, NG)                   \
  BARR; WAIT_LGKM; SBAR;             \
  __builtin_amdgcn_s_setprio(1);     \
  MMA(MG, NG);                       \
  __builtin_amdgcn_s_setprio(0);     \
  SBAR;                              \
  BARR;
#define PH_V(MG, NG)                 \
  BARR; WAIT_LGKM; SBAR;             \
  __builtin_amdgcn_s_setprio(1);     \
  MMA(MG, NG);                       \
  __builtin_amdgcn_s_setprio(0);     \
  SBAR;                              \
  WAIT_VM6;                          \
  BARR;

  // prologue: buf0 <- kt0 complete; buf1 <- kt1 {A0, A1, B1} (B0 staged at g1)
  STAGE_A(0, 0, 0) STAGE_A(0, 1, 0) STAGE_B(0, 0, 0) STAGE_B(0, 1, 0)
  STAGE_A(1, 0, 1) STAGE_A(1, 1, 1) STAGE_B(1, 1, 1)
  WAIT_VM6;   // buf0's 8 loads (oldest) complete; buf1's 6 stay in flight
  BARR;

#pragma unroll 1
  for (int it = 0; it < (KT >> 1); ++it) {
    const int kt = it * 2;
    // g1: quad (0,0) of buf0; stage buf1.B0 <- kt+1 (slot dead since prev g8)
    LD_A(0, 0) LD_B(0, 0)
    STAGE_B(1, 0, kt + 1)
    PH(0, 0)
    // g2: (0,1); stage buf0.A0 <- kt+2 (A0 last read g1)
    LD_B(0, 1)
    STAGE_A(0, 0, kt + 2)
    PH(0, 1)
    // g3: (1,1); stage buf0.B1 <- kt+2 (B1 last read g2)
    LD_A(0, 1)
    STAGE_B(0, 1, kt + 2)
    PH(1, 1)
    // g4: (1,0) re-reads B0; stage buf0.A1 <- kt+2 (A1 last read g3);
    //     vmcnt(6): retires buf1(kt+1)'s 8, leaves buf0(kt+2)'s 6 in flight
    LD_B(0, 0)
    STAGE_A(0, 1, kt + 2)
    PH_V(1, 0)
    // g5: quad (0,0) of buf1; stage buf0.B0 <- kt+2 (B0 last read g4)
    LD_A(1, 0) LD_B(1, 0)
    STAGE_B(0, 0, kt + 2)
    PH(0, 0)
    // g6: (0,1); stage buf1.A0 <- kt+3 (A0 last read g5)
    LD_B(1, 1)
    STAGE_A(1, 0, kt + 3)
    PH(0, 1)
    // g7: (1,1); stage buf1.B1 <- kt+3 (B1 last read g6)
    LD_A(1, 1)
    STAGE_B(1, 1, kt + 3)
    PH(1, 1)
    // g8: (1,0); stage buf1.A1 <- kt+3 (A1 last read g7);
    //     vmcnt(6): retires buf0(kt+2)'s 8, leaves buf1(kt+3)'s 6 in flight
    LD_B(1, 0)
    STAGE_A(1, 1, kt + 3)
    PH_V(1, 0)
  }

#undef STAGE_A
#undef STAGE_B
#undef LD_A
#undef LD_B
#undef MMA
#undef BARR
#undef WAIT_LGKM
#undef WAIT_VM6
#undef SBAR
#undef PH
#undef PH_V

#pragma unroll
  for (int i = 0; i < 8; ++i) {
#pragma unroll
    for (int j = 0; j < 4; ++j) {
#pragma unroll
      for (int r = 0; r < 4; ++r) {
        int m = bm + wm * 128 + i * 16 + quad * 4 + r;
        int n = bn + wn * 64 + j * 16 + l16;
        size_t idx = (size_t)m * DMODEL + n;
        float v = acc[i][j][r];
        if (EP == 1) {         // gate + plugback
          float g = sigm(v + ep.bias[n]);
          float pm = ep.p[m];
          int bb = m >> 11;
          float sm = ep.smoothed[((size_t)(bb * NM + ep.bucket[m])) * DMODEL + n];
          float e = __bfloat162float(ep.encb[idx]);
          ep.outb[idx] = __float2bfloat16((1.f - pm) * g * e + sm);
        } else {               // EP == 5: plain bf16 out
          ep.outb[idx] = __float2bfloat16(v);
        }
      }
    }
  }
}

// ---------------- dual GEMM: r & i heads share A, fused a_t/s_t epilogue ----------------
// A = xconv bf16 [BLR,256]; Wr,Wi [256,256]. Writes packed uint{d=1-a bf16, s bf16}.

__global__ __launch_bounds__(256) void gemm_ri(const bf16* __restrict__ A,
                                               const bf16* __restrict__ Wr,
                                               const bf16* __restrict__ Wi,
                                               const float* __restrict__ rbias,
                                               const float* __restrict__ ibias,
                                               const float* __restrict__ e8,
                                               unsigned int* __restrict__ ds_out) {
  __shared__ __align__(16) bf16 As[128 * 64];
  __shared__ __align__(16) bf16 Br[128 * 64];
  __shared__ __align__(16) bf16 Bi[128 * 64];
  const int t = threadIdx.x;
  const int lane = t & 63;
  const int wv = t >> 6;
  const int wm = wv >> 1, wn = wv & 1;
  const int quad = lane >> 4, l16 = lane & 15;
  const int bm = blockIdx.x << 7, bn = blockIdx.y << 7;

  f32x4 ar[4][4] = {};
  f32x4 ai[4][4] = {};

  for (int k0 = 0; k0 < DO; k0 += 64) {
    __syncthreads();
#pragma unroll
    for (int i = 0; i < 4; ++i) {
      int slot = i * 256 + t;
      int m = slot >> 3;
      int lk8 = (slot & 7) ^ (m & 7);
      gl_lds16(A + (size_t)(bm + m) * DO + k0 + lk8 * 8, As + slot * 8);
      gl_lds16(Wr + (size_t)(bn + m) * DO + k0 + lk8 * 8, Br + slot * 8);
      gl_lds16(Wi + (size_t)(bn + m) * DO + k0 + lk8 * 8, Bi + slot * 8);
    }
    __syncthreads();
#pragma unroll
    for (int ks = 0; ks < 2; ++ks) {
      short8 af[4], br[4], bi[4];
#pragma unroll
      for (int i = 0; i < 4; ++i) {
        int m = wm * 64 + i * 16 + l16;
        int pa = (ks * 4 + quad) ^ (m & 7);
        af[i] = *(const short8*)(As + m * 64 + pa * 8);
        int n = wn * 64 + i * 16 + l16;
        int pb = (ks * 4 + quad) ^ (n & 7);
        br[i] = *(const short8*)(Br + n * 64 + pb * 8);
        bi[i] = *(const short8*)(Bi + n * 64 + pb * 8);
      }
#pragma unroll
      for (int i = 0; i < 4; ++i)
#pragma unroll
        for (int j = 0; j < 4; ++j) {
          ar[i][j] = __builtin_amdgcn_mfma_f32_16x16x32_bf16(af[i], br[j], ar[i][j], 0, 0, 0);
          ai[i][j] = __builtin_amdgcn_mfma_f32_16x16x32_bf16(af[i], bi[j], ai[i][j], 0, 0, 0);
        }
    }
  }

#pragma unroll
  for (int i = 0; i < 4; ++i) {
#pragma unroll
    for (int j = 0; j < 4; ++j) {
#pragma unroll
      for (int r = 0; r < 4; ++r) {
        int m = bm + wm * 64 + i * 16 + quad * 4 + r;
        int n = bn + wn * 64 + j * 16 + l16;
        size_t idx = (size_t)m * DO + n;
        float rv = sigm(ar[i][j][r] + rbias[n]);
        float a = exp2f(rv * e8[n]);
        float d = 1.f - a;                               // ~5e-3, bf16-safe
        float iv = sigm(ai[i][j][r] + ibias[n]);
        float xc = __bfloat162float(A[idx]);             // xconv[m][n] == A[m][n]
        float s = sqrtf(fmaxf(1.f - a * a, 0.f)) * iv * xc;
        ds_out[idx] = (unsigned int)bf16bits(d) | ((unsigned int)bf16bits(s) << 16);
      }
    }
  }
}

// ---------------- out-proj GEMM tile 64x256 + fused RMSNorm(256) ----------------

__global__ __launch_bounds__(256) void gemm_on(const bf16* __restrict__ A,   // hs [BLR,256]
                                               const bf16* __restrict__ W,   // ow [256,256]
                                               const float* __restrict__ rnw,
                                               bf16* __restrict__ xb) {
  __shared__ __align__(16) bf16 As[64 * 64];
  __shared__ __align__(16) bf16 Bs[256 * 64];
  __shared__ float red[4][64];
  const int t = threadIdx.x;
  const int lane = t & 63;
  const int wn = t >> 6;           // wave = column slice of 64
  const int quad = lane >> 4, l16 = lane & 15;
  const int bm = blockIdx.x << 6;

  f32x4 acc[4][4] = {};

  for (int k0 = 0; k0 < DO; k0 += 64) {
    __syncthreads();
#pragma unroll
    for (int i = 0; i < 2; ++i) {
      int slot = i * 256 + t;
      int m = slot >> 3;
      int lk8 = (slot & 7) ^ (m & 7);
      gl_lds16(A + (size_t)(bm + m) * DO + k0 + lk8 * 8, As + slot * 8);
    }
#pragma unroll
    for (int i = 0; i < 8; ++i) {
      int slot = i * 256 + t;
      int n = slot >> 3;
      int lk8 = (slot & 7) ^ (n & 7);
      gl_lds16(W + (size_t)n * DO + k0 + lk8 * 8, Bs + slot * 8);
    }
    __syncthreads();
#pragma unroll
    for (int ks = 0; ks < 2; ++ks) {
      short8 af[4], bfr[4];
#pragma unroll
      for (int i = 0; i < 4; ++i) {
        int m = i * 16 + l16;
        int pa = (ks * 4 + quad) ^ (m & 7);
        af[i] = *(const short8*)(As + m * 64 + pa * 8);
        int n = wn * 64 + i * 16 + l16;
        int pb = (ks * 4 + quad) ^ (n & 7);
        bfr[i] = *(const short8*)(Bs + n * 64 + pb * 8);
      }
#pragma unroll
      for (int i = 0; i < 4; ++i)
#pragma unroll
        for (int j = 0; j < 4; ++j)
          acc[i][j] = __builtin_amdgcn_mfma_f32_16x16x32_bf16(af[i], bfr[j], acc[i][j], 0, 0, 0);
    }
  }

  float part[4][4];
#pragma unroll
  for (int i = 0; i < 4; ++i)
#pragma unroll
    for (int r = 0; r < 4; ++r) {
      float s = 0.f;
#pragma unroll
      for (int j = 0; j < 4; ++j) s += acc[i][j][r] * acc[i][j][r];
      part[i][r] = s;
    }
#pragma unroll
  for (int mask = 1; mask <= 8; mask <<= 1)
#pragma unroll
    for (int i = 0; i < 4; ++i)
#pragma unroll
      for (int r = 0; r < 4; ++r) part[i][r] += __shfl_xor(part[i][r], mask, 64);
  if (l16 == 0) {
#pragma unroll
    for (int i = 0; i < 4; ++i)
#pragma unroll
      for (int r = 0; r < 4; ++r) red[wn][i * 16 + quad * 4 + r] = part[i][r];
  }
  __syncthreads();
#pragma unroll
  for (int i = 0; i < 4; ++i) {
#pragma unroll
    for (int r = 0; r < 4; ++r) {
      int ml = i * 16 + quad * 4 + r;
      float tot = red[0][ml] + red[1][ml] + red[2][ml] + red[3][ml];
      float sc = rsqrtf(tot * (1.f / 256.f) + 1e-6f);
#pragma unroll
      for (int j = 0; j < 4; ++j) {
        int n = wn * 64 + j * 16 + l16;
        xb[(size_t)(bm + ml) * DO + n] = __float2bfloat16(acc[i][j][r] * sc * rnw[n]);
      }
    }
  }
}

// ---------------- launch ----------------

extern "C" void kernel_launch(void* const* d_in, const int* in_sizes, int n_in,
                              void* d_out, int out_size, void* d_ws, size_t ws_size,
                              hipStream_t stream) {
  const float* concept_out = (const float*)d_in[0];
  const float* encoder_out = (const float*)d_in[1];
  const float* bprobs      = (const float*)d_in[2];
  const int*   bidx        = (const int*)d_in[3];
  const float* gate_w      = (const float*)d_in[4];
  const float* gate_b      = (const float*)d_in[5];
  const float* down_w      = (const float*)d_in[6];
  const float* up_w        = (const float*)d_in[7];
  const float* norm_out_w  = (const float*)d_in[8];
  const float* rc_w        = (const float*)d_in[9];
  const float* rc_b        = (const float*)d_in[10];
  const float* wr_w        = (const float*)d_in[11];
  const float* wr_b        = (const float*)d_in[12];
  const float* wi_w        = (const float*)d_in[13];
  const float* wi_b        = (const float*)d_in[14];
  const float* log_a       = (const float*)d_in[15];
  const float* ow_w        = (const float*)d_in[16];
  const float* rn_w        = (const float*)d_in[17];
  float* out = (float*)d_out;
  (void)in_sizes; (void)n_in; (void)out_size; (void)ws_size;

  char* base = (char*)d_ws;
  size_t off = 0;
  auto alloc = [&](size_t bytes) -> char* {
    char* p = base + off;
    off += (bytes + 255) & ~(size_t)255;
    return p;
  };
  float* smoothed = (float*)alloc((size_t)NB * NM * DMODEL * 4);   // 8 MB
  int*   bucket   = (int*)alloc((size_t)BLR * 4);
  bf16*  gate_wb  = (bf16*)alloc((size_t)DMODEL * DMODEL * 2);
  bf16*  down_wb  = (bf16*)alloc((size_t)DO * DMODEL * 2);
  bf16*  up_wb    = (bf16*)alloc((size_t)DMODEL * DO * 2);
  bf16*  wrb      = (bf16*)alloc((size_t)3 * DO * DO * 2);
  bf16*  wib      = (bf16*)alloc((size_t)3 * DO * DO * 2);
  bf16*  owb      = (bf16*)alloc((size_t)3 * DO * DO * 2);
  float* e8       = (float*)alloc(3 * DO * 4);
  float2* ASsum   = (float2*)alloc((size_t)NB * NCH * DO * 8);     // 512 KB chunk summaries
  bf16*  xb       = (bf16*)alloc((size_t)BLR * DO * 2);            // 8 MB layer io

  // reused overlay region — offsets computed from actual buffer sizes
  const size_t SZ_ENC   = (size_t)BLR * DMODEL * 2;   // 32 MB
  const size_t SZ_XCONV = (size_t)BLR * DO * 2;       //  8 MB
  const size_t SZ_DS    = (size_t)BLR * DO * 4;       // 16 MB (packed uint32!)
  char* RA = alloc(2 * SZ_ENC);                       // 64 MB
  // head overlays
  bf16*  encb = (bf16*)RA;
  bf16*  h0b  = (bf16*)(RA + SZ_ENC);
  // layer overlays (xconvb | dsbuf | hsb disjoint: 8 + 16 + 8 = 32 MB)
  bf16*         xconvb = (bf16*)RA;
  unsigned int* dsbuf  = (unsigned int*)(RA + SZ_XCONV);
  bf16*         hsb    = (bf16*)(RA + SZ_XCONV + SZ_DS);
  // tail overlay
  bf16*  tmp2b  = (bf16*)RA;

  cvt4_kernel<<<(BLR * DMODEL / 4 + 255) / 256, 256, 0, stream>>>(
      (const float4*)encoder_out, (ushort4*)encb, BLR * DMODEL / 4);
  prep_kernel<<<(2163456 + 255) / 256, 256, 0, stream>>>(
      gate_w, down_w, up_w, wr_w, wi_w, ow_w, log_a,
      gate_wb, down_wb, up_wb, wrb, wib, owb, e8);
  ema_kernel<<<NB * 4, 256, 0, stream>>>(concept_out, bprobs, bidx, smoothed);
  bucket_kernel<<<BLR / 256, 256, 0, stream>>>(bidx, bucket);

  EpA ep;
  // G1: gate GEMM + fused gated residual + plugback -> h0 (bf16), 256^2 8-phase
  ep = EpA{};
  ep.outb = h0b; ep.bias = gate_b; ep.encb = encb; ep.p = bprobs;
  ep.bucket = bucket; ep.smoothed = smoothed;
  gemm256<1, DMODEL><<<dim3(BLR / 256, DMODEL / 256), 512, 0, stream>>>(encb, gate_wb, ep);
  // G2: down projection -> xb (bf16)  (N=256 -> keep 128^2 kernel; C++ LDS-read control)
  ep = EpA{}; ep.outb = xb;
  gemm_bt<5, DO, DMODEL><<<dim3(BLR / 128, DO / 128), 256, 0, stream>>>(h0b, down_wb, ep);

  for (int k = 0; k < 3; ++k) {
    conv_kernel<<<BLR, 256, 0, stream>>>(xb, rc_w + k * DO * 4, rc_b + k * DO, xconvb);
    gemm_ri<<<dim3(BLR / 128, DO / 128), 256, 0, stream>>>(
        xconvb, wrb + k * DO * DO, wib + k * DO * DO,
        wr_b + k * DO, wi_b + k * DO, e8 + k * DO, dsbuf);
    scan_p1<<<NB * NCH, 256, 0, stream>>>(dsbuf, ASsum);
    scan_p2<<<NB * NCH, 256, 0, stream>>>(dsbuf, ASsum, hsb);
    gemm_on<<<BLR / 64, 256, 0, stream>>>(hsb, owb + k * DO * DO, rn_w + k * DO, xb);
  }

  // up projection -> tmp2 (bf16), 256^2 8-phase; final rmsnorm -> out (f32)
  ep = EpA{}; ep.outb = tmp2b;
  gemm256<5, DO><<<dim3(BLR / 256, DMODEL / 256), 512, 0, stream>>>(xb, up_wb, ep);
  rmsnorm1024_kernel<<<BLR, 256, 0, stream>>>(tmp2b, norm_out_w, out);
}

// Round 5
// 517.670 us; speedup vs baseline: 1.0324x; 1.0300x over previous
//
#include <hip/hip_runtime.h>
#include <hip/hip_bf16.h>
#include <stdint.h>

typedef __attribute__((ext_vector_type(8))) short short8;   // 8 bf16 (4 VGPRs)
typedef __attribute__((ext_vector_type(4))) float f32x4;    // 4 fp32 acc
typedef __hip_bfloat16 bf16;

#define NB   8
#define LSEQ 2048
#define NM   256
#define DMODEL 1024
#define DO   256
#define BLR  16384   /* NB*LSEQ rows */
#define NCH  32      /* scan chunks */
#define CLK  64      /* chunk length */

__device__ __forceinline__ float sigm(float x) { return 1.f / (1.f + __expf(-x)); }

__device__ __forceinline__ void gl_lds16(const void* g, void* l) {
  __builtin_amdgcn_global_load_lds((const __attribute__((address_space(1))) void*)g,
                                   (__attribute__((address_space(3))) void*)l, 16, 0, 0);
}

// inline-asm LDS read: invisible to compiler alias analysis (no auto vmcnt(0)
// drain vs in-flight global_load_lds). Fenced by lgkmcnt(0)+sched_barrier(0).
__device__ __forceinline__ short8 ds_read128(const bf16* p) {
  short8 r;
  unsigned a = (unsigned)(uintptr_t)(const __attribute__((address_space(3))) bf16*)p;
  asm volatile("ds_read_b128 %0, %1" : "=v"(r) : "v"(a));
  return r;
}

__device__ __forceinline__ unsigned short bf16bits(float v) {
  bf16 b = __float2bfloat16(v);
  return *(unsigned short*)&b;
}
__device__ __forceinline__ float bits2f(unsigned short u) {
  bf16 b = *(bf16*)&u;
  return __bfloat162float(b);
}

// ---------------- prep: all weight cvts + e8l2a in ONE dispatch ----------------

__global__ __launch_bounds__(256) void prep_kernel(
    const float* __restrict__ gate_w, const float* __restrict__ down_w,
    const float* __restrict__ up_w, const float* __restrict__ wr_w,
    const float* __restrict__ wi_w, const float* __restrict__ ow_w,
    const float* __restrict__ log_a,
    bf16* __restrict__ gate_wb, bf16* __restrict__ down_wb, bf16* __restrict__ up_wb,
    bf16* __restrict__ wrb, bf16* __restrict__ wib, bf16* __restrict__ owb,
    float* __restrict__ e8) {
  int i = blockIdx.x * 256 + threadIdx.x;
  if (i < 1048576) { gate_wb[i] = __float2bfloat16(gate_w[i]); return; }
  i -= 1048576;
  if (i < 262144) { down_wb[i] = __float2bfloat16(down_w[i]); return; }
  i -= 262144;
  if (i < 262144) { up_wb[i] = __float2bfloat16(up_w[i]); return; }
  i -= 262144;
  if (i < 196608) { wrb[i] = __float2bfloat16(wr_w[i]); return; }
  i -= 196608;
  if (i < 196608) { wib[i] = __float2bfloat16(wi_w[i]); return; }
  i -= 196608;
  if (i < 196608) { owb[i] = __float2bfloat16(ow_w[i]); return; }
  i -= 196608;
  if (i < 768) {
    float ab = 1.f / (1.f + expf(-log_a[i]));
    e8[i] = 8.f * log2f(ab);
  }
}

// vectorized f32 -> bf16 (4 elem/thread)
__global__ __launch_bounds__(256) void cvt4_kernel(const float4* __restrict__ in,
                                                   ushort4* __restrict__ out, int n4) {
  int i = blockIdx.x * 256 + threadIdx.x;
  if (i < n4) {
    float4 v = in[i];
    ushort4 o;
    o.x = bf16bits(v.x); o.y = bf16bits(v.y); o.z = bf16bits(v.z); o.w = bf16bits(v.w);
    out[i] = o;
  }
}

// ---------------- EMA + bucket ----------------

__global__ __launch_bounds__(256) void ema_kernel(const float* __restrict__ cpt,
                                                  const float* __restrict__ bprobs,
                                                  const int* __restrict__ bidx,
                                                  float* __restrict__ smoothed) {
  int b = blockIdx.x >> 2;
  int c = ((blockIdx.x & 3) << 8) + threadIdx.x;
  __shared__ float p[NM];
  p[threadIdx.x] = bprobs[b * LSEQ + bidx[b * NM + threadIdx.x]];
  __syncthreads();
  const float* cp = cpt + (size_t)b * NM * DMODEL + c;
  float* sp = smoothed + (size_t)b * NM * DMODEL + c;
  float h = 0.f;
  for (int m = 0; m < NM; ++m) {
    float pm = p[m];
    h = pm * cp[(size_t)m * DMODEL] + (1.f - pm) * h;
    sp[(size_t)m * DMODEL] = h;
  }
}

__global__ __launch_bounds__(256) void bucket_kernel(const int* __restrict__ bidx,
                                                     int* __restrict__ bucket) {
  int i = blockIdx.x * 256 + threadIdx.x;
  int b = i >> 11, l = i & 2047;
  const int* bi = bidx + b * NM;
  int lo = 0, hi = NM;
  while (lo < hi) {
    int mid = (lo + hi) >> 1;
    if (bi[mid] <= l) lo = mid + 1; else hi = mid;
  }
  int v = lo - 1;
  bucket[i] = v < 0 ? 0 : v;
}

// ---------------- gate + plugback elementwise (split from G1 epilogue) ----------
// h0 holds raw gemm logits (bf16); transformed IN PLACE:
// h0[m][n] = (1-p[m]) * sigm(h0[m][n] + gb[n]) * enc[m][n] + smoothed[b][bucket[m]][n]

__global__ __launch_bounds__(256) void gate_plug_kernel(bf16* __restrict__ h0,
                                                        const bf16* __restrict__ encb,
                                                        const float* __restrict__ gbias,
                                                        const float* __restrict__ bprobs,
                                                        const int* __restrict__ bucket,
                                                        const float* __restrict__ smoothed) {
  const int m = blockIdx.x;
  const int t = threadIdx.x;
  const int b = m >> 11;
  const float pm1 = 1.f - bprobs[m];
  const float* srow = smoothed + ((size_t)(b * NM + bucket[m])) * DMODEL + t * 4;
  const size_t base = (size_t)m * DMODEL + t * 4;
  ushort4 gr = *(const ushort4*)(h0 + base);
  ushort4 er = *(const ushort4*)(encb + base);
  float4 sm4 = *(const float4*)srow;
  float4 gb4 = *(const float4*)(gbias + t * 4);
  ushort4 o;
  o.x = bf16bits(pm1 * sigm(bits2f(gr.x) + gb4.x) * bits2f(er.x) + sm4.x);
  o.y = bf16bits(pm1 * sigm(bits2f(gr.y) + gb4.y) * bits2f(er.y) + sm4.y);
  o.z = bf16bits(pm1 * sigm(bits2f(gr.z) + gb4.z) * bits2f(er.z) + sm4.z);
  o.w = bf16bits(pm1 * sigm(bits2f(gr.w) + gb4.w) * bits2f(er.w) + sm4.w);
  *(ushort4*)(h0 + base) = o;
}

// ---------------- depthwise causal conv k=4 ----------------

__global__ __launch_bounds__(256) void conv_kernel(const bf16* __restrict__ x,
                                                   const float* __restrict__ cw,
                                                   const float* __restrict__ cb,
                                                   bf16* __restrict__ xcb) {
  int i = blockIdx.x * 256 + threadIdx.x;
  int c = i & 255;
  int bl = i >> 8;
  int l = bl & 2047;
  float4 w4 = ((const float4*)cw)[c];
  const float* wf = (const float*)&w4;
  float s = cb[c];
#pragma unroll
  for (int kk = 0; kk < 4; ++kk) {
    int ll = l - 3 + kk;
    if (ll >= 0) s += wf[kk] * __bfloat162float(x[i + (kk - 3) * 256]);
  }
  xcb[i] = __float2bfloat16(s);
}

// ---------------- chunked scan, 2 dispatches, 256 blocks each ----------------
// input packed uint: lo16 = d = 1-a (bf16), hi16 = s (bf16). h = (1-d)*h + s.

__global__ __launch_bounds__(256) void scan_p1(const unsigned int* __restrict__ ds,
                                               float2* __restrict__ AS) {
  int b = blockIdx.x >> 5, ch = blockIdx.x & 31, c = threadIdx.x;
  size_t base = ((size_t)b * LSEQ + ch * CLK) * DO + c;
  float A = 1.f, S = 0.f;
  for (int t = 0; t < CLK; ++t) {
    unsigned int u = ds[base + (size_t)t * DO];
    float d = bits2f((unsigned short)(u & 0xffff));
    float s = bits2f((unsigned short)(u >> 16));
    float a = 1.f - d;
    A *= a;
    S = __builtin_fmaf(a, S, s);
  }
  AS[blockIdx.x * DO + c] = make_float2(A, S);
}

__global__ __launch_bounds__(256) void scan_p2(const unsigned int* __restrict__ ds,
                                               const float2* __restrict__ AS,
                                               bf16* __restrict__ hs) {
  int b = blockIdx.x >> 5, ch = blockIdx.x & 31, c = threadIdx.x;
  // prefix over earlier chunks of this batch (L2-hot, <=31 iterations)
  float h = 0.f;
  for (int j = 0; j < ch; ++j) {
    float2 as = AS[(b * NCH + j) * DO + c];
    h = __builtin_fmaf(as.x, h, as.y);
  }
  size_t base = ((size_t)b * LSEQ + ch * CLK) * DO + c;
  for (int t = 0; t < CLK; ++t) {
    unsigned int u = ds[base + (size_t)t * DO];
    float d = bits2f((unsigned short)(u & 0xffff));
    float s = bits2f((unsigned short)(u >> 16));
    h = __builtin_fmaf(-d, h, h) + s;   // (1-d)*h + s
    hs[base + (size_t)t * DO] = __float2bfloat16(h);
  }
}

// ---------------- final rmsnorm over 1024, bf16 in -> f32 out ----------------

__global__ __launch_bounds__(256) void rmsnorm1024_kernel(const bf16* __restrict__ in,
                                                          const float* __restrict__ w,
                                                          float* __restrict__ out) {
  int row = blockIdx.x, t = threadIdx.x;
  ushort4 raw = ((const ushort4*)(in + (size_t)row * 1024))[t];
  float v0 = bits2f(raw.x), v1 = bits2f(raw.y), v2 = bits2f(raw.z), v3 = bits2f(raw.w);
  float ss = v0 * v0 + v1 * v1 + v2 * v2 + v3 * v3;
#pragma unroll
  for (int ofs = 32; ofs > 0; ofs >>= 1) ss += __shfl_down(ss, ofs, 64);
  __shared__ float wsum[4];
  if ((t & 63) == 0) wsum[t >> 6] = ss;
  __syncthreads();
  float tot = wsum[0] + wsum[1] + wsum[2] + wsum[3];
  float sc = rsqrtf(tot * (1.f / 1024.f) + 1e-6f);
  float4 wv = ((const float4*)w)[t];
  float4 o;
  o.x = v0 * sc * wv.x; o.y = v1 * sc * wv.y;
  o.z = v2 * sc * wv.z; o.w = v3 * sc * wv.w;
  ((float4*)(out + (size_t)row * 1024))[t] = o;
}

// ---------------- epilogue arg pack (gemm_bt only) ----------------

struct EpA {
  bf16* outb;
  const float* bias;
  const bf16* encb;
  const float* p;
  const int* bucket;
  const float* smoothed;
};

// ---------------- generic MFMA GEMM 128x128, 2-phase (small-N GEMMs) ----------

template <int EP, int NC, int KC>
__global__ __launch_bounds__(256) void gemm_bt(const bf16* __restrict__ A,
                                               const bf16* __restrict__ W, EpA ep) {
  __shared__ __align__(16) bf16 As[128 * 64];
  __shared__ __align__(16) bf16 Bs[128 * 64];
  const int t = threadIdx.x;
  const int lane = t & 63;
  const int wv = t >> 6;
  const int wm = wv >> 1, wn = wv & 1;
  const int quad = lane >> 4, l16 = lane & 15;
  const int bm = blockIdx.x << 7, bn = blockIdx.y << 7;

  f32x4 acc[4][4] = {};

  for (int k0 = 0; k0 < KC; k0 += 64) {
    __syncthreads();
#pragma unroll
    for (int i = 0; i < 4; ++i) {
      int slot = i * 256 + t;
      int m = slot >> 3;
      int lk8 = (slot & 7) ^ (m & 7);
      gl_lds16(A + (size_t)(bm + m) * KC + k0 + lk8 * 8, As + slot * 8);
      gl_lds16(W + (size_t)(bn + m) * KC + k0 + lk8 * 8, Bs + slot * 8);
    }
    __syncthreads();
#pragma unroll
    for (int ks = 0; ks < 2; ++ks) {
      short8 af[4], bfr[4];
#pragma unroll
      for (int i = 0; i < 4; ++i) {
        int m = wm * 64 + i * 16 + l16;
        int pa = (ks * 4 + quad) ^ (m & 7);
        af[i] = *(const short8*)(As + m * 64 + pa * 8);
        int n = wn * 64 + i * 16 + l16;
        int pb = (ks * 4 + quad) ^ (n & 7);
        bfr[i] = *(const short8*)(Bs + n * 64 + pb * 8);
      }
#pragma unroll
      for (int i = 0; i < 4; ++i)
#pragma unroll
        for (int j = 0; j < 4; ++j)
          acc[i][j] = __builtin_amdgcn_mfma_f32_16x16x32_bf16(af[i], bfr[j], acc[i][j], 0, 0, 0);
    }
  }

#pragma unroll
  for (int i = 0; i < 4; ++i) {
#pragma unroll
    for (int j = 0; j < 4; ++j) {
#pragma unroll
      for (int r = 0; r < 4; ++r) {
        int m = bm + wm * 64 + i * 16 + quad * 4 + r;
        int n = bn + wn * 64 + j * 16 + l16;
        size_t idx = (size_t)m * NC + n;
        float v = acc[i][j][r];
        if (EP == 1) {         // gate + plugback (NC == DMODEL) [unused now]
          float g = sigm(v + ep.bias[n]);
          float pm = ep.p[m];
          int bb = m >> 11;
          float sm = ep.smoothed[((size_t)(bb * NM + ep.bucket[m])) * DMODEL + n];
          float e = __bfloat162float(ep.encb[idx]);
          ep.outb[idx] = __float2bfloat16((1.f - pm) * g * e + sm);
        } else {               // EP == 5: plain bf16 out
          ep.outb[idx] = __float2bfloat16(v);
        }
      }
    }
  }
}

// ---------------- 256x256 8-phase GEMM (T2+T3+T4+T5), N = DMODEL, pure ----------
// 8 waves (2M x 4N), BK=64, LDS = 2 dbuf x {A,B} x 2 half-tiles of [128][64] bf16.
// Pure GEMM (no fused epilogue): writes raw bf16. Epilogue split into
// gate_plug_kernel for ablation + vectorized one-pass transform.

template <int KC>
__global__ __launch_bounds__(512, 2) void gemm256(const bf16* __restrict__ Ag,
                                                  const bf16* __restrict__ W,
                                                  bf16* __restrict__ outb) {
  __shared__ __align__(16) bf16 lds[2][4][128 * 64];   // [buf][A0,A1,B0,B1][...]
  const int t = threadIdx.x;
  const int lane = t & 63;
  const int wv = t >> 6;
  const int wm = wv >> 2, wn = wv & 3;
  const int quad = lane >> 4, l16 = lane & 15;
  const int bm = blockIdx.x << 8, bn = blockIdx.y << 8;
  constexpr int KT = KC >> 6;   // # 64-wide k-tiles (power of 2, >= 4)
  constexpr int KM = KT - 1;

  const int rr = t >> 3;                 // 0..63 staging row (q=0); q=1 adds +128 global
  const int cc = (t & 7) ^ (rr & 7);     // pre-swizzled source chunk

  f32x4 acc[8][4] = {};
  short8 af[4][2], bfr[2][2];

#define STAGE_A(BUF, H, KTI)                                                      \
  {                                                                               \
    int kk = ((KTI) & KM) << 6;                                                   \
    const bf16* s0 = Ag + (size_t)(bm + (H) * 64 + rr) * KC + kk + cc * 8;        \
    gl_lds16(s0, &lds[BUF][H][t * 8]);                                            \
    const bf16* s1 = Ag + (size_t)(bm + (H) * 64 + rr + 128) * KC + kk + cc * 8;  \
    gl_lds16(s1, &lds[BUF][H][(512 + t) * 8]);                                    \
  }
#define STAGE_B(BUF, H, KTI)                                                      \
  {                                                                               \
    int kk = ((KTI) & KM) << 6;                                                   \
    int n0 = (H) * 32 + (rr & 31) + ((rr >> 5) << 6);                             \
    const bf16* s0 = W + (size_t)(bn + n0) * KC + kk + cc * 8;                    \
    gl_lds16(s0, &lds[BUF][2 + (H)][t * 8]);                                      \
    const bf16* s1 = W + (size_t)(bn + n0 + 128) * KC + kk + cc * 8;              \
    gl_lds16(s1, &lds[BUF][2 + (H)][(512 + t) * 8]);                              \
  }
#define LD_A(BUF, MG)                                                             \
  _Pragma("unroll") for (int ii = 0; ii < 4; ++ii) {                              \
    int r = wm * 64 + ii * 16 + l16;                                              \
    _Pragma("unroll") for (int ks = 0; ks < 2; ++ks) {                            \
      int ch = (ks * 4 + quad) ^ (r & 7);                                         \
      af[ii][ks] = ds_read128(&lds[BUF][MG][(r * 8 + ch) * 8]);                   \
    }                                                                             \
  }
#define LD_B(BUF, NG)                                                             \
  _Pragma("unroll") for (int jj = 0; jj < 2; ++jj) {                              \
    int r = wn * 32 + jj * 16 + l16;                                              \
    _Pragma("unroll") for (int ks = 0; ks < 2; ++ks) {                            \
      int ch = (ks * 4 + quad) ^ (r & 7);                                         \
      bfr[jj][ks] = ds_read128(&lds[BUF][2 + (NG)][(r * 8 + ch) * 8]);            \
    }                                                                             \
  }
#define MMA(MG, NG)                                                               \
  _Pragma("unroll") for (int ks = 0; ks < 2; ++ks)                                \
  _Pragma("unroll") for (int ii = 0; ii < 4; ++ii)                                \
  _Pragma("unroll") for (int jj = 0; jj < 2; ++jj)                                \
    acc[(MG) * 4 + ii][(NG) * 2 + jj] = __builtin_amdgcn_mfma_f32_16x16x32_bf16(  \
        af[ii][ks], bfr[jj][ks], acc[(MG) * 4 + ii][(NG) * 2 + jj], 0, 0, 0);
#define BARR __builtin_amdgcn_s_barrier()
#define WAIT_LGKM asm volatile("s_waitcnt lgkmcnt(0)" ::: "memory")
#define WAIT_VM6 asm volatile("s_waitcnt vmcnt(6)" ::: "memory")
#define SBAR __builtin_amdgcn_sched_barrier(0)
#define PH(MG, NG)                   \
  BARR; WAIT_LGKM; SBAR;             \
  __builtin_amdgcn_s_setprio(1);     \
  MMA(MG, NG);                       \
  __builtin_amdgcn_s_setprio(0);     \
  SBAR;                              \
  BARR;
#define PH_V(MG, NG)                 \
  BARR; WAIT_LGKM; SBAR;             \
  __builtin_amdgcn_s_setprio(1);     \
  MMA(MG, NG);                       \
  __builtin_amdgcn_s_setprio(0);     \
  SBAR;                              \
  WAIT_VM6;                          \
  BARR;

  // prologue: buf0 <- kt0 complete; buf1 <- kt1 {A0, A1, B1} (B0 staged at g1)
  STAGE_A(0, 0, 0) STAGE_A(0, 1, 0) STAGE_B(0, 0, 0) STAGE_B(0, 1, 0)
  STAGE_A(1, 0, 1) STAGE_A(1, 1, 1) STAGE_B(1, 1, 1)
  WAIT_VM6;   // buf0's 8 loads (oldest) complete; buf1's 6 stay in flight
  BARR;

#pragma unroll 1
  for (int it = 0; it < (KT >> 1); ++it) {
    const int kt = it * 2;
    // g1: quad (0,0) of buf0; stage buf1.B0 <- kt+1 (slot dead since prev g8)
    LD_A(0, 0) LD_B(0, 0)
    STAGE_B(1, 0, kt + 1)
    PH(0, 0)
    // g2: (0,1); stage buf0.A0 <- kt+2 (A0 last read g1)
    LD_B(0, 1)
    STAGE_A(0, 0, kt + 2)
    PH(0, 1)
    // g3: (1,1); stage buf0.B1 <- kt+2 (B1 last read g2)
    LD_A(0, 1)
    STAGE_B(0, 1, kt + 2)
    PH(1, 1)
    // g4: (1,0) re-reads B0; stage buf0.A1 <- kt+2 (A1 last read g3);
    //     vmcnt(6): retires buf1(kt+1)'s 8, leaves buf0(kt+2)'s 6 in flight
    LD_B(0, 0)
    STAGE_A(0, 1, kt + 2)
    PH_V(1, 0)
    // g5: quad (0,0) of buf1; stage buf0.B0 <- kt+2 (B0 last read g4)
    LD_A(1, 0) LD_B(1, 0)
    STAGE_B(0, 0, kt + 2)
    PH(0, 0)
    // g6: (0,1); stage buf1.A0 <- kt+3 (A0 last read g5)
    LD_B(1, 1)
    STAGE_A(1, 0, kt + 3)
    PH(0, 1)
    // g7: (1,1); stage buf1.B1 <- kt+3 (B1 last read g6)
    LD_A(1, 1)
    STAGE_B(1, 1, kt + 3)
    PH(1, 1)
    // g8: (1,0); stage buf1.A1 <- kt+3 (A1 last read g7);
    //     vmcnt(6): retires buf0(kt+2)'s 8, leaves buf1(kt+3)'s 6 in flight
    LD_B(1, 0)
    STAGE_A(1, 1, kt + 3)
    PH_V(1, 0)
  }

#undef STAGE_A
#undef STAGE_B
#undef LD_A
#undef LD_B
#undef MMA
#undef BARR
#undef WAIT_LGKM
#undef WAIT_VM6
#undef SBAR
#undef PH
#undef PH_V

#pragma unroll
  for (int i = 0; i < 8; ++i) {
#pragma unroll
    for (int j = 0; j < 4; ++j) {
#pragma unroll
      for (int r = 0; r < 4; ++r) {
        int m = bm + wm * 128 + i * 16 + quad * 4 + r;
        int n = bn + wn * 64 + j * 16 + l16;
        outb[(size_t)m * DMODEL + n] = __float2bfloat16(acc[i][j][r]);
      }
    }
  }
}

// ---------------- dual GEMM: r & i heads share A, fused a_t/s_t epilogue ----------------
// A = xconv bf16 [BLR,256]; Wr,Wi [256,256]. Writes packed uint{d=1-a bf16, s bf16}.

__global__ __launch_bounds__(256) void gemm_ri(const bf16* __restrict__ A,
                                               const bf16* __restrict__ Wr,
                                               const bf16* __restrict__ Wi,
                                               const float* __restrict__ rbias,
                                               const float* __restrict__ ibias,
                                               const float* __restrict__ e8,
                                               unsigned int* __restrict__ ds_out) {
  __shared__ __align__(16) bf16 As[128 * 64];
  __shared__ __align__(16) bf16 Br[128 * 64];
  __shared__ __align__(16) bf16 Bi[128 * 64];
  const int t = threadIdx.x;
  const int lane = t & 63;
  const int wv = t >> 6;
  const int wm = wv >> 1, wn = wv & 1;
  const int quad = lane >> 4, l16 = lane & 15;
  const int bm = blockIdx.x << 7, bn = blockIdx.y << 7;

  f32x4 ar[4][4] = {};
  f32x4 ai[4][4] = {};

  for (int k0 = 0; k0 < DO; k0 += 64) {
    __syncthreads();
#pragma unroll
    for (int i = 0; i < 4; ++i) {
      int slot = i * 256 + t;
      int m = slot >> 3;
      int lk8 = (slot & 7) ^ (m & 7);
      gl_lds16(A + (size_t)(bm + m) * DO + k0 + lk8 * 8, As + slot * 8);
      gl_lds16(Wr + (size_t)(bn + m) * DO + k0 + lk8 * 8, Br + slot * 8);
      gl_lds16(Wi + (size_t)(bn + m) * DO + k0 + lk8 * 8, Bi + slot * 8);
    }
    __syncthreads();
#pragma unroll
    for (int ks = 0; ks < 2; ++ks) {
      short8 af[4], br[4], bi[4];
#pragma unroll
      for (int i = 0; i < 4; ++i) {
        int m = wm * 64 + i * 16 + l16;
        int pa = (ks * 4 + quad) ^ (m & 7);
        af[i] = *(const short8*)(As + m * 64 + pa * 8);
        int n = wn * 64 + i * 16 + l16;
        int pb = (ks * 4 + quad) ^ (n & 7);
        br[i] = *(const short8*)(Br + n * 64 + pb * 8);
        bi[i] = *(const short8*)(Bi + n * 64 + pb * 8);
      }
#pragma unroll
      for (int i = 0; i < 4; ++i)
#pragma unroll
        for (int j = 0; j < 4; ++j) {
          ar[i][j] = __builtin_amdgcn_mfma_f32_16x16x32_bf16(af[i], br[j], ar[i][j], 0, 0, 0);
          ai[i][j] = __builtin_amdgcn_mfma_f32_16x16x32_bf16(af[i], bi[j], ai[i][j], 0, 0, 0);
        }
    }
  }

#pragma unroll
  for (int i = 0; i < 4; ++i) {
#pragma unroll
    for (int j = 0; j < 4; ++j) {
#pragma unroll
      for (int r = 0; r < 4; ++r) {
        int m = bm + wm * 64 + i * 16 + quad * 4 + r;
        int n = bn + wn * 64 + j * 16 + l16;
        size_t idx = (size_t)m * DO + n;
        float rv = sigm(ar[i][j][r] + rbias[n]);
        float a = exp2f(rv * e8[n]);
        float d = 1.f - a;                               // ~5e-3, bf16-safe
        float iv = sigm(ai[i][j][r] + ibias[n]);
        float xc = __bfloat162float(A[idx]);             // xconv[m][n] == A[m][n]
        float s = sqrtf(fmaxf(1.f - a * a, 0.f)) * iv * xc;
        ds_out[idx] = (unsigned int)bf16bits(d) | ((unsigned int)bf16bits(s) << 16);
      }
    }
  }
}

// ---------------- out-proj GEMM tile 64x256 + fused RMSNorm(256) ----------------

__global__ __launch_bounds__(256) void gemm_on(const bf16* __restrict__ A,   // hs [BLR,256]
                                               const bf16* __restrict__ W,   // ow [256,256]
                                               const float* __restrict__ rnw,
                                               bf16* __restrict__ xb) {
  __shared__ __align__(16) bf16 As[64 * 64];
  __shared__ __align__(16) bf16 Bs[256 * 64];
  __shared__ float red[4][64];
  const int t = threadIdx.x;
  const int lane = t & 63;
  const int wn = t >> 6;           // wave = column slice of 64
  const int quad = lane >> 4, l16 = lane & 15;
  const int bm = blockIdx.x << 6;

  f32x4 acc[4][4] = {};

  for (int k0 = 0; k0 < DO; k0 += 64) {
    __syncthreads();
#pragma unroll
    for (int i = 0; i < 2; ++i) {
      int slot = i * 256 + t;
      int m = slot >> 3;
      int lk8 = (slot & 7) ^ (m & 7);
      gl_lds16(A + (size_t)(bm + m) * DO + k0 + lk8 * 8, As + slot * 8);
    }
#pragma unroll
    for (int i = 0; i < 8; ++i) {
      int slot = i * 256 + t;
      int n = slot >> 3;
      int lk8 = (slot & 7) ^ (n & 7);
      gl_lds16(W + (size_t)n * DO + k0 + lk8 * 8, Bs + slot * 8);
    }
    __syncthreads();
#pragma unroll
    for (int ks = 0; ks < 2; ++ks) {
      short8 af[4], bfr[4];
#pragma unroll
      for (int i = 0; i < 4; ++i) {
        int m = i * 16 + l16;
        int pa = (ks * 4 + quad) ^ (m & 7);
        af[i] = *(const short8*)(As + m * 64 + pa * 8);
        int n = wn * 64 + i * 16 + l16;
        int pb = (ks * 4 + quad) ^ (n & 7);
        bfr[i] = *(const short8*)(Bs + n * 64 + pb * 8);
      }
#pragma unroll
      for (int i = 0; i < 4; ++i)
#pragma unroll
        for (int j = 0; j < 4; ++j)
          acc[i][j] = __builtin_amdgcn_mfma_f32_16x16x32_bf16(af[i], bfr[j], acc[i][j], 0, 0, 0);
    }
  }

  float part[4][4];
#pragma unroll
  for (int i = 0; i < 4; ++i)
#pragma unroll
    for (int r = 0; r < 4; ++r) {
      float s = 0.f;
#pragma unroll
      for (int j = 0; j < 4; ++j) s += acc[i][j][r] * acc[i][j][r];
      part[i][r] = s;
    }
#pragma unroll
  for (int mask = 1; mask <= 8; mask <<= 1)
#pragma unroll
    for (int i = 0; i < 4; ++i)
#pragma unroll
      for (int r = 0; r < 4; ++r) part[i][r] += __shfl_xor(part[i][r], mask, 64);
  if (l16 == 0) {
#pragma unroll
    for (int i = 0; i < 4; ++i)
#pragma unroll
      for (int r = 0; r < 4; ++r) red[wn][i * 16 + quad * 4 + r] = part[i][r];
  }
  __syncthreads();
#pragma unroll
  for (int i = 0; i < 4; ++i) {
#pragma unroll
    for (int r = 0; r < 4; ++r) {
      int ml = i * 16 + quad * 4 + r;
      float tot = red[0][ml] + red[1][ml] + red[2][ml] + red[3][ml];
      float sc = rsqrtf(tot * (1.f / 256.f) + 1e-6f);
#pragma unroll
      for (int j = 0; j < 4; ++j) {
        int n = wn * 64 + j * 16 + l16;
        xb[(size_t)(bm + ml) * DO + n] = __float2bfloat16(acc[i][j][r] * sc * rnw[n]);
      }
    }
  }
}

// ---------------- launch ----------------

extern "C" void kernel_launch(void* const* d_in, const int* in_sizes, int n_in,
                              void* d_out, int out_size, void* d_ws, size_t ws_size,
                              hipStream_t stream) {
  const float* concept_out = (const float*)d_in[0];
  const float* encoder_out = (const float*)d_in[1];
  const float* bprobs      = (const float*)d_in[2];
  const int*   bidx        = (const int*)d_in[3];
  const float* gate_w      = (const float*)d_in[4];
  const float* gate_b      = (const float*)d_in[5];
  const float* down_w      = (const float*)d_in[6];
  const float* up_w        = (const float*)d_in[7];
  const float* norm_out_w  = (const float*)d_in[8];
  const float* rc_w        = (const float*)d_in[9];
  const float* rc_b        = (const float*)d_in[10];
  const float* wr_w        = (const float*)d_in[11];
  const float* wr_b        = (const float*)d_in[12];
  const float* wi_w        = (const float*)d_in[13];
  const float* wi_b        = (const float*)d_in[14];
  const float* log_a       = (const float*)d_in[15];
  const float* ow_w        = (const float*)d_in[16];
  const float* rn_w        = (const float*)d_in[17];
  float* out = (float*)d_out;
  (void)in_sizes; (void)n_in; (void)out_size; (void)ws_size;

  char* base = (char*)d_ws;
  size_t off = 0;
  auto alloc = [&](size_t bytes) -> char* {
    char* p = base + off;
    off += (bytes + 255) & ~(size_t)255;
    return p;
  };
  float* smoothed = (float*)alloc((size_t)NB * NM * DMODEL * 4);   // 8 MB
  int*   bucket   = (int*)alloc((size_t)BLR * 4);
  bf16*  gate_wb  = (bf16*)alloc((size_t)DMODEL * DMODEL * 2);
  bf16*  down_wb  = (bf16*)alloc((size_t)DO * DMODEL * 2);
  bf16*  up_wb    = (bf16*)alloc((size_t)DMODEL * DO * 2);
  bf16*  wrb      = (bf16*)alloc((size_t)3 * DO * DO * 2);
  bf16*  wib      = (bf16*)alloc((size_t)3 * DO * DO * 2);
  bf16*  owb      = (bf16*)alloc((size_t)3 * DO * DO * 2);
  float* e8       = (float*)alloc(3 * DO * 4);
  float2* ASsum   = (float2*)alloc((size_t)NB * NCH * DO * 8);     // 512 KB chunk summaries
  bf16*  xb       = (bf16*)alloc((size_t)BLR * DO * 2);            // 8 MB layer io

  // reused overlay region — offsets computed from actual buffer sizes
  const size_t SZ_ENC   = (size_t)BLR * DMODEL * 2;   // 32 MB
  const size_t SZ_XCONV = (size_t)BLR * DO * 2;       //  8 MB
  const size_t SZ_DS    = (size_t)BLR * DO * 4;       // 16 MB (packed uint32!)
  char* RA = alloc(2 * SZ_ENC);                       // 64 MB
  // head overlays
  bf16*  encb = (bf16*)RA;
  bf16*  h0b  = (bf16*)(RA + SZ_ENC);   // raw G1 logits, then gated in-place
  // layer overlays (xconvb | dsbuf | hsb disjoint: 8 + 16 + 8 = 32 MB)
  bf16*         xconvb = (bf16*)RA;
  unsigned int* dsbuf  = (unsigned int*)(RA + SZ_XCONV);
  bf16*         hsb    = (bf16*)(RA + SZ_XCONV + SZ_DS);
  // tail overlay
  bf16*  tmp2b  = (bf16*)RA;

  cvt4_kernel<<<(BLR * DMODEL / 4 + 255) / 256, 256, 0, stream>>>(
      (const float4*)encoder_out, (ushort4*)encb, BLR * DMODEL / 4);
  prep_kernel<<<(2163456 + 255) / 256, 256, 0, stream>>>(
      gate_w, down_w, up_w, wr_w, wi_w, ow_w, log_a,
      gate_wb, down_wb, up_wb, wrb, wib, owb, e8);
  ema_kernel<<<NB * 4, 256, 0, stream>>>(concept_out, bprobs, bidx, smoothed);
  bucket_kernel<<<BLR / 256, 256, 0, stream>>>(bidx, bucket);

  // G1: pure gate GEMM -> h0b (raw logits), then fused gate+plugback in place
  gemm256<DMODEL><<<dim3(BLR / 256, DMODEL / 256), 512, 0, stream>>>(encb, gate_wb, h0b);
  gate_plug_kernel<<<BLR, 256, 0, stream>>>(h0b, encb, gate_b, bprobs, bucket, smoothed);

  // G2: down projection -> xb (bf16)
  EpA ep{};
  ep.outb = xb;
  gemm_bt<5, DO, DMODEL><<<dim3(BLR / 128, DO / 128), 256, 0, stream>>>(h0b, down_wb, ep);

  for (int k = 0; k < 3; ++k) {
    conv_kernel<<<BLR, 256, 0, stream>>>(xb, rc_w + k * DO * 4, rc_b + k * DO, xconvb);
    gemm_ri<<<dim3(BLR / 128, DO / 128), 256, 0, stream>>>(
        xconvb, wrb + k * DO * DO, wib + k * DO * DO,
        wr_b + k * DO, wi_b + k * DO, e8 + k * DO, dsbuf);
    scan_p1<<<NB * NCH, 256, 0, stream>>>(dsbuf, ASsum);
    scan_p2<<<NB * NCH, 256, 0, stream>>>(dsbuf, ASsum, hsb);
    gemm_on<<<BLR / 64, 256, 0, stream>>>(hsb, owb + k * DO * DO, rn_w + k * DO, xb);
  }

  // up projection -> tmp2 (bf16), 256^2 8-phase; final rmsnorm -> out (f32)
  gemm256<DO><<<dim3(BLR / 256, DMODEL / 256), 512, 0, stream>>>(xb, up_wb, tmp2b);
  rmsnorm1024_kernel<<<BLR, 256, 0, stream>>>(tmp2b, norm_out_w, out);
}

// Round 6
// 486.404 us; speedup vs baseline: 1.0988x; 1.0643x over previous
//
#include <hip/hip_runtime.h>
#include <hip/hip_bf16.h>
#include <stdint.h>

typedef __attribute__((ext_vector_type(8))) short short8;   // 8 bf16 (4 VGPRs)
typedef __attribute__((ext_vector_type(4))) float f32x4;    // 4 fp32 acc
typedef __hip_bfloat16 bf16;

#define NB   8
#define LSEQ 2048
#define NM   256
#define DMODEL 1024
#define DO   256
#define BLR  16384   /* NB*LSEQ rows */
#define NCH  32      /* scan chunks */
#define CLK  64      /* chunk length */

__device__ __forceinline__ float sigm(float x) { return 1.f / (1.f + __expf(-x)); }

__device__ __forceinline__ void gl_lds16(const void* g, void* l) {
  __builtin_amdgcn_global_load_lds((const __attribute__((address_space(1))) void*)g,
                                   (__attribute__((address_space(3))) void*)l, 16, 0, 0);
}

// inline-asm LDS read: invisible to compiler alias analysis (no auto vmcnt(0)
// drain vs in-flight global_load_lds). Fenced by lgkmcnt(0)+sched_barrier(0).
__device__ __forceinline__ short8 ds_read128(const bf16* p) {
  short8 r;
  unsigned a = (unsigned)(uintptr_t)(const __attribute__((address_space(3))) bf16*)p;
  asm volatile("ds_read_b128 %0, %1" : "=v"(r) : "v"(a));
  return r;
}

__device__ __forceinline__ unsigned short bf16bits(float v) {
  bf16 b = __float2bfloat16(v);
  return *(unsigned short*)&b;
}
__device__ __forceinline__ float bits2f(unsigned short u) {
  bf16 b = *(bf16*)&u;
  return __bfloat162float(b);
}

// ---------------- prep: all weight cvts + e8l2a in ONE dispatch ----------------

__global__ __launch_bounds__(256) void prep_kernel(
    const float* __restrict__ gate_w, const float* __restrict__ down_w,
    const float* __restrict__ up_w, const float* __restrict__ wr_w,
    const float* __restrict__ wi_w, const float* __restrict__ ow_w,
    const float* __restrict__ log_a,
    bf16* __restrict__ gate_wb, bf16* __restrict__ down_wb, bf16* __restrict__ up_wb,
    bf16* __restrict__ wrb, bf16* __restrict__ wib, bf16* __restrict__ owb,
    float* __restrict__ e8) {
  int i = blockIdx.x * 256 + threadIdx.x;
  if (i < 1048576) { gate_wb[i] = __float2bfloat16(gate_w[i]); return; }
  i -= 1048576;
  if (i < 262144) { down_wb[i] = __float2bfloat16(down_w[i]); return; }
  i -= 262144;
  if (i < 262144) { up_wb[i] = __float2bfloat16(up_w[i]); return; }
  i -= 262144;
  if (i < 196608) { wrb[i] = __float2bfloat16(wr_w[i]); return; }
  i -= 196608;
  if (i < 196608) { wib[i] = __float2bfloat16(wi_w[i]); return; }
  i -= 196608;
  if (i < 196608) { owb[i] = __float2bfloat16(ow_w[i]); return; }
  i -= 196608;
  if (i < 768) {
    float ab = 1.f / (1.f + expf(-log_a[i]));
    e8[i] = 8.f * log2f(ab);
  }
}

// vectorized f32 -> bf16 (4 elem/thread)
__global__ __launch_bounds__(256) void cvt4_kernel(const float4* __restrict__ in,
                                                   ushort4* __restrict__ out, int n4) {
  int i = blockIdx.x * 256 + threadIdx.x;
  if (i < n4) {
    float4 v = in[i];
    ushort4 o;
    o.x = bf16bits(v.x); o.y = bf16bits(v.y); o.z = bf16bits(v.z); o.w = bf16bits(v.w);
    out[i] = o;
  }
}

// ---------------- EMA + bucket ----------------

__global__ __launch_bounds__(256) void ema_kernel(const float* __restrict__ cpt,
                                                  const float* __restrict__ bprobs,
                                                  const int* __restrict__ bidx,
                                                  float* __restrict__ smoothed) {
  int b = blockIdx.x >> 2;
  int c = ((blockIdx.x & 3) << 8) + threadIdx.x;
  __shared__ float p[NM];
  p[threadIdx.x] = bprobs[b * LSEQ + bidx[b * NM + threadIdx.x]];
  __syncthreads();
  const float* cp = cpt + (size_t)b * NM * DMODEL + c;
  float* sp = smoothed + (size_t)b * NM * DMODEL + c;
  float h = 0.f;
  for (int m = 0; m < NM; ++m) {
    float pm = p[m];
    h = pm * cp[(size_t)m * DMODEL] + (1.f - pm) * h;
    sp[(size_t)m * DMODEL] = h;
  }
}

__global__ __launch_bounds__(256) void bucket_kernel(const int* __restrict__ bidx,
                                                     int* __restrict__ bucket) {
  int i = blockIdx.x * 256 + threadIdx.x;
  int b = i >> 11, l = i & 2047;
  const int* bi = bidx + b * NM;
  int lo = 0, hi = NM;
  while (lo < hi) {
    int mid = (lo + hi) >> 1;
    if (bi[mid] <= l) lo = mid + 1; else hi = mid;
  }
  int v = lo - 1;
  bucket[i] = v < 0 ? 0 : v;
}

// ---------------- gate + plugback elementwise (split from G1 epilogue) ----------
// h0 holds raw gemm logits (bf16); transformed IN PLACE:
// h0[m][n] = (1-p[m]) * sigm(h0[m][n] + gb[n]) * enc[m][n] + smoothed[b][bucket[m]][n]

__global__ __launch_bounds__(256) void gate_plug_kernel(bf16* __restrict__ h0,
                                                        const bf16* __restrict__ encb,
                                                        const float* __restrict__ gbias,
                                                        const float* __restrict__ bprobs,
                                                        const int* __restrict__ bucket,
                                                        const float* __restrict__ smoothed) {
  const int m = blockIdx.x;
  const int t = threadIdx.x;
  const int b = m >> 11;
  const float pm1 = 1.f - bprobs[m];
  const float* srow = smoothed + ((size_t)(b * NM + bucket[m])) * DMODEL + t * 4;
  const size_t base = (size_t)m * DMODEL + t * 4;
  ushort4 gr = *(const ushort4*)(h0 + base);
  ushort4 er = *(const ushort4*)(encb + base);
  float4 sm4 = *(const float4*)srow;
  float4 gb4 = *(const float4*)(gbias + t * 4);
  ushort4 o;
  o.x = bf16bits(pm1 * sigm(bits2f(gr.x) + gb4.x) * bits2f(er.x) + sm4.x);
  o.y = bf16bits(pm1 * sigm(bits2f(gr.y) + gb4.y) * bits2f(er.y) + sm4.y);
  o.z = bf16bits(pm1 * sigm(bits2f(gr.z) + gb4.z) * bits2f(er.z) + sm4.z);
  o.w = bf16bits(pm1 * sigm(bits2f(gr.w) + gb4.w) * bits2f(er.w) + sm4.w);
  *(ushort4*)(h0 + base) = o;
}

// ---------------- depthwise causal conv k=4 ----------------

__global__ __launch_bounds__(256) void conv_kernel(const bf16* __restrict__ x,
                                                   const float* __restrict__ cw,
                                                   const float* __restrict__ cb,
                                                   bf16* __restrict__ xcb) {
  int i = blockIdx.x * 256 + threadIdx.x;
  int c = i & 255;
  int bl = i >> 8;
  int l = bl & 2047;
  float4 w4 = ((const float4*)cw)[c];
  const float* wf = (const float*)&w4;
  float s = cb[c];
#pragma unroll
  for (int kk = 0; kk < 4; ++kk) {
    int ll = l - 3 + kk;
    if (ll >= 0) s += wf[kk] * __bfloat162float(x[i + (kk - 3) * 256]);
  }
  xcb[i] = __float2bfloat16(s);
}

// ---------------- chunked scan, 2 dispatches, 256 blocks each ----------------
// input packed uint: lo16 = d = 1-a (bf16), hi16 = s (bf16). h = (1-d)*h + s.

__global__ __launch_bounds__(256) void scan_p1(const unsigned int* __restrict__ ds,
                                               float2* __restrict__ AS) {
  int b = blockIdx.x >> 5, ch = blockIdx.x & 31, c = threadIdx.x;
  size_t base = ((size_t)b * LSEQ + ch * CLK) * DO + c;
  float A = 1.f, S = 0.f;
  for (int t = 0; t < CLK; ++t) {
    unsigned int u = ds[base + (size_t)t * DO];
    float d = bits2f((unsigned short)(u & 0xffff));
    float s = bits2f((unsigned short)(u >> 16));
    float a = 1.f - d;
    A *= a;
    S = __builtin_fmaf(a, S, s);
  }
  AS[blockIdx.x * DO + c] = make_float2(A, S);
}

__global__ __launch_bounds__(256) void scan_p2(const unsigned int* __restrict__ ds,
                                               const float2* __restrict__ AS,
                                               bf16* __restrict__ hs) {
  int b = blockIdx.x >> 5, ch = blockIdx.x & 31, c = threadIdx.x;
  // prefix over earlier chunks of this batch (L2-hot, <=31 iterations)
  float h = 0.f;
  for (int j = 0; j < ch; ++j) {
    float2 as = AS[(b * NCH + j) * DO + c];
    h = __builtin_fmaf(as.x, h, as.y);
  }
  size_t base = ((size_t)b * LSEQ + ch * CLK) * DO + c;
  for (int t = 0; t < CLK; ++t) {
    unsigned int u = ds[base + (size_t)t * DO];
    float d = bits2f((unsigned short)(u & 0xffff));
    float s = bits2f((unsigned short)(u >> 16));
    h = __builtin_fmaf(-d, h, h) + s;   // (1-d)*h + s
    hs[base + (size_t)t * DO] = __float2bfloat16(h);
  }
}

// ---------------- final rmsnorm over 1024, bf16 in -> f32 out ----------------

__global__ __launch_bounds__(256) void rmsnorm1024_kernel(const bf16* __restrict__ in,
                                                          const float* __restrict__ w,
                                                          float* __restrict__ out) {
  int row = blockIdx.x, t = threadIdx.x;
  ushort4 raw = ((const ushort4*)(in + (size_t)row * 1024))[t];
  float v0 = bits2f(raw.x), v1 = bits2f(raw.y), v2 = bits2f(raw.z), v3 = bits2f(raw.w);
  float ss = v0 * v0 + v1 * v1 + v2 * v2 + v3 * v3;
#pragma unroll
  for (int ofs = 32; ofs > 0; ofs >>= 1) ss += __shfl_down(ss, ofs, 64);
  __shared__ float wsum[4];
  if ((t & 63) == 0) wsum[t >> 6] = ss;
  __syncthreads();
  float tot = wsum[0] + wsum[1] + wsum[2] + wsum[3];
  float sc = rsqrtf(tot * (1.f / 1024.f) + 1e-6f);
  float4 wv = ((const float4*)w)[t];
  float4 o;
  o.x = v0 * sc * wv.x; o.y = v1 * sc * wv.y;
  o.z = v2 * sc * wv.z; o.w = v3 * sc * wv.w;
  ((float4*)(out + (size_t)row * 1024))[t] = o;
}

// ---------------- epilogue arg pack (gemm_bt only) ----------------

struct EpA {
  bf16* outb;
  const float* bias;
  const bf16* encb;
  const float* p;
  const int* bucket;
  const float* smoothed;
};

// ---------------- generic MFMA GEMM 128x128, 2-phase (small-N GEMMs) ----------

template <int EP, int NC, int KC>
__global__ __launch_bounds__(256) void gemm_bt(const bf16* __restrict__ A,
                                               const bf16* __restrict__ W, EpA ep) {
  __shared__ __align__(16) bf16 As[128 * 64];
  __shared__ __align__(16) bf16 Bs[128 * 64];
  const int t = threadIdx.x;
  const int lane = t & 63;
  const int wv = t >> 6;
  const int wm = wv >> 1, wn = wv & 1;
  const int quad = lane >> 4, l16 = lane & 15;
  const int bm = blockIdx.x << 7, bn = blockIdx.y << 7;

  f32x4 acc[4][4] = {};

  for (int k0 = 0; k0 < KC; k0 += 64) {
    __syncthreads();
#pragma unroll
    for (int i = 0; i < 4; ++i) {
      int slot = i * 256 + t;
      int m = slot >> 3;
      int lk8 = (slot & 7) ^ (m & 7);
      gl_lds16(A + (size_t)(bm + m) * KC + k0 + lk8 * 8, As + slot * 8);
      gl_lds16(W + (size_t)(bn + m) * KC + k0 + lk8 * 8, Bs + slot * 8);
    }
    __syncthreads();
#pragma unroll
    for (int ks = 0; ks < 2; ++ks) {
      short8 af[4], bfr[4];
#pragma unroll
      for (int i = 0; i < 4; ++i) {
        int m = wm * 64 + i * 16 + l16;
        int pa = (ks * 4 + quad) ^ (m & 7);
        af[i] = *(const short8*)(As + m * 64 + pa * 8);
        int n = wn * 64 + i * 16 + l16;
        int pb = (ks * 4 + quad) ^ (n & 7);
        bfr[i] = *(const short8*)(Bs + n * 64 + pb * 8);
      }
#pragma unroll
      for (int i = 0; i < 4; ++i)
#pragma unroll
        for (int j = 0; j < 4; ++j)
          acc[i][j] = __builtin_amdgcn_mfma_f32_16x16x32_bf16(af[i], bfr[j], acc[i][j], 0, 0, 0);
    }
  }

#pragma unroll
  for (int i = 0; i < 4; ++i) {
#pragma unroll
    for (int j = 0; j < 4; ++j) {
#pragma unroll
      for (int r = 0; r < 4; ++r) {
        int m = bm + wm * 64 + i * 16 + quad * 4 + r;
        int n = bn + wn * 64 + j * 16 + l16;
        size_t idx = (size_t)m * NC + n;
        float v = acc[i][j][r];
        if (EP == 1) {         // gate + plugback (NC == DMODEL) [unused now]
          float g = sigm(v + ep.bias[n]);
          float pm = ep.p[m];
          int bb = m >> 11;
          float sm = ep.smoothed[((size_t)(bb * NM + ep.bucket[m])) * DMODEL + n];
          float e = __bfloat162float(ep.encb[idx]);
          ep.outb[idx] = __float2bfloat16((1.f - pm) * g * e + sm);
        } else {               // EP == 5: plain bf16 out
          ep.outb[idx] = __float2bfloat16(v);
        }
      }
    }
  }
}

// ---------------- 256x256 8-phase GEMM (T2+T3+T4+T5), N = DMODEL, pure ----------
// 8 waves (2M x 4N), BK=64, LDS = 2 dbuf x {A,B} x 2 half-tiles of [128][64] bf16.
// Pure GEMM (no fused epilogue): writes raw bf16.

template <int KC>
__global__ __launch_bounds__(512, 2) void gemm256(const bf16* __restrict__ Ag,
                                                  const bf16* __restrict__ W,
                                                  bf16* __restrict__ outb) {
  __shared__ __align__(16) bf16 lds[2][4][128 * 64];   // [buf][A0,A1,B0,B1][...]
  const int t = threadIdx.x;
  const int lane = t & 63;
  const int wv = t >> 6;
  const int wm = wv >> 2, wn = wv & 3;
  const int quad = lane >> 4, l16 = lane & 15;
  const int bm = blockIdx.x << 8, bn = blockIdx.y << 8;
  constexpr int KT = KC >> 6;   // # 64-wide k-tiles (power of 2, >= 4)
  constexpr int KM = KT - 1;

  const int rr = t >> 3;                 // 0..63 staging row (q=0); q=1 adds +128 global
  const int cc = (t & 7) ^ (rr & 7);     // pre-swizzled source chunk

  f32x4 acc[8][4] = {};
  short8 af[4][2], bfr[2][2];

#define STAGE_A(BUF, H, KTI)                                                      \
  {                                                                               \
    int kk = ((KTI) & KM) << 6;                                                   \
    const bf16* s0 = Ag + (size_t)(bm + (H) * 64 + rr) * KC + kk + cc * 8;        \
    gl_lds16(s0, &lds[BUF][H][t * 8]);                                            \
    const bf16* s1 = Ag + (size_t)(bm + (H) * 64 + rr + 128) * KC + kk + cc * 8;  \
    gl_lds16(s1, &lds[BUF][H][(512 + t) * 8]);                                    \
  }
#define STAGE_B(BUF, H, KTI)                                                      \
  {                                                                               \
    int kk = ((KTI) & KM) << 6;                                                   \
    int n0 = (H) * 32 + (rr & 31) + ((rr >> 5) << 6);                             \
    const bf16* s0 = W + (size_t)(bn + n0) * KC + kk + cc * 8;                    \
    gl_lds16(s0, &lds[BUF][2 + (H)][t * 8]);                                      \
    const bf16* s1 = W + (size_t)(bn + n0 + 128) * KC + kk + cc * 8;              \
    gl_lds16(s1, &lds[BUF][2 + (H)][(512 + t) * 8]);                              \
  }
#define LD_A(BUF, MG)                                                             \
  _Pragma("unroll") for (int ii = 0; ii < 4; ++ii) {                              \
    int r = wm * 64 + ii * 16 + l16;                                              \
    _Pragma("unroll") for (int ks = 0; ks < 2; ++ks) {                            \
      int ch = (ks * 4 + quad) ^ (r & 7);                                         \
      af[ii][ks] = ds_read128(&lds[BUF][MG][(r * 8 + ch) * 8]);                   \
    }                                                                             \
  }
#define LD_B(BUF, NG)                                                             \
  _Pragma("unroll") for (int jj = 0; jj < 2; ++jj) {                              \
    int r = wn * 32 + jj * 16 + l16;                                              \
    _Pragma("unroll") for (int ks = 0; ks < 2; ++ks) {                            \
      int ch = (ks * 4 + quad) ^ (r & 7);                                         \
      bfr[jj][ks] = ds_read128(&lds[BUF][2 + (NG)][(r * 8 + ch) * 8]);            \
    }                                                                             \
  }
#define MMA(MG, NG)                                                               \
  _Pragma("unroll") for (int ks = 0; ks < 2; ++ks)                                \
  _Pragma("unroll") for (int ii = 0; ii < 4; ++ii)                                \
  _Pragma("unroll") for (int jj = 0; jj < 2; ++jj)                                \
    acc[(MG) * 4 + ii][(NG) * 2 + jj] = __builtin_amdgcn_mfma_f32_16x16x32_bf16(  \
        af[ii][ks], bfr[jj][ks], acc[(MG) * 4 + ii][(NG) * 2 + jj], 0, 0, 0);
#define BARR __builtin_amdgcn_s_barrier()
#define WAIT_LGKM asm volatile("s_waitcnt lgkmcnt(0)" ::: "memory")
#define WAIT_VM6 asm volatile("s_waitcnt vmcnt(6)" ::: "memory")
#define SBAR __builtin_amdgcn_sched_barrier(0)
#define PH(MG, NG)                   \
  BARR; WAIT_LGKM; SBAR;             \
  __builtin_amdgcn_s_setprio(1);     \
  MMA(MG, NG);                       \
  __builtin_amdgcn_s_setprio(0);     \
  SBAR;                              \
  BARR;
#define PH_V(MG, NG)                 \
  BARR; WAIT_LGKM; SBAR;             \
  __builtin_amdgcn_s_setprio(1);     \
  MMA(MG, NG);                       \
  __builtin_amdgcn_s_setprio(0);     \
  SBAR;                              \
  WAIT_VM6;                          \
  BARR;

  // prologue: buf0 <- kt0 complete; buf1 <- kt1 {A0, A1, B1} (B0 staged at g1)
  STAGE_A(0, 0, 0) STAGE_A(0, 1, 0) STAGE_B(0, 0, 0) STAGE_B(0, 1, 0)
  STAGE_A(1, 0, 1) STAGE_A(1, 1, 1) STAGE_B(1, 1, 1)
  WAIT_VM6;   // buf0's 8 loads (oldest) complete; buf1's 6 stay in flight
  BARR;

#pragma unroll 1
  for (int it = 0; it < (KT >> 1); ++it) {
    const int kt = it * 2;
    LD_A(0, 0) LD_B(0, 0)
    STAGE_B(1, 0, kt + 1)
    PH(0, 0)
    LD_B(0, 1)
    STAGE_A(0, 0, kt + 2)
    PH(0, 1)
    LD_A(0, 1)
    STAGE_B(0, 1, kt + 2)
    PH(1, 1)
    LD_B(0, 0)
    STAGE_A(0, 1, kt + 2)
    PH_V(1, 0)
    LD_A(1, 0) LD_B(1, 0)
    STAGE_B(0, 0, kt + 2)
    PH(0, 0)
    LD_B(1, 1)
    STAGE_A(1, 0, kt + 3)
    PH(0, 1)
    LD_A(1, 1)
    STAGE_B(1, 1, kt + 3)
    PH(1, 1)
    LD_B(1, 0)
    STAGE_A(1, 1, kt + 3)
    PH_V(1, 0)
  }

#undef STAGE_A
#undef STAGE_B
#undef LD_A
#undef LD_B
#undef MMA
#undef BARR
#undef WAIT_LGKM
#undef WAIT_VM6
#undef SBAR
#undef PH
#undef PH_V

#pragma unroll
  for (int i = 0; i < 8; ++i) {
#pragma unroll
    for (int j = 0; j < 4; ++j) {
#pragma unroll
      for (int r = 0; r < 4; ++r) {
        int m = bm + wm * 128 + i * 16 + quad * 4 + r;
        int n = bn + wn * 64 + j * 16 + l16;
        outb[(size_t)m * DMODEL + n] = __float2bfloat16(acc[i][j][r]);
      }
    }
  }
}

// ---------------- dual GEMM v2: occupancy-tiled 32x128, 1024 blocks ----------------
// M=16384 K=256 N=256 dual-head: compute is trivial (4.3 GF); the old 128^2
// tiling gave 256 blocks = 1 wave/SIMD and ran 94% stall (MfmaUtil 1.9%).
// v2: 32x128 tiles -> grid (512,2)=1024 blocks, LDS 36KB, acc 32 VGPR ->
// 4 blocks/CU, 16 waves/CU. Epilogue 16 outputs/thread (was 64).

__global__ __launch_bounds__(256, 4) void gemm_ri(const bf16* __restrict__ A,
                                                  const bf16* __restrict__ Wr,
                                                  const bf16* __restrict__ Wi,
                                                  const float* __restrict__ rbias,
                                                  const float* __restrict__ ibias,
                                                  const float* __restrict__ e8,
                                                  unsigned int* __restrict__ ds_out) {
  __shared__ __align__(16) bf16 As[32 * 64];    //  4 KB
  __shared__ __align__(16) bf16 Br[128 * 64];   // 16 KB
  __shared__ __align__(16) bf16 Bi[128 * 64];   // 16 KB
  const int t = threadIdx.x;
  const int lane = t & 63;
  const int wv = t >> 6;
  const int wm = wv >> 1, wn = wv & 1;    // 2x2 waves, wave tile 16x64
  const int quad = lane >> 4, l16 = lane & 15;
  const int bm = blockIdx.x << 5;         // 32-row tile
  const int bn = blockIdx.y << 7;         // 128-col tile

  f32x4 ar[4] = {};
  f32x4 ai[4] = {};

  for (int k0 = 0; k0 < DO; k0 += 64) {
    __syncthreads();
    {  // A: 32 rows x 64 k, one 16B chunk per thread
      int m = t >> 3, lk8 = (t & 7) ^ (m & 7);
      gl_lds16(A + (size_t)(bm + m) * DO + k0 + lk8 * 8, As + t * 8);
    }
#pragma unroll
    for (int i = 0; i < 4; ++i) {  // Wr/Wi: 128 rows x 64 k each
      int slot = i * 256 + t;
      int n = slot >> 3, lk8 = (slot & 7) ^ (n & 7);
      gl_lds16(Wr + (size_t)(bn + n) * DO + k0 + lk8 * 8, Br + slot * 8);
      gl_lds16(Wi + (size_t)(bn + n) * DO + k0 + lk8 * 8, Bi + slot * 8);
    }
    __syncthreads();
#pragma unroll
    for (int ks = 0; ks < 2; ++ks) {
      int m = wm * 16 + l16;
      int pa = (ks * 4 + quad) ^ (m & 7);
      short8 af = *(const short8*)(As + m * 64 + pa * 8);
#pragma unroll
      for (int j = 0; j < 4; ++j) {
        int n = wn * 64 + j * 16 + l16;
        int pb = (ks * 4 + quad) ^ (n & 7);
        short8 br = *(const short8*)(Br + n * 64 + pb * 8);
        short8 bi = *(const short8*)(Bi + n * 64 + pb * 8);
        ar[j] = __builtin_amdgcn_mfma_f32_16x16x32_bf16(af, br, ar[j], 0, 0, 0);
        ai[j] = __builtin_amdgcn_mfma_f32_16x16x32_bf16(af, bi, ai[j], 0, 0, 0);
      }
    }
  }

#pragma unroll
  for (int j = 0; j < 4; ++j) {
    int n = bn + wn * 64 + j * 16 + l16;
    float rb = rbias[n], ib = ibias[n], e8n = e8[n];
#pragma unroll
    for (int r = 0; r < 4; ++r) {
      int m = bm + wm * 16 + quad * 4 + r;
      size_t idx = (size_t)m * DO + n;
      float rv = sigm(ar[j][r] + rb);
      float a = exp2f(rv * e8n);
      float d = 1.f - a;                               // ~5e-3, bf16-safe
      float iv = sigm(ai[j][r] + ib);
      float xc = __bfloat162float(A[idx]);             // xconv[m][n] == A[m][n]
      float s = sqrtf(fmaxf(1.f - a * a, 0.f)) * iv * xc;
      ds_out[idx] = (unsigned int)bf16bits(d) | ((unsigned int)bf16bits(s) << 16);
    }
  }
}

// ---------------- out-proj GEMM tile 64x256 + fused RMSNorm(256) ----------------

__global__ __launch_bounds__(256) void gemm_on(const bf16* __restrict__ A,   // hs [BLR,256]
                                               const bf16* __restrict__ W,   // ow [256,256]
                                               const float* __restrict__ rnw,
                                               bf16* __restrict__ xb) {
  __shared__ __align__(16) bf16 As[64 * 64];
  __shared__ __align__(16) bf16 Bs[256 * 64];
  __shared__ float red[4][64];
  const int t = threadIdx.x;
  const int lane = t & 63;
  const int wn = t >> 6;           // wave = column slice of 64
  const int quad = lane >> 4, l16 = lane & 15;
  const int bm = blockIdx.x << 6;

  f32x4 acc[4][4] = {};

  for (int k0 = 0; k0 < DO; k0 += 64) {
    __syncthreads();
#pragma unroll
    for (int i = 0; i < 2; ++i) {
      int slot = i * 256 + t;
      int m = slot >> 3;
      int lk8 = (slot & 7) ^ (m & 7);
      gl_lds16(A + (size_t)(bm + m) * DO + k0 + lk8 * 8, As + slot * 8);
    }
#pragma unroll
    for (int i = 0; i < 8; ++i) {
      int slot = i * 256 + t;
      int n = slot >> 3;
      int lk8 = (slot & 7) ^ (n & 7);
      gl_lds16(W + (size_t)n * DO + k0 + lk8 * 8, Bs + slot * 8);
    }
    __syncthreads();
#pragma unroll
    for (int ks = 0; ks < 2; ++ks) {
      short8 af[4], bfr[4];
#pragma unroll
      for (int i = 0; i < 4; ++i) {
        int m = i * 16 + l16;
        int pa = (ks * 4 + quad) ^ (m & 7);
        af[i] = *(const short8*)(As + m * 64 + pa * 8);
        int n = wn * 64 + i * 16 + l16;
        int pb = (ks * 4 + quad) ^ (n & 7);
        bfr[i] = *(const short8*)(Bs + n * 64 + pb * 8);
      }
#pragma unroll
      for (int i = 0; i < 4; ++i)
#pragma unroll
        for (int j = 0; j < 4; ++j)
          acc[i][j] = __builtin_amdgcn_mfma_f32_16x16x32_bf16(af[i], bfr[j], acc[i][j], 0, 0, 0);
    }
  }

  float part[4][4];
#pragma unroll
  for (int i = 0; i < 4; ++i)
#pragma unroll
    for (int r = 0; r < 4; ++r) {
      float s = 0.f;
#pragma unroll
      for (int j = 0; j < 4; ++j) s += acc[i][j][r] * acc[i][j][r];
      part[i][r] = s;
    }
#pragma unroll
  for (int mask = 1; mask <= 8; mask <<= 1)
#pragma unroll
    for (int i = 0; i < 4; ++i)
#pragma unroll
      for (int r = 0; r < 4; ++r) part[i][r] += __shfl_xor(part[i][r], mask, 64);
  if (l16 == 0) {
#pragma unroll
    for (int i = 0; i < 4; ++i)
#pragma unroll
      for (int r = 0; r < 4; ++r) red[wn][i * 16 + quad * 4 + r] = part[i][r];
  }
  __syncthreads();
#pragma unroll
  for (int i = 0; i < 4; ++i) {
#pragma unroll
    for (int r = 0; r < 4; ++r) {
      int ml = i * 16 + quad * 4 + r;
      float tot = red[0][ml] + red[1][ml] + red[2][ml] + red[3][ml];
      float sc = rsqrtf(tot * (1.f / 256.f) + 1e-6f);
#pragma unroll
      for (int j = 0; j < 4; ++j) {
        int n = wn * 64 + j * 16 + l16;
        xb[(size_t)(bm + ml) * DO + n] = __float2bfloat16(acc[i][j][r] * sc * rnw[n]);
      }
    }
  }
}

// ---------------- launch ----------------

extern "C" void kernel_launch(void* const* d_in, const int* in_sizes, int n_in,
                              void* d_out, int out_size, void* d_ws, size_t ws_size,
                              hipStream_t stream) {
  const float* concept_out = (const float*)d_in[0];
  const float* encoder_out = (const float*)d_in[1];
  const float* bprobs      = (const float*)d_in[2];
  const int*   bidx        = (const int*)d_in[3];
  const float* gate_w      = (const float*)d_in[4];
  const float* gate_b      = (const float*)d_in[5];
  const float* down_w      = (const float*)d_in[6];
  const float* up_w        = (const float*)d_in[7];
  const float* norm_out_w  = (const float*)d_in[8];
  const float* rc_w        = (const float*)d_in[9];
  const float* rc_b        = (const float*)d_in[10];
  const float* wr_w        = (const float*)d_in[11];
  const float* wr_b        = (const float*)d_in[12];
  const float* wi_w        = (const float*)d_in[13];
  const float* wi_b        = (const float*)d_in[14];
  const float* log_a       = (const float*)d_in[15];
  const float* ow_w        = (const float*)d_in[16];
  const float* rn_w        = (const float*)d_in[17];
  float* out = (float*)d_out;
  (void)in_sizes; (void)n_in; (void)out_size; (void)ws_size;

  char* base = (char*)d_ws;
  size_t off = 0;
  auto alloc = [&](size_t bytes) -> char* {
    char* p = base + off;
    off += (bytes + 255) & ~(size_t)255;
    return p;
  };
  float* smoothed = (float*)alloc((size_t)NB * NM * DMODEL * 4);   // 8 MB
  int*   bucket   = (int*)alloc((size_t)BLR * 4);
  bf16*  gate_wb  = (bf16*)alloc((size_t)DMODEL * DMODEL * 2);
  bf16*  down_wb  = (bf16*)alloc((size_t)DO * DMODEL * 2);
  bf16*  up_wb    = (bf16*)alloc((size_t)DMODEL * DO * 2);
  bf16*  wrb      = (bf16*)alloc((size_t)3 * DO * DO * 2);
  bf16*  wib      = (bf16*)alloc((size_t)3 * DO * DO * 2);
  bf16*  owb      = (bf16*)alloc((size_t)3 * DO * DO * 2);
  float* e8       = (float*)alloc(3 * DO * 4);
  float2* ASsum   = (float2*)alloc((size_t)NB * NCH * DO * 8);     // 512 KB chunk summaries
  bf16*  xb       = (bf16*)alloc((size_t)BLR * DO * 2);            // 8 MB layer io

  // reused overlay region — offsets computed from actual buffer sizes
  const size_t SZ_ENC   = (size_t)BLR * DMODEL * 2;   // 32 MB
  const size_t SZ_XCONV = (size_t)BLR * DO * 2;       //  8 MB
  const size_t SZ_DS    = (size_t)BLR * DO * 4;       // 16 MB (packed uint32!)
  char* RA = alloc(2 * SZ_ENC);                       // 64 MB
  // head overlays
  bf16*  encb = (bf16*)RA;
  bf16*  h0b  = (bf16*)(RA + SZ_ENC);   // raw G1 logits, then gated in-place
  // layer overlays (xconvb | dsbuf | hsb disjoint: 8 + 16 + 8 = 32 MB)
  bf16*         xconvb = (bf16*)RA;
  unsigned int* dsbuf  = (unsigned int*)(RA + SZ_XCONV);
  bf16*         hsb    = (bf16*)(RA + SZ_XCONV + SZ_DS);
  // tail overlay
  bf16*  tmp2b  = (bf16*)RA;

  cvt4_kernel<<<(BLR * DMODEL / 4 + 255) / 256, 256, 0, stream>>>(
      (const float4*)encoder_out, (ushort4*)encb, BLR * DMODEL / 4);
  prep_kernel<<<(2163456 + 255) / 256, 256, 0, stream>>>(
      gate_w, down_w, up_w, wr_w, wi_w, ow_w, log_a,
      gate_wb, down_wb, up_wb, wrb, wib, owb, e8);
  ema_kernel<<<NB * 4, 256, 0, stream>>>(concept_out, bprobs, bidx, smoothed);
  bucket_kernel<<<BLR / 256, 256, 0, stream>>>(bidx, bucket);

  // G1: pure gate GEMM -> h0b (raw logits), then fused gate+plugback in place
  gemm256<DMODEL><<<dim3(BLR / 256, DMODEL / 256), 512, 0, stream>>>(encb, gate_wb, h0b);
  gate_plug_kernel<<<BLR, 256, 0, stream>>>(h0b, encb, gate_b, bprobs, bucket, smoothed);

  // G2: down projection -> xb (bf16)
  EpA ep{};
  ep.outb = xb;
  gemm_bt<5, DO, DMODEL><<<dim3(BLR / 128, DO / 128), 256, 0, stream>>>(h0b, down_wb, ep);

  for (int k = 0; k < 3; ++k) {
    conv_kernel<<<BLR, 256, 0, stream>>>(xb, rc_w + k * DO * 4, rc_b + k * DO, xconvb);
    gemm_ri<<<dim3(BLR / 32, DO / 128), 256, 0, stream>>>(
        xconvb, wrb + k * DO * DO, wib + k * DO * DO,
        wr_b + k * DO, wi_b + k * DO, e8 + k * DO, dsbuf);
    scan_p1<<<NB * NCH, 256, 0, stream>>>(dsbuf, ASsum);
    scan_p2<<<NB * NCH, 256, 0, stream>>>(dsbuf, ASsum, hsb);
    gemm_on<<<BLR / 64, 256, 0, stream>>>(hsb, owb + k * DO * DO, rn_w + k * DO, xb);
  }

  // up projection -> tmp2 (bf16), 256^2 8-phase; final rmsnorm -> out (f32)
  gemm256<DO><<<dim3(BLR / 256, DMODEL / 256), 512, 0, stream>>>(xb, up_wb, tmp2b);
  rmsnorm1024_kernel<<<BLR, 256, 0, stream>>>(tmp2b, norm_out_w, out);
}

// Round 8
// 472.191 us; speedup vs baseline: 1.1318x; 1.0301x over previous
//
#include <hip/hip_runtime.h>
#include <hip/hip_bf16.h>
#include <stdint.h>

typedef __attribute__((ext_vector_type(8))) short short8;   // 8 bf16 (4 VGPRs)
typedef __attribute__((ext_vector_type(4))) float f32x4;    // 4 fp32 acc
typedef __hip_bfloat16 bf16;

#define NB   8
#define LSEQ 2048
#define NM   256
#define DMODEL 1024
#define DO   256
#define BLR  16384   /* NB*LSEQ rows */
#define NCH  32      /* scan chunks */
#define CLK  64      /* chunk length */

__device__ __forceinline__ float sigm(float x) { return 1.f / (1.f + __expf(-x)); }

__device__ __forceinline__ void gl_lds16(const void* g, void* l) {
  __builtin_amdgcn_global_load_lds((const __attribute__((address_space(1))) void*)g,
                                   (__attribute__((address_space(3))) void*)l, 16, 0, 0);
}

// inline-asm LDS read: invisible to compiler alias analysis (no auto vmcnt(0)
// drain vs in-flight global_load_lds). Fenced by lgkmcnt(0)+sched_barrier(0).
__device__ __forceinline__ short8 ds_read128(const bf16* p) {
  short8 r;
  unsigned a = (unsigned)(uintptr_t)(const __attribute__((address_space(3))) bf16*)p;
  asm volatile("ds_read_b128 %0, %1" : "=v"(r) : "v"(a));
  return r;
}

__device__ __forceinline__ unsigned short bf16bits(float v) {
  bf16 b = __float2bfloat16(v);
  return *(unsigned short*)&b;
}
__device__ __forceinline__ float bits2f(unsigned short u) {
  bf16 b = *(bf16*)&u;
  return __bfloat162float(b);
}

// ---------------- prep: enc cvt + all weight cvts + e8l2a in ONE dispatch ------
// ranges: [0, 4194304) float4 enc cvt; then weight chains; then e8.

__global__ __launch_bounds__(256) void prep_kernel(
    const float* __restrict__ encoder_out, ushort4* __restrict__ encb4,
    const float* __restrict__ gate_w, const float* __restrict__ down_w,
    const float* __restrict__ up_w, const float* __restrict__ wr_w,
    const float* __restrict__ wi_w, const float* __restrict__ ow_w,
    const float* __restrict__ log_a,
    bf16* __restrict__ gate_wb, bf16* __restrict__ down_wb, bf16* __restrict__ up_wb,
    bf16* __restrict__ wrb, bf16* __restrict__ wib, bf16* __restrict__ owb,
    float* __restrict__ e8) {
  int i = blockIdx.x * 256 + threadIdx.x;
  if (i < 4194304) {
    float4 v = ((const float4*)encoder_out)[i];
    ushort4 o;
    o.x = bf16bits(v.x); o.y = bf16bits(v.y); o.z = bf16bits(v.z); o.w = bf16bits(v.w);
    encb4[i] = o;
    return;
  }
  i -= 4194304;
  if (i < 1048576) { gate_wb[i] = __float2bfloat16(gate_w[i]); return; }
  i -= 1048576;
  if (i < 262144) { down_wb[i] = __float2bfloat16(down_w[i]); return; }
  i -= 262144;
  if (i < 262144) { up_wb[i] = __float2bfloat16(up_w[i]); return; }
  i -= 262144;
  if (i < 196608) { wrb[i] = __float2bfloat16(wr_w[i]); return; }
  i -= 196608;
  if (i < 196608) { wib[i] = __float2bfloat16(wi_w[i]); return; }
  i -= 196608;
  if (i < 196608) { owb[i] = __float2bfloat16(ow_w[i]); return; }
  i -= 196608;
  if (i < 768) {
    float ab = 1.f / (1.f + expf(-log_a[i]));
    e8[i] = 8.f * log2f(ab);
  }
}

// ---------------- EMA + bucket, merged (blocks 0..31 ema, 32..95 bucket) -------

__global__ __launch_bounds__(256) void ema_bucket_kernel(const float* __restrict__ cpt,
                                                         const float* __restrict__ bprobs,
                                                         const int* __restrict__ bidx,
                                                         float* __restrict__ smoothed,
                                                         int* __restrict__ bucket) {
  if (blockIdx.x < NB * 4) {
    int b = blockIdx.x >> 2;
    int c = ((blockIdx.x & 3) << 8) + threadIdx.x;
    __shared__ float p[NM];
    p[threadIdx.x] = bprobs[b * LSEQ + bidx[b * NM + threadIdx.x]];
    __syncthreads();
    const float* cp = cpt + (size_t)b * NM * DMODEL + c;
    float* sp = smoothed + (size_t)b * NM * DMODEL + c;
    float h = 0.f;
    for (int m = 0; m < NM; ++m) {
      float pm = p[m];
      h = pm * cp[(size_t)m * DMODEL] + (1.f - pm) * h;
      sp[(size_t)m * DMODEL] = h;
    }
  } else {
    int i = (blockIdx.x - NB * 4) * 256 + threadIdx.x;
    int b = i >> 11, l = i & 2047;
    const int* bi = bidx + b * NM;
    int lo = 0, hi = NM;
    while (lo < hi) {
      int mid = (lo + hi) >> 1;
      if (bi[mid] <= l) lo = mid + 1; else hi = mid;
    }
    int v = lo - 1;
    bucket[i] = v < 0 ? 0 : v;
  }
}

// ---------------- gate + plugback elementwise (split from G1 epilogue) ----------
// h0 holds raw gemm logits (bf16); transformed IN PLACE:
// h0[m][n] = (1-p[m]) * sigm(h0[m][n] + gb[n]) * enc[m][n] + smoothed[b][bucket[m]][n]

__global__ __launch_bounds__(256) void gate_plug_kernel(bf16* __restrict__ h0,
                                                        const bf16* __restrict__ encb,
                                                        const float* __restrict__ gbias,
                                                        const float* __restrict__ bprobs,
                                                        const int* __restrict__ bucket,
                                                        const float* __restrict__ smoothed) {
  const int m = blockIdx.x;
  const int t = threadIdx.x;
  const int b = m >> 11;
  const float pm1 = 1.f - bprobs[m];
  const float* srow = smoothed + ((size_t)(b * NM + bucket[m])) * DMODEL + t * 4;
  const size_t base = (size_t)m * DMODEL + t * 4;
  ushort4 gr = *(const ushort4*)(h0 + base);
  ushort4 er = *(const ushort4*)(encb + base);
  float4 sm4 = *(const float4*)srow;
  float4 gb4 = *(const float4*)(gbias + t * 4);
  ushort4 o;
  o.x = bf16bits(pm1 * sigm(bits2f(gr.x) + gb4.x) * bits2f(er.x) + sm4.x);
  o.y = bf16bits(pm1 * sigm(bits2f(gr.y) + gb4.y) * bits2f(er.y) + sm4.y);
  o.z = bf16bits(pm1 * sigm(bits2f(gr.z) + gb4.z) * bits2f(er.z) + sm4.z);
  o.w = bf16bits(pm1 * sigm(bits2f(gr.w) + gb4.w) * bits2f(er.w) + sm4.w);
  *(ushort4*)(h0 + base) = o;
}

// ---------------- depthwise causal conv k=4, vectorized ushort4 ----------------
// thread handles 4 consecutive channels of one (b,l) row. grid = BLR*64/256.

__global__ __launch_bounds__(256) void conv_kernel(const bf16* __restrict__ x,
                                                   const float* __restrict__ cw,
                                                   const float* __restrict__ cb,
                                                   bf16* __restrict__ xcb) {
  int i4 = blockIdx.x * 256 + threadIdx.x;   // 4-channel group index
  int cg = i4 & 63;
  int bl = i4 >> 6;
  int l = bl & 2047;
  int c0 = cg << 2;
  float wf[4][4];
#pragma unroll
  for (int cc = 0; cc < 4; ++cc) {
    float4 w4 = ((const float4*)cw)[c0 + cc];
    wf[cc][0] = w4.x; wf[cc][1] = w4.y; wf[cc][2] = w4.z; wf[cc][3] = w4.w;
  }
  float4 cb4 = *(const float4*)(cb + c0);
  float s0 = cb4.x, s1 = cb4.y, s2 = cb4.z, s3 = cb4.w;
#pragma unroll
  for (int kk = 0; kk < 4; ++kk) {
    int ll = l - 3 + kk;
    if (ll >= 0) {
      ushort4 xv = *(const ushort4*)(x + (size_t)(bl + kk - 3) * DO + c0);
      s0 += wf[0][kk] * bits2f(xv.x);
      s1 += wf[1][kk] * bits2f(xv.y);
      s2 += wf[2][kk] * bits2f(xv.z);
      s3 += wf[3][kk] * bits2f(xv.w);
    }
  }
  ushort4 o;
  o.x = bf16bits(s0); o.y = bf16bits(s1); o.z = bf16bits(s2); o.w = bf16bits(s3);
  *(ushort4*)(xcb + (size_t)bl * DO + c0) = o;
}

// ---------------- chunked scan, 2 dispatches, 256 blocks each ----------------
// input packed uint: lo16 = d = 1-a (bf16), hi16 = s (bf16). h = (1-d)*h + s.

__global__ __launch_bounds__(256) void scan_p1(const unsigned int* __restrict__ ds,
                                               float2* __restrict__ AS) {
  int b = blockIdx.x >> 5, ch = blockIdx.x & 31, c = threadIdx.x;
  size_t base = ((size_t)b * LSEQ + ch * CLK) * DO + c;
  float A = 1.f, S = 0.f;
  for (int t = 0; t < CLK; ++t) {
    unsigned int u = ds[base + (size_t)t * DO];
    float d = bits2f((unsigned short)(u & 0xffff));
    float s = bits2f((unsigned short)(u >> 16));
    float a = 1.f - d;
    A *= a;
    S = __builtin_fmaf(a, S, s);
  }
  AS[blockIdx.x * DO + c] = make_float2(A, S);
}

__global__ __launch_bounds__(256) void scan_p2(const unsigned int* __restrict__ ds,
                                               const float2* __restrict__ AS,
                                               bf16* __restrict__ hs) {
  int b = blockIdx.x >> 5, ch = blockIdx.x & 31, c = threadIdx.x;
  // prefix over earlier chunks of this batch (L2-hot, <=31 iterations)
  float h = 0.f;
  for (int j = 0; j < ch; ++j) {
    float2 as = AS[(b * NCH + j) * DO + c];
    h = __builtin_fmaf(as.x, h, as.y);
  }
  size_t base = ((size_t)b * LSEQ + ch * CLK) * DO + c;
  for (int t = 0; t < CLK; ++t) {
    unsigned int u = ds[base + (size_t)t * DO];
    float d = bits2f((unsigned short)(u & 0xffff));
    float s = bits2f((unsigned short)(u >> 16));
    h = __builtin_fmaf(-d, h, h) + s;   // (1-d)*h + s
    hs[base + (size_t)t * DO] = __float2bfloat16(h);
  }
}

// ---------------- final rmsnorm over 1024, bf16 in -> f32 out ----------------

__global__ __launch_bounds__(256) void rmsnorm1024_kernel(const bf16* __restrict__ in,
                                                          const float* __restrict__ w,
                                                          float* __restrict__ out) {
  int row = blockIdx.x, t = threadIdx.x;
  ushort4 raw = ((const ushort4*)(in + (size_t)row * 1024))[t];
  float v0 = bits2f(raw.x), v1 = bits2f(raw.y), v2 = bits2f(raw.z), v3 = bits2f(raw.w);
  float ss = v0 * v0 + v1 * v1 + v2 * v2 + v3 * v3;
#pragma unroll
  for (int ofs = 32; ofs > 0; ofs >>= 1) ss += __shfl_down(ss, ofs, 64);
  __shared__ float wsum[4];
  if ((t & 63) == 0) wsum[t >> 6] = ss;
  __syncthreads();
  float tot = wsum[0] + wsum[1] + wsum[2] + wsum[3];
  float sc = rsqrtf(tot * (1.f / 1024.f) + 1e-6f);
  float4 wv = ((const float4*)w)[t];
  float4 o;
  o.x = v0 * sc * wv.x; o.y = v1 * sc * wv.y;
  o.z = v2 * sc * wv.z; o.w = v3 * sc * wv.w;
  ((float4*)(out + (size_t)row * 1024))[t] = o;
}

// ---------------- down-proj GEMM 64x128, occupancy-tiled ----------------
// M=16384 N=256 K=1024. 64-row x 128-col tiles -> grid (256,2)=512 blocks,
// LDS 24KB, acc 32 VGPR/thread -> multi-block/CU (old 128^2 = 1 block/CU).

__global__ __launch_bounds__(256, 4) void gemm_dn(const bf16* __restrict__ A,
                                                  const bf16* __restrict__ W,
                                                  bf16* __restrict__ outb) {
  __shared__ __align__(16) bf16 As[64 * 64];    //  8 KB
  __shared__ __align__(16) bf16 Bs[128 * 64];   // 16 KB
  const int t = threadIdx.x;
  const int lane = t & 63;
  const int wv = t >> 6;
  const int wm = wv >> 1, wn = wv & 1;   // 2x2 waves, wave tile 32x64
  const int quad = lane >> 4, l16 = lane & 15;
  const int bm = blockIdx.x << 6, bn = blockIdx.y << 7;

  f32x4 acc[2][4] = {};

  for (int k0 = 0; k0 < DMODEL; k0 += 64) {
    __syncthreads();
#pragma unroll
    for (int i = 0; i < 2; ++i) {   // A: 64 rows x 64 k
      int slot = i * 256 + t;
      int m = slot >> 3, lk8 = (slot & 7) ^ (m & 7);
      gl_lds16(A + (size_t)(bm + m) * DMODEL + k0 + lk8 * 8, As + slot * 8);
    }
#pragma unroll
    for (int i = 0; i < 4; ++i) {   // B: 128 rows x 64 k
      int slot = i * 256 + t;
      int n = slot >> 3, lk8 = (slot & 7) ^ (n & 7);
      gl_lds16(W + (size_t)(bn + n) * DMODEL + k0 + lk8 * 8, Bs + slot * 8);
    }
    __syncthreads();
#pragma unroll
    for (int ks = 0; ks < 2; ++ks) {
      short8 af[2], bfr[4];
#pragma unroll
      for (int i = 0; i < 2; ++i) {
        int m = wm * 32 + i * 16 + l16;
        int pa = (ks * 4 + quad) ^ (m & 7);
        af[i] = *(const short8*)(As + m * 64 + pa * 8);
      }
#pragma unroll
      for (int j = 0; j < 4; ++j) {
        int n = wn * 64 + j * 16 + l16;
        int pb = (ks * 4 + quad) ^ (n & 7);
        bfr[j] = *(const short8*)(Bs + n * 64 + pb * 8);
      }
#pragma unroll
      for (int i = 0; i < 2; ++i)
#pragma unroll
        for (int j = 0; j < 4; ++j)
          acc[i][j] = __builtin_amdgcn_mfma_f32_16x16x32_bf16(af[i], bfr[j], acc[i][j], 0, 0, 0);
    }
  }

#pragma unroll
  for (int i = 0; i < 2; ++i)
#pragma unroll
    for (int j = 0; j < 4; ++j)
#pragma unroll
      for (int r = 0; r < 4; ++r) {
        int m = bm + wm * 32 + i * 16 + quad * 4 + r;
        int n = bn + wn * 64 + j * 16 + l16;
        outb[(size_t)m * DO + n] = __float2bfloat16(acc[i][j][r]);
      }
}

// ---------------- 256x256 8-phase GEMM (T2+T3+T4+T5), N = DMODEL, pure ----------

template <int KC>
__global__ __launch_bounds__(512, 2) void gemm256(const bf16* __restrict__ Ag,
                                                  const bf16* __restrict__ W,
                                                  bf16* __restrict__ outb) {
  __shared__ __align__(16) bf16 lds[2][4][128 * 64];   // [buf][A0,A1,B0,B1][...]
  const int t = threadIdx.x;
  const int lane = t & 63;
  const int wv = t >> 6;
  const int wm = wv >> 2, wn = wv & 3;
  const int quad = lane >> 4, l16 = lane & 15;
  const int bm = blockIdx.x << 8, bn = blockIdx.y << 8;
  constexpr int KT = KC >> 6;   // # 64-wide k-tiles (power of 2, >= 4)
  constexpr int KM = KT - 1;

  const int rr = t >> 3;                 // 0..63 staging row (q=0); q=1 adds +128 global
  const int cc = (t & 7) ^ (rr & 7);     // pre-swizzled source chunk

  f32x4 acc[8][4] = {};
  short8 af[4][2], bfr[2][2];

#define STAGE_A(BUF, H, KTI)                                                      \
  {                                                                               \
    int kk = ((KTI) & KM) << 6;                                                   \
    const bf16* s0 = Ag + (size_t)(bm + (H) * 64 + rr) * KC + kk + cc * 8;        \
    gl_lds16(s0, &lds[BUF][H][t * 8]);                                            \
    const bf16* s1 = Ag + (size_t)(bm + (H) * 64 + rr + 128) * KC + kk + cc * 8;  \
    gl_lds16(s1, &lds[BUF][H][(512 + t) * 8]);                                    \
  }
#define STAGE_B(BUF, H, KTI)                                                      \
  {                                                                               \
    int kk = ((KTI) & KM) << 6;                                                   \
    int n0 = (H) * 32 + (rr & 31) + ((rr >> 5) << 6);                             \
    const bf16* s0 = W + (size_t)(bn + n0) * KC + kk + cc * 8;                    \
    gl_lds16(s0, &lds[BUF][2 + (H)][t * 8]);                                      \
    const bf16* s1 = W + (size_t)(bn + n0 + 128) * KC + kk + cc * 8;              \
    gl_lds16(s1, &lds[BUF][2 + (H)][(512 + t) * 8]);                              \
  }
#define LD_A(BUF, MG)                                                             \
  _Pragma("unroll") for (int ii = 0; ii < 4; ++ii) {                              \
    int r = wm * 64 + ii * 16 + l16;                                              \
    _Pragma("unroll") for (int ks = 0; ks < 2; ++ks) {                            \
      int ch = (ks * 4 + quad) ^ (r & 7);                                         \
      af[ii][ks] = ds_read128(&lds[BUF][MG][(r * 8 + ch) * 8]);                   \
    }                                                                             \
  }
#define LD_B(BUF, NG)                                                             \
  _Pragma("unroll") for (int jj = 0; jj < 2; ++jj) {                              \
    int r = wn * 32 + jj * 16 + l16;                                              \
    _Pragma("unroll") for (int ks = 0; ks < 2; ++ks) {                            \
      int ch = (ks * 4 + quad) ^ (r & 7);                                         \
      bfr[jj][ks] = ds_read128(&lds[BUF][2 + (NG)][(r * 8 + ch) * 8]);            \
    }                                                                             \
  }
#define MMA(MG, NG)                                                               \
  _Pragma("unroll") for (int ks = 0; ks < 2; ++ks)                                \
  _Pragma("unroll") for (int ii = 0; ii < 4; ++ii)                                \
  _Pragma("unroll") for (int jj = 0; jj < 2; ++jj)                                \
    acc[(MG) * 4 + ii][(NG) * 2 + jj] = __builtin_amdgcn_mfma_f32_16x16x32_bf16(  \
        af[ii][ks], bfr[jj][ks], acc[(MG) * 4 + ii][(NG) * 2 + jj], 0, 0, 0);
#define BARR __builtin_amdgcn_s_barrier()
#define WAIT_LGKM asm volatile("s_waitcnt lgkmcnt(0)" ::: "memory")
#define WAIT_VM6 asm volatile("s_waitcnt vmcnt(6)" ::: "memory")
#define SBAR __builtin_amdgcn_sched_barrier(0)
#define PH(MG, NG)                   \
  BARR; WAIT_LGKM; SBAR;             \
  __builtin_amdgcn_s_setprio(1);     \
  MMA(MG, NG);                       \
  __builtin_amdgcn_s_setprio(0);     \
  SBAR;                              \
  BARR;
#define PH_V(MG, NG)                 \
  BARR; WAIT_LGKM; SBAR;             \
  __builtin_amdgcn_s_setprio(1);     \
  MMA(MG, NG);                       \
  __builtin_amdgcn_s_setprio(0);     \
  SBAR;                              \
  WAIT_VM6;                          \
  BARR;

  // prologue: buf0 <- kt0 complete; buf1 <- kt1 {A0, A1, B1} (B0 staged at g1)
  STAGE_A(0, 0, 0) STAGE_A(0, 1, 0) STAGE_B(0, 0, 0) STAGE_B(0, 1, 0)
  STAGE_A(1, 0, 1) STAGE_A(1, 1, 1) STAGE_B(1, 1, 1)
  WAIT_VM6;   // buf0's 8 loads (oldest) complete; buf1's 6 stay in flight
  BARR;

#pragma unroll 1
  for (int it = 0; it < (KT >> 1); ++it) {
    const int kt = it * 2;
    LD_A(0, 0) LD_B(0, 0)
    STAGE_B(1, 0, kt + 1)
    PH(0, 0)
    LD_B(0, 1)
    STAGE_A(0, 0, kt + 2)
    PH(0, 1)
    LD_A(0, 1)
    STAGE_B(0, 1, kt + 2)
    PH(1, 1)
    LD_B(0, 0)
    STAGE_A(0, 1, kt + 2)
    PH_V(1, 0)
    LD_A(1, 0) LD_B(1, 0)
    STAGE_B(0, 0, kt + 2)
    PH(0, 0)
    LD_B(1, 1)
    STAGE_A(1, 0, kt + 3)
    PH(0, 1)
    LD_A(1, 1)
    STAGE_B(1, 1, kt + 3)
    PH(1, 1)
    LD_B(1, 0)
    STAGE_A(1, 1, kt + 3)
    PH_V(1, 0)
  }

#undef STAGE_A
#undef STAGE_B
#undef LD_A
#undef LD_B
#undef MMA
#undef BARR
#undef WAIT_LGKM
#undef WAIT_VM6
#undef SBAR
#undef PH
#undef PH_V

#pragma unroll
  for (int i = 0; i < 8; ++i) {
#pragma unroll
    for (int j = 0; j < 4; ++j) {
#pragma unroll
      for (int r = 0; r < 4; ++r) {
        int m = bm + wm * 128 + i * 16 + quad * 4 + r;
        int n = bn + wn * 64 + j * 16 + l16;
        outb[(size_t)m * DMODEL + n] = __float2bfloat16(acc[i][j][r]);
      }
    }
  }
}

// ---------------- dual GEMM v2: occupancy-tiled 32x128, 1024 blocks ----------------

__global__ __launch_bounds__(256, 4) void gemm_ri(const bf16* __restrict__ A,
                                                  const bf16* __restrict__ Wr,
                                                  const bf16* __restrict__ Wi,
                                                  const float* __restrict__ rbias,
                                                  const float* __restrict__ ibias,
                                                  const float* __restrict__ e8,
                                                  unsigned int* __restrict__ ds_out) {
  __shared__ __align__(16) bf16 As[32 * 64];    //  4 KB
  __shared__ __align__(16) bf16 Br[128 * 64];   // 16 KB
  __shared__ __align__(16) bf16 Bi[128 * 64];   // 16 KB
  const int t = threadIdx.x;
  const int lane = t & 63;
  const int wv = t >> 6;
  const int wm = wv >> 1, wn = wv & 1;    // 2x2 waves, wave tile 16x64
  const int quad = lane >> 4, l16 = lane & 15;
  const int bm = blockIdx.x << 5;         // 32-row tile
  const int bn = blockIdx.y << 7;         // 128-col tile

  f32x4 ar[4] = {};
  f32x4 ai[4] = {};

  for (int k0 = 0; k0 < DO; k0 += 64) {
    __syncthreads();
    {  // A: 32 rows x 64 k, one 16B chunk per thread
      int m = t >> 3, lk8 = (t & 7) ^ (m & 7);
      gl_lds16(A + (size_t)(bm + m) * DO + k0 + lk8 * 8, As + t * 8);
    }
#pragma unroll
    for (int i = 0; i < 4; ++i) {  // Wr/Wi: 128 rows x 64 k each
      int slot = i * 256 + t;
      int n = slot >> 3, lk8 = (slot & 7) ^ (n & 7);
      gl_lds16(Wr + (size_t)(bn + n) * DO + k0 + lk8 * 8, Br + slot * 8);
      gl_lds16(Wi + (size_t)(bn + n) * DO + k0 + lk8 * 8, Bi + slot * 8);
    }
    __syncthreads();
#pragma unroll
    for (int ks = 0; ks < 2; ++ks) {
      int m = wm * 16 + l16;
      int pa = (ks * 4 + quad) ^ (m & 7);
      short8 af = *(const short8*)(As + m * 64 + pa * 8);
#pragma unroll
      for (int j = 0; j < 4; ++j) {
        int n = wn * 64 + j * 16 + l16;
        int pb = (ks * 4 + quad) ^ (n & 7);
        short8 br = *(const short8*)(Br + n * 64 + pb * 8);
        short8 bi = *(const short8*)(Bi + n * 64 + pb * 8);
        ar[j] = __builtin_amdgcn_mfma_f32_16x16x32_bf16(af, br, ar[j], 0, 0, 0);
        ai[j] = __builtin_amdgcn_mfma_f32_16x16x32_bf16(af, bi, ai[j], 0, 0, 0);
      }
    }
  }

#pragma unroll
  for (int j = 0; j < 4; ++j) {
    int n = bn + wn * 64 + j * 16 + l16;
    float rb = rbias[n], ib = ibias[n], e8n = e8[n];
#pragma unroll
    for (int r = 0; r < 4; ++r) {
      int m = bm + wm * 16 + quad * 4 + r;
      size_t idx = (size_t)m * DO + n;
      float rv = sigm(ar[j][r] + rb);
      float a = exp2f(rv * e8n);
      float d = 1.f - a;                               // ~5e-3, bf16-safe
      float iv = sigm(ai[j][r] + ib);
      float xc = __bfloat162float(A[idx]);             // xconv[m][n] == A[m][n]
      float s = sqrtf(fmaxf(1.f - a * a, 0.f)) * iv * xc;
      ds_out[idx] = (unsigned int)bf16bits(d) | ((unsigned int)bf16bits(s) << 16);
    }
  }
}

// ---------------- out-proj GEMM v2: 32x256 tiles + fused RMSNorm(256) -----------
// grid BLR/32 = 512 blocks (was 256), acc 32 VGPR (was 64), LDS 36.5KB.

__global__ __launch_bounds__(256, 4) void gemm_on(const bf16* __restrict__ A,   // hs [BLR,256]
                                                  const bf16* __restrict__ W,   // ow [256,256]
                                                  const float* __restrict__ rnw,
                                                  bf16* __restrict__ xb) {
  __shared__ __align__(16) bf16 As[32 * 64];    //  4 KB
  __shared__ __align__(16) bf16 Bs[256 * 64];   // 32 KB
  __shared__ float red[4][32];
  const int t = threadIdx.x;
  const int lane = t & 63;
  const int wn = t >> 6;           // wave = column slice of 64
  const int quad = lane >> 4, l16 = lane & 15;
  const int bm = blockIdx.x << 5;  // 32-row tile

  f32x4 acc[2][4] = {};

  for (int k0 = 0; k0 < DO; k0 += 64) {
    __syncthreads();
    {  // A: 32 rows x 64 k, one chunk per thread
      int m = t >> 3, lk8 = (t & 7) ^ (m & 7);
      gl_lds16(A + (size_t)(bm + m) * DO + k0 + lk8 * 8, As + t * 8);
    }
#pragma unroll
    for (int i = 0; i < 8; ++i) {  // B: 256 rows x 64 k
      int slot = i * 256 + t;
      int n = slot >> 3, lk8 = (slot & 7) ^ (n & 7);
      gl_lds16(W + (size_t)n * DO + k0 + lk8 * 8, Bs + slot * 8);
    }
    __syncthreads();
#pragma unroll
    for (int ks = 0; ks < 2; ++ks) {
      short8 af[2], bfr[4];
#pragma unroll
      for (int i = 0; i < 2; ++i) {
        int m = i * 16 + l16;
        int pa = (ks * 4 + quad) ^ (m & 7);
        af[i] = *(const short8*)(As + m * 64 + pa * 8);
      }
#pragma unroll
      for (int j = 0; j < 4; ++j) {
        int n = wn * 64 + j * 16 + l16;
        int pb = (ks * 4 + quad) ^ (n & 7);
        bfr[j] = *(const short8*)(Bs + n * 64 + pb * 8);
      }
#pragma unroll
      for (int i = 0; i < 2; ++i)
#pragma unroll
        for (int j = 0; j < 4; ++j)
          acc[i][j] = __builtin_amdgcn_mfma_f32_16x16x32_bf16(af[i], bfr[j], acc[i][j], 0, 0, 0);
    }
  }

  float part[2][4];
#pragma unroll
  for (int i = 0; i < 2; ++i)
#pragma unroll
    for (int r = 0; r < 4; ++r) {
      float s = 0.f;
#pragma unroll
      for (int j = 0; j < 4; ++j) s += acc[i][j][r] * acc[i][j][r];
      part[i][r] = s;
    }
#pragma unroll
  for (int mask = 1; mask <= 8; mask <<= 1)
#pragma unroll
    for (int i = 0; i < 2; ++i)
#pragma unroll
      for (int r = 0; r < 4; ++r) part[i][r] += __shfl_xor(part[i][r], mask, 64);
  if (l16 == 0) {
#pragma unroll
    for (int i = 0; i < 2; ++i)
#pragma unroll
      for (int r = 0; r < 4; ++r) red[wn][i * 16 + quad * 4 + r] = part[i][r];
  }
  __syncthreads();
#pragma unroll
  for (int i = 0; i < 2; ++i) {
#pragma unroll
    for (int r = 0; r < 4; ++r) {
      int ml = i * 16 + quad * 4 + r;
      float tot = red[0][ml] + red[1][ml] + red[2][ml] + red[3][ml];
      float sc = rsqrtf(tot * (1.f / 256.f) + 1e-6f);
#pragma unroll
      for (int j = 0; j < 4; ++j) {
        int n = wn * 64 + j * 16 + l16;
        xb[(size_t)(bm + ml) * DO + n] = __float2bfloat16(acc[i][j][r] * sc * rnw[n]);
      }
    }
  }
}

// ---------------- launch ----------------

extern "C" void kernel_launch(void* const* d_in, const int* in_sizes, int n_in,
                              void* d_out, int out_size, void* d_ws, size_t ws_size,
                              hipStream_t stream) {
  const float* concept_out = (const float*)d_in[0];
  const float* encoder_out = (const float*)d_in[1];
  const float* bprobs      = (const float*)d_in[2];
  const int*   bidx        = (const int*)d_in[3];
  const float* gate_w      = (const float*)d_in[4];
  const float* gate_b      = (const float*)d_in[5];
  const float* down_w      = (const float*)d_in[6];
  const float* up_w        = (const float*)d_in[7];
  const float* norm_out_w  = (const float*)d_in[8];
  const float* rc_w        = (const float*)d_in[9];
  const float* rc_b        = (const float*)d_in[10];
  const float* wr_w        = (const float*)d_in[11];
  const float* wr_b        = (const float*)d_in[12];
  const float* wi_w        = (const float*)d_in[13];
  const float* wi_b        = (const float*)d_in[14];
  const float* log_a       = (const float*)d_in[15];
  const float* ow_w        = (const float*)d_in[16];
  const float* rn_w        = (const float*)d_in[17];
  float* out = (float*)d_out;
  (void)in_sizes; (void)n_in; (void)out_size; (void)ws_size;

  char* base = (char*)d_ws;
  size_t off = 0;
  auto alloc = [&](size_t bytes) -> char* {
    char* p = base + off;
    off += (bytes + 255) & ~(size_t)255;
    return p;
  };
  float* smoothed = (float*)alloc((size_t)NB * NM * DMODEL * 4);   // 8 MB
  int*   bucket   = (int*)alloc((size_t)BLR * 4);
  bf16*  gate_wb  = (bf16*)alloc((size_t)DMODEL * DMODEL * 2);
  bf16*  down_wb  = (bf16*)alloc((size_t)DO * DMODEL * 2);
  bf16*  up_wb    = (bf16*)alloc((size_t)DMODEL * DO * 2);
  bf16*  wrb      = (bf16*)alloc((size_t)3 * DO * DO * 2);
  bf16*  wib      = (bf16*)alloc((size_t)3 * DO * DO * 2);
  bf16*  owb      = (bf16*)alloc((size_t)3 * DO * DO * 2);
  float* e8       = (float*)alloc(3 * DO * 4);
  float2* ASsum   = (float2*)alloc((size_t)NB * NCH * DO * 8);     // 512 KB chunk summaries
  bf16*  xb       = (bf16*)alloc((size_t)BLR * DO * 2);            // 8 MB layer io

  // reused overlay region — offsets computed from actual buffer sizes
  const size_t SZ_ENC   = (size_t)BLR * DMODEL * 2;   // 32 MB
  const size_t SZ_XCONV = (size_t)BLR * DO * 2;       //  8 MB
  const size_t SZ_DS    = (size_t)BLR * DO * 4;       // 16 MB (packed uint32!)
  char* RA = alloc(2 * SZ_ENC);                       // 64 MB
  // head overlays
  bf16*  encb = (bf16*)RA;
  bf16*  h0b  = (bf16*)(RA + SZ_ENC);   // raw G1 logits, then gated in-place
  // layer overlays (xconvb | dsbuf | hsb disjoint: 8 + 16 + 8 = 32 MB)
  bf16*         xconvb = (bf16*)RA;
  unsigned int* dsbuf  = (unsigned int*)(RA + SZ_XCONV);
  bf16*         hsb    = (bf16*)(RA + SZ_XCONV + SZ_DS);
  // tail overlay
  bf16*  tmp2b  = (bf16*)RA;

  // prep: enc cvt (4194304 vec4) + weight cvts (2162688) + e8 (768)
  prep_kernel<<<(4194304 + 2163456 + 255) / 256, 256, 0, stream>>>(
      encoder_out, (ushort4*)encb,
      gate_w, down_w, up_w, wr_w, wi_w, ow_w, log_a,
      gate_wb, down_wb, up_wb, wrb, wib, owb, e8);
  ema_bucket_kernel<<<NB * 4 + BLR / 256, 256, 0, stream>>>(
      concept_out, bprobs, bidx, smoothed, bucket);

  // G1: pure gate GEMM -> h0b (raw logits), then fused gate+plugback in place
  gemm256<DMODEL><<<dim3(BLR / 256, DMODEL / 256), 512, 0, stream>>>(encb, gate_wb, h0b);
  gate_plug_kernel<<<BLR, 256, 0, stream>>>(h0b, encb, gate_b, bprobs, bucket, smoothed);

  // G2: down projection -> xb (bf16), occupancy-tiled
  gemm_dn<<<dim3(BLR / 64, DO / 128), 256, 0, stream>>>(h0b, down_wb, xb);

  for (int k = 0; k < 3; ++k) {
    conv_kernel<<<BLR * 64 / 256, 256, 0, stream>>>(xb, rc_w + k * DO * 4, rc_b + k * DO, xconvb);
    gemm_ri<<<dim3(BLR / 32, DO / 128), 256, 0, stream>>>(
        xconvb, wrb + k * DO * DO, wib + k * DO * DO,
        wr_b + k * DO, wi_b + k * DO, e8 + k * DO, dsbuf);
    scan_p1<<<NB * NCH, 256, 0, stream>>>(dsbuf, ASsum);
    scan_p2<<<NB * NCH, 256, 0, stream>>>(dsbuf, ASsum, hsb);
    gemm_on<<<BLR / 32, 256, 0, stream>>>(hsb, owb + k * DO * DO, rn_w + k * DO, xb);
  }

  // up projection -> tmp2 (bf16), 256^2 8-phase; final rmsnorm -> out (f32)
  gemm256<DO><<<dim3(BLR / 256, DMODEL / 256), 512, 0, stream>>>(xb, up_wb, tmp2b);
  rmsnorm1024_kernel<<<BLR, 256, 0, stream>>>(tmp2b, norm_out_w, out);
}